// Round 1
// baseline (14998.399 us; speedup 1.0000x reference)
//
#include <hip/hip_runtime.h>

#define V_SZ 32000
#define D_SZ 256
#define H_SZ 512
#define B_SZ 16
#define S_SZ 400
#define T_SZ 100
#define NX   50
#define G4   2048
#define VX   32050
#define NB_ENC 256
#define NB_DEC 128

typedef unsigned short ushort_t;
typedef __attribute__((ext_vector_type(8))) __bf16 bf16x8;
typedef __attribute__((ext_vector_type(8))) unsigned short ushort8_t;
typedef __attribute__((ext_vector_type(4))) float f32x4;

__device__ __forceinline__ ushort_t f2bf(float x) {
  union { float f; unsigned u; } v; v.f = x;
  unsigned r = v.u + 0x7fffu + ((v.u >> 16) & 1u);
  return (ushort_t)(r >> 16);
}
__device__ __forceinline__ float sigf(float x) { return 1.0f / (1.0f + __expf(-x)); }
__device__ __forceinline__ float tanh_f(float x) {
  float e = __expf(2.0f * x);
  return 1.0f - 2.0f / (e + 1.0f);
}
__device__ __forceinline__ float dot4(f32x4 a, f32x4 b) {
  return a.x * b.x + a.y * b.y + a.z * b.z + a.w * b.w;
}

// Grid barrier via per-block flags. Monotonic phase counter; flags zeroed by
// hipMemsetAsync at launch start. Release store pushes this block's prior
// writes to the device coherence point; all communicated data buffers are
// write-once per launch, so readers never hold stale copies (no invalidation
// needed -> read-only weights stay L2-hot across steps).
__device__ __forceinline__ void barrier_flags(int* flags, int nflags, int pc) {
  __syncthreads();
  if (threadIdx.x == 0)
    __hip_atomic_store(&flags[blockIdx.x], pc, __ATOMIC_RELEASE, __HIP_MEMORY_SCOPE_AGENT);
  if ((int)threadIdx.x < nflags) {
    while (__hip_atomic_load(&flags[threadIdx.x], __ATOMIC_RELAXED, __HIP_MEMORY_SCOPE_AGENT) < pc)
      __builtin_amdgcn_s_sleep(2);
  }
  __syncthreads();
}

// ---------------- f32 -> bf16 convert ----------------
__global__ __launch_bounds__(256) void cvt_kernel(const float* in, ushort_t* outp, int n) {
  int i = blockIdx.x * 256 + threadIdx.x;
  int stride = gridDim.x * 256;
  for (; i < n; i += stride) outp[i] = f2bf(in[i]);
}

// ---------------- gather source embeddings (bf16), rows m = s*16+b ----------------
__global__ __launch_bounds__(256) void gather_src_kernel(const ushort_t* emb_bf, const int* source,
                                                         ushort_t* xs_bf) {
  int gid = blockIdx.x * 256 + threadIdx.x;  // 6400*32 = 204800
  int r = gid >> 5;
  int e = gid & 31;
  int s = r >> 4, b = r & 15;
  int tok = source[b * S_SZ + s];
  ((ushort8_t*)xs_bf)[gid] = ((const ushort8_t*)emb_bf)[(size_t)tok * 32 + e];
}

// ---------------- MFMA helper: one wave computes a 16x64 tile of A(M,K) @ B(N,K)^T ----------------
__device__ __forceinline__ void mfma_16x64(const ushort_t* A, const ushort_t* B_, int K,
                                           int m0, int n0, f32x4 acc[4]) {
  const int lane = threadIdx.x & 63;
  const int lr = lane & 15, kh = lane >> 4;
  const ushort_t* ap = A + (size_t)(m0 + lr) * K + kh * 8;
  const ushort_t* bp = B_ + (size_t)(n0 + lr) * K + kh * 8;
  for (int k0 = 0; k0 < K; k0 += 32) {
    bf16x8 av = *(const bf16x8*)(ap + k0);
#pragma unroll
    for (int s = 0; s < 4; ++s) {
      bf16x8 bv = *(const bf16x8*)(bp + (size_t)s * 16 * K + k0);
      acc[s] = __builtin_amdgcn_mfma_f32_16x16x32_bf16(av, bv, acc[s], 0, 0, 0);
    }
  }
}

// ---------------- K1: gates_x = xs @ Wih^T + b  (both directions via blockIdx.z) ----------------
__global__ __launch_bounds__(256) void gemm_gates(const ushort_t* xs_bf, const ushort_t* wihf_bf,
                                                  const ushort_t* wihb_bf, const float* bias_f,
                                                  const float* bias_b, float* gx_f, float* gx_b) {
  int wave = threadIdx.x >> 6;
  int m0 = blockIdx.y * 16;
  int n0 = blockIdx.x * 256 + wave * 64;
  const ushort_t* B_ = blockIdx.z ? wihb_bf : wihf_bf;
  const float* bias = blockIdx.z ? bias_b : bias_f;
  float* out = blockIdx.z ? gx_b : gx_f;
  f32x4 acc[4] = {};
  mfma_16x64(xs_bf, B_, D_SZ, m0, n0, acc);
  int lane = threadIdx.x & 63, lr = lane & 15, kh = lane >> 4;
#pragma unroll
  for (int s = 0; s < 4; ++s) {
    int n = n0 + s * 16 + lr;
    float bv = bias[n];
#pragma unroll
    for (int i = 0; i < 4; ++i) {
      int m = m0 + kh * 4 + i;
      out[(size_t)m * G4 + n] = acc[s][i] + bv;
    }
  }
}

// ---------------- K3a: enc_outs = ys_cat @ Wproj^T + bproj, out layout [b][s][h] ----------------
__global__ __launch_bounds__(256) void gemm_encout(const ushort_t* ys_cat, const ushort_t* wproj_bf,
                                                   const float* bproj, float* enc_outs) {
  int wave = threadIdx.x >> 6;
  int m0 = blockIdx.y * 16;
  int n0 = blockIdx.x * 256 + wave * 64;
  f32x4 acc[4] = {};
  mfma_16x64(ys_cat, wproj_bf, 2 * H_SZ, m0, n0, acc);
  int lane = threadIdx.x & 63, lr = lane & 15, kh = lane >> 4;
#pragma unroll
  for (int s = 0; s < 4; ++s) {
    int n = n0 + s * 16 + lr;
    float bv = bproj[n];
#pragma unroll
    for (int i = 0; i < 4; ++i) {
      int m = m0 + kh * 4 + i;
      int b = m & 15, si = m >> 4;
      enc_outs[((size_t)b * S_SZ + si) * H_SZ + n] = acc[s][i] + bv;
    }
  }
}

// ---------------- K5: logits = dec_out @ emb^T, written into d_out cols [0,V) ----------------
__global__ __launch_bounds__(256) void gemm_logits(const ushort_t* dec_out_bf, const ushort_t* emb_bf,
                                                   float* out) {
  int wave = threadIdx.x >> 6;
  int m0 = blockIdx.x * 16;             // m fast-varying -> emb tile reuse in L2
  int n0 = blockIdx.y * 256 + wave * 64;
  f32x4 acc[4] = {};
  mfma_16x64(dec_out_bf, emb_bf, D_SZ, m0, n0, acc);
  int lane = threadIdx.x & 63, lr = lane & 15, kh = lane >> 4;
#pragma unroll
  for (int s = 0; s < 4; ++s) {
    int n = n0 + s * 16 + lr;
#pragma unroll
    for (int i = 0; i < 4; ++i) {
      int m = m0 + kh * 4 + i;
      out[(size_t)m * VX + n] = acc[s][i];
    }
  }
}

// ---------------- K2: persistent bidirectional encoder LSTM ----------------
// 256 blocks: blocks [0,128) forward, [128,256) backward; block owns 4 hidden units.
// h_hist[dir][t][b][j], write-once per t. ys_cat bf16 rows m=s*16+b, cols [dir*512 + j].
__global__ __launch_bounds__(256) void enc_kernel(const float* gx_f, const float* gx_b,
                                                  const float* whh_f, const float* whh_b,
                                                  const int* src_len, float* h_hist,
                                                  ushort_t* ys_cat, float* h_final, float* c_final,
                                                  int* flags) {
  __shared__ f32x4 h_s4[16 * 129];
  __shared__ float gates_s[16 * 17];
  float* h_s = (float*)h_s4;

  const int blk = blockIdx.x;
  const int dir = blk >> 7;
  const int ub = blk & 127;
  const int j0 = ub * 4;
  const int tid = threadIdx.x;
  const int b = tid & 15;
  const int q = tid >> 4;
  const int jj = q >> 2, g = q & 3;
  const int row = g * H_SZ + j0 + jj;
  const float* gx = dir ? gx_b : gx_f;
  const float* whh = dir ? whh_b : whh_f;
  const f32x4* wr = (const f32x4*)(whh + (size_t)row * H_SZ);
  float* hh = h_hist + (size_t)dir * (S_SZ + 1) * (B_SZ * H_SZ);
  const int len_b = src_len[b];
  const bool owner = tid < 64;
  const int ob = tid & 15, ojj = tid >> 4;  // valid for owners
  float c_reg = 0.0f;
  const f32x4 zv = {0.0f, 0.0f, 0.0f, 0.0f};

  for (int t = 0; t < S_SZ; ++t) {
    const int s_pos = dir ? (S_SZ - 1 - t) : t;
    // stage h_prev (16x512 f32) into padded LDS
    const f32x4* hsrc = (const f32x4*)(hh + (size_t)t * (B_SZ * H_SZ));
    for (int i = tid; i < 2048; i += 256) {
      f32x4 v = (t == 0) ? zv : hsrc[i];
      h_s4[i + (i >> 7)] = v;
    }
    __syncthreads();
    // gate dot: gates_x + h_prev . Whh[row]
    float gxv = gx[(size_t)s_pos * (B_SZ * G4) + b * G4 + row];
    const f32x4* hr = h_s4 + b * 129;
    float a0 = 0, a1 = 0, a2 = 0, a3 = 0;
#pragma unroll 4
    for (int k = 0; k < 128; k += 4) {
      a0 += dot4(hr[k], wr[k]);
      a1 += dot4(hr[k + 1], wr[k + 1]);
      a2 += dot4(hr[k + 2], wr[k + 2]);
      a3 += dot4(hr[k + 3], wr[k + 3]);
    }
    gates_s[q * 17 + b] = gxv + ((a0 + a1) + (a2 + a3));
    __syncthreads();
    if (owner) {
      const int j = j0 + ojj;
      float gi = gates_s[(ojj * 4 + 0) * 17 + ob];
      float gf = gates_s[(ojj * 4 + 1) * 17 + ob];
      float gg = gates_s[(ojj * 4 + 2) * 17 + ob];
      float go = gates_s[(ojj * 4 + 3) * 17 + ob];
      bool msk = s_pos < len_b;
      float cn = sigf(gf) * c_reg + sigf(gi) * tanh_f(gg);
      float hn = sigf(go) * tanh_f(cn);
      float hprev = (t == 0) ? 0.0f : h_s[ob * 516 + j];
      float hout = msk ? hn : hprev;
      if (msk) c_reg = cn;
      hh[(size_t)(t + 1) * (B_SZ * H_SZ) + ob * 512 + j] = hout;
      ys_cat[(size_t)(s_pos * 16 + ob) * (2 * H_SZ) + dir * 512 + j] = msk ? f2bf(hn) : (ushort_t)0;
      if (t == S_SZ - 1) {
        h_final[dir * 8192 + ob * 512 + j] = hout;
        c_final[dir * 8192 + ob * 512 + j] = c_reg;
      }
    }
    barrier_flags(flags, NB_ENC, t + 1);
  }
}

// ---------------- seq_mean ----------------
__global__ __launch_bounds__(256) void seqmean_kernel(const float* enc_outs, const int* src_len,
                                                      float* seq_mean) {
  int b = blockIdx.x >> 1;
  int j = (blockIdx.x & 1) * 256 + threadIdx.x;
  int L = src_len[b];
  float a = 0;
  for (int s = 0; s < L; ++s) a += enc_outs[((size_t)b * S_SZ + s) * H_SZ + j];
  seq_mean[b * 512 + j] = a / (float)L;
}

// ---------------- dec_h / dec_c init ----------------
__global__ __launch_bounds__(256) void init_state_kernel(const float* h_final, const float* c_final,
                                                         const float* w2h, const float* b2h,
                                                         const float* w2c, const float* b2c,
                                                         float* h_dec0, float* c_init) {
  int gid = blockIdx.x * 256 + threadIdx.x;  // 16384
  int half = gid >> 13;
  int idx = gid & 8191;
  int b = idx >> 9, j = idx & 511;
  const float* src = half ? c_final : h_final;
  const float* w = (half ? w2c : w2h) + (size_t)j * 1024;
  float acc = (half ? b2c : b2h)[j];
  const f32x4* s0 = (const f32x4*)(src + b * 512);
  const f32x4* s1 = (const f32x4*)(src + 8192 + b * 512);
  const f32x4* w0 = (const f32x4*)w;
  const f32x4* w1 = w0 + 128;
  float a = 0;
  for (int k = 0; k < 128; ++k) a += dot4(s0[k], w0[k]);
  for (int k = 0; k < 128; ++k) a += dot4(s1[k], w1[k]);
  acc += a;
  if (half) c_init[idx] = acc; else h_dec0[idx] = acc;
}

// ---------------- tmp0 = tanh([dec_h | seq_mean] @ Wo1^T + bo1) ----------------
__global__ __launch_bounds__(256) void tmp0_kernel(const float* h_dec0, const float* seq_mean,
                                                   const float* wo1, const float* bo1, float* tmp0) {
  int gid = blockIdx.x * 256 + threadIdx.x;  // 8192
  int b = gid >> 9, j = gid & 511;
  const f32x4* x0 = (const f32x4*)(h_dec0 + b * 512);
  const f32x4* x1 = (const f32x4*)(seq_mean + b * 512);
  const f32x4* w0 = (const f32x4*)(wo1 + (size_t)j * 1024);
  const f32x4* w1 = w0 + 128;
  float a = bo1[j];
  float p = 0;
  for (int k = 0; k < 128; ++k) p += dot4(x0[k], w0[k]);
  for (int k = 0; k < 128; ++k) p += dot4(x1[k], w1[k]);
  tmp0[gid] = tanh_f(a + p);
}

// ---------------- dec_out0 = tmp0 @ Wo2^T ----------------
__global__ __launch_bounds__(256) void decout0_kernel(const float* tmp0, const float* wo2,
                                                      float* dec_out0) {
  int gid = blockIdx.x * 256 + threadIdx.x;  // 4096
  int b = gid >> 8, d = gid & 255;
  const f32x4* x0 = (const f32x4*)(tmp0 + b * 512);
  const f32x4* w0 = (const f32x4*)(wo2 + (size_t)d * 512);
  float a = 0;
  for (int k = 0; k < 128; ++k) a += dot4(x0[k], w0[k]);
  dec_out0[gid] = a;
}

// ---------------- K4: persistent decoder (100 steps x 5 phases) ----------------
__global__ __launch_bounds__(256) void dec_kernel(
    const float* emb, const int* target, const int* src_len, const float* dwih, const float* dwhh,
    const float* dbias, const float* wpgen, const float* bpgen, const float* wo1, const float* bo1,
    const float* wo2, const float* enc_outs, float* h_dec, const float* c_init, float* dec_out_f,
    ushort_t* dec_out_bf, float* tmp_dec, float* ctx_part, float* ctx_f, float* z_part, float* zinv,
    float* pgen_o, float* pexp, int* flags) {
  __shared__ f32x4 xh_s4[16 * 257];
  __shared__ float gates_s[16 * 17];
  __shared__ float red_s[256];
  __shared__ float p_s[64];
  float* xh_s = (float*)xh_s4;

  const int blk = blockIdx.x, tid = threadIdx.x;
  // PA decomposition: block owns 4 hidden units
  const int j0 = blk * 4;
  const int b_a = tid & 15, q = tid >> 4, jj = q >> 2, g = q & 3;
  const int row = g * H_SZ + j0 + jj;
  const bool owner = tid < 64;
  const int ob = tid & 15, ojj = tid >> 4;
  float c_reg = owner ? c_init[ob * 512 + j0 + ojj] : 0.0f;
  const float bias_row = dbias[row];
  const f32x4* w1r = (const f32x4*)(dwih + (size_t)row * 512);
  const f32x4* w2r = (const f32x4*)(dwhh + (size_t)row * 512);
  // PB decomposition
  const int b_pb = blk >> 3, ch = blk & 7, s0c = (blk & 7) * 50;
  const int len_pb = src_len[b_pb];
  // PD / PE decomposition
  const int b_pd = blk >> 3, nc = blk & 7;
  int pc = 0;

  for (int t = 0; t < T_SZ; ++t) {
    // ---------- PA: gates + (h,c) update ----------
    {
      for (int i = tid; i < 4096; i += 256) {
        int bb = i >> 8, r = i & 255;
        f32x4 v;
        if (r < 64) {
          int tok = target[bb * T_SZ + t];
          v = ((const f32x4*)(emb + (size_t)tok * 256))[r];
        } else if (r < 128) {
          v = ((const f32x4*)(dec_out_f + (size_t)t * 4096 + bb * 256))[r - 64];
        } else {
          v = ((const f32x4*)(h_dec + (size_t)t * 8192 + bb * 512))[r - 128];
        }
        xh_s4[bb * 257 + r] = v;
      }
      __syncthreads();
      const f32x4* xr = xh_s4 + b_a * 257;
      float a0 = 0, a1 = 0, a2 = 0, a3 = 0;
#pragma unroll 4
      for (int k = 0; k < 128; k += 4) {
        a0 += dot4(xr[k], w1r[k]);
        a1 += dot4(xr[k + 1], w1r[k + 1]);
        a2 += dot4(xr[k + 2], w1r[k + 2]);
        a3 += dot4(xr[k + 3], w1r[k + 3]);
      }
#pragma unroll 4
      for (int k = 0; k < 128; k += 4) {
        a0 += dot4(xr[128 + k], w2r[k]);
        a1 += dot4(xr[128 + k + 1], w2r[k + 1]);
        a2 += dot4(xr[128 + k + 2], w2r[k + 2]);
        a3 += dot4(xr[128 + k + 3], w2r[k + 3]);
      }
      gates_s[q * 17 + b_a] = bias_row + ((a0 + a1) + (a2 + a3));
      __syncthreads();
      if (owner) {
        float gi = gates_s[(ojj * 4 + 0) * 17 + ob];
        float gf = gates_s[(ojj * 4 + 1) * 17 + ob];
        float gg = gates_s[(ojj * 4 + 2) * 17 + ob];
        float go = gates_s[(ojj * 4 + 3) * 17 + ob];
        float cn = sigf(gf) * c_reg + sigf(gi) * tanh_f(gg);
        c_reg = cn;
        float hn = sigf(go) * tanh_f(cn);
        h_dec[(size_t)(t + 1) * 8192 + ob * 512 + j0 + ojj] = hn;
      }
    }
    barrier_flags(flags, NB_DEC, ++pc);
    // ---------- PB: score chunks -> pexp, Z_part, ctx_part ----------
    {
      if (tid < 128)
        xh_s4[tid] = ((const f32x4*)(h_dec + (size_t)(t + 1) * 8192 + b_pb * 512))[tid];
      __syncthreads();
      int st = tid >> 2, kq = tid & 3;
      if (st < 50) {
        const f32x4* er = (const f32x4*)(enc_outs + ((size_t)b_pb * S_SZ + s0c + st) * H_SZ) + kq * 32;
        const f32x4* hr = xh_s4 + kq * 32;
        float sc = 0;
        for (int k = 0; k < 32; ++k) sc += dot4(hr[k], er[k]);
        sc += __shfl_xor(sc, 1);
        sc += __shfl_xor(sc, 2);
        if (kq == 0) {
          int s_abs = s0c + st;
          float p = (s_abs < len_pb) ? __expf(sc) : 0.0f;
          p_s[st] = p;
          pexp[((size_t)t * 16 + b_pb) * S_SZ + s_abs] = p;
        }
      }
      __syncthreads();
      if (tid == 0) {
        float z = 0;
        for (int s = 0; s < 50; ++s) z += p_s[s];
        z_part[((size_t)t * 16 + b_pb) * 8 + ch] = z;
      }
      float a0 = 0, a1 = 0;
      for (int s = 0; s < 50; ++s) {
        float p = p_s[s];
        const float* er = enc_outs + ((size_t)b_pb * S_SZ + s0c + s) * H_SZ;
        a0 += p * er[tid];
        a1 += p * er[tid + 256];
      }
      float* cp = ctx_part + (((size_t)t * 16 + b_pb) * 8 + ch) * 512;
      cp[tid] = a0;
      cp[tid + 256] = a1;
    }
    barrier_flags(flags, NB_DEC, ++pc);
    // ---------- PC: combine ctx, Zinv, p_gen ----------
    if (blk < 16) {
      int bb = blk;
      const float* zp = z_part + ((size_t)t * 16 + bb) * 8;
      if (tid == 0) {
        float z = 0;
        for (int c2 = 0; c2 < 8; ++c2) z += zp[c2];
        red_s[0] = 1.0f / z;
      }
      __syncthreads();
      float inv = red_s[0];
      const float* cpb = ctx_part + ((size_t)t * 16 + bb) * 8 * 512;
      float c0 = 0, c1 = 0;
      for (int c2 = 0; c2 < 8; ++c2) {
        c0 += cpb[c2 * 512 + tid];
        c1 += cpb[c2 * 512 + tid + 256];
      }
      c0 *= inv;
      c1 *= inv;
      float* cf = ctx_f + ((size_t)t * 16 + bb) * 512;
      cf[tid] = c0;
      cf[tid + 256] = c1;
      xh_s[tid] = c0;
      xh_s[tid + 256] = c1;
      if (tid == 0) zinv[t * 16 + bb] = inv;
      __syncthreads();
      // p_gen dot over [ctx(512), h(512), x_t(256), dec_out(256)]
      float pg = 0;
      for (int r6 = 0; r6 < 6; ++r6) {
        int k = r6 * 256 + tid;
        float v;
        if (k < 512) v = xh_s[k];
        else if (k < 1024) v = h_dec[(size_t)(t + 1) * 8192 + bb * 512 + (k - 512)];
        else if (k < 1280) {
          int tok = target[bb * T_SZ + t];
          v = emb[(size_t)tok * 256 + (k - 1024)];
        } else v = dec_out_f[(size_t)t * 4096 + bb * 256 + (k - 1280)];
        pg += v * wpgen[k];
      }
      red_s[tid] = pg;
      __syncthreads();
      for (int o2 = 128; o2 > 0; o2 >>= 1) {
        if (tid < o2) red_s[tid] += red_s[tid + o2];
        __syncthreads();
      }
      if (tid == 0) pgen_o[t * 16 + bb] = sigf(red_s[0] + bpgen[0]);
    }
    barrier_flags(flags, NB_DEC, ++pc);
    // ---------- PD: tmp = tanh([h | ctx] @ Wo1^T + bo1) ----------
    {
      if (tid < 128)
        xh_s4[tid] = ((const f32x4*)(h_dec + (size_t)(t + 1) * 8192 + b_pd * 512))[tid];
      else
        xh_s4[tid] = ((const f32x4*)(ctx_f + ((size_t)t * 16 + b_pd) * 512))[tid - 128];
      __syncthreads();
      int nidx = tid >> 2, kq = tid & 3;
      int n = nc * 64 + nidx;
      const f32x4* wrp = (const f32x4*)(wo1 + (size_t)n * 1024) + kq * 64;
      const f32x4* xr2 = xh_s4 + kq * 64;
      float a = 0;
#pragma unroll 4
      for (int k = 0; k < 64; ++k) a += dot4(xr2[k], wrp[k]);
      a += __shfl_xor(a, 1);
      a += __shfl_xor(a, 2);
      if (kq == 0) tmp_dec[((size_t)t * 16 + b_pd) * 512 + n] = tanh_f(a + bo1[n]);
    }
    barrier_flags(flags, NB_DEC, ++pc);
    // ---------- PE: dec_out = tmp @ Wo2^T ----------
    {
      if (tid < 128)
        xh_s4[tid] = ((const f32x4*)(tmp_dec + ((size_t)t * 16 + b_pd) * 512))[tid];
      __syncthreads();
      int didx = tid >> 3, kq = tid & 7;
      int d = nc * 32 + didx;
      const f32x4* wrp = (const f32x4*)(wo2 + (size_t)d * 512) + kq * 16;
      const f32x4* xr2 = xh_s4 + kq * 16;
      float a = 0;
#pragma unroll 4
      for (int k = 0; k < 16; ++k) a += dot4(xr2[k], wrp[k]);
      a += __shfl_xor(a, 1);
      a += __shfl_xor(a, 2);
      a += __shfl_xor(a, 4);
      if (kq == 0) {
        dec_out_f[(size_t)(t + 1) * 4096 + b_pd * 256 + d] = a;
        dec_out_bf[((size_t)t * 16 + b_pd) * 256 + d] = f2bf(a);
      }
    }
    barrier_flags(flags, NB_DEC, ++pc);
  }
}

// ---------------- K6: per (t,b) row softmax + copy-scatter + log ----------------
__global__ __launch_bounds__(1024) void finalize_kernel(float* out, const float* pexp,
                                                        const float* zinv, const float* pgen_i,
                                                        const int* src_ext) {
  __shared__ float scat[VX];
  __shared__ float red[64];
  const int row = blockIdx.x;
  const int b = row & 15;
  const int tid = threadIdx.x;
  for (int i = tid; i < VX; i += 1024) scat[i] = 0.0f;
  __syncthreads();
  const float pg = pgen_i[row];
  const float inv = zinv[row];
  if (tid < S_SZ) {
    float v = (1.0f - pg) * pexp[(size_t)row * S_SZ + tid] * inv;
    int col = src_ext[b * S_SZ + tid];
    atomicAdd(&scat[col], v);
  }
  float* orow = out + (size_t)row * VX;
  float l[32];
  float mx = -3.4e38f;
#pragma unroll
  for (int i2 = 0; i2 < 32; ++i2) {
    int col = tid + (i2 << 10);
    l[i2] = (col < V_SZ) ? orow[col] : -3.4e38f;
    mx = fmaxf(mx, l[i2]);
  }
#pragma unroll
  for (int o = 32; o; o >>= 1) mx = fmaxf(mx, __shfl_xor(mx, o));
  if ((tid & 63) == 0) red[16 + (tid >> 6)] = mx;
  __syncthreads();
  if (tid == 0) {
    float m2 = red[16];
    for (int w = 1; w < 16; ++w) m2 = fmaxf(m2, red[16 + w]);
    red[0] = m2;
  }
  __syncthreads();
  const float gmx = red[0];
  float se = 0.0f;
#pragma unroll
  for (int i2 = 0; i2 < 32; ++i2) {
    int col = tid + (i2 << 10);
    if (col < V_SZ) {
      l[i2] = __expf(l[i2] - gmx);
      se += l[i2];
    }
  }
#pragma unroll
  for (int o = 32; o; o >>= 1) se += __shfl_xor(se, o);
  if ((tid & 63) == 0) red[32 + (tid >> 6)] = se;
  __syncthreads();
  if (tid == 0) {
    float s2 = 0;
    for (int w = 0; w < 16; ++w) s2 += red[32 + w];
    red[1] = s2;
  }
  __syncthreads();
  const float scale = pg / red[1];
#pragma unroll
  for (int i2 = 0; i2 < 32; ++i2) {
    int col = tid + (i2 << 10);
    if (col < VX) {
      float base = (col < V_SZ) ? l[i2] * scale : 0.0f;
      orow[col] = __logf(base + scat[col] + 1e-20f);
    }
  }
}

extern "C" void kernel_launch(void* const* d_in, const int* in_sizes, int n_in, void* d_out,
                              int out_size, void* d_ws, size_t ws_size, hipStream_t stream) {
  (void)in_sizes; (void)n_in; (void)out_size; (void)ws_size;
  const int* source = (const int*)d_in[0];
  const int* source_ext = (const int*)d_in[1];
  const int* source_len = (const int*)d_in[2];
  const int* target = (const int*)d_in[3];
  const float* emb = (const float*)d_in[4];
  const float* wih_f = (const float*)d_in[5];
  const float* whh_f = (const float*)d_in[6];
  const float* b_f = (const float*)d_in[7];
  const float* wih_b = (const float*)d_in[8];
  const float* whh_b = (const float*)d_in[9];
  const float* b_b = (const float*)d_in[10];
  const float* wproj = (const float*)d_in[11];
  const float* bproj = (const float*)d_in[12];
  const float* w2h = (const float*)d_in[13];
  const float* b2h = (const float*)d_in[14];
  const float* w2c = (const float*)d_in[15];
  const float* b2c = (const float*)d_in[16];
  const float* wo1 = (const float*)d_in[17];
  const float* bo1 = (const float*)d_in[18];
  const float* wo2 = (const float*)d_in[19];
  const float* dwih = (const float*)d_in[20];
  const float* dwhh = (const float*)d_in[21];
  const float* dbias = (const float*)d_in[22];
  const float* wpgen = (const float*)d_in[23];
  const float* bpgen = (const float*)d_in[24];
  float* out = (float*)d_out;

  size_t off = 0;
  char* wsb = (char*)d_ws;
  auto alloc = [&](size_t bytes) -> void* {
    void* p = wsb + off;
    off += (bytes + 255) & ~(size_t)255;
    return p;
  };
  int* flags_enc = (int*)alloc(NB_ENC * 4);
  int* flags_dec = (int*)alloc(NB_DEC * 4);
  ushort_t* emb_bf = (ushort_t*)alloc((size_t)V_SZ * D_SZ * 2);
  ushort_t* wihf_bf = (ushort_t*)alloc((size_t)G4 * D_SZ * 2);
  ushort_t* wihb_bf = (ushort_t*)alloc((size_t)G4 * D_SZ * 2);
  ushort_t* wproj_bf = (ushort_t*)alloc((size_t)H_SZ * 2 * H_SZ * 2);
  ushort_t* xs_bf = (ushort_t*)alloc((size_t)S_SZ * B_SZ * D_SZ * 2);
  float* gx_f = (float*)alloc((size_t)S_SZ * B_SZ * G4 * 4);
  float* gx_b = (float*)alloc((size_t)S_SZ * B_SZ * G4 * 4);
  float* h_hist = (float*)alloc((size_t)2 * (S_SZ + 1) * B_SZ * H_SZ * 4);
  ushort_t* ys_cat = (ushort_t*)alloc((size_t)S_SZ * B_SZ * 2 * H_SZ * 2);
  float* h_final = (float*)alloc((size_t)2 * B_SZ * H_SZ * 4);
  float* c_final = (float*)alloc((size_t)2 * B_SZ * H_SZ * 4);
  float* enc_outs = (float*)alloc((size_t)B_SZ * S_SZ * H_SZ * 4);
  float* seq_mean = (float*)alloc((size_t)B_SZ * H_SZ * 4);
  float* h_dec = (float*)alloc((size_t)(T_SZ + 1) * B_SZ * H_SZ * 4);
  float* c_init = (float*)alloc((size_t)B_SZ * H_SZ * 4);
  float* dec_out_f = (float*)alloc((size_t)(T_SZ + 1) * B_SZ * D_SZ * 4);
  ushort_t* dec_out_bf = (ushort_t*)alloc((size_t)T_SZ * B_SZ * D_SZ * 2);
  float* tmp0 = (float*)alloc((size_t)B_SZ * H_SZ * 4);
  float* tmp_dec = (float*)alloc((size_t)T_SZ * B_SZ * H_SZ * 4);
  float* ctx_part = (float*)alloc((size_t)T_SZ * B_SZ * 8 * H_SZ * 4);
  float* ctx_f = (float*)alloc((size_t)T_SZ * B_SZ * H_SZ * 4);
  float* z_part = (float*)alloc((size_t)T_SZ * B_SZ * 8 * 4);
  float* zinv = (float*)alloc((size_t)T_SZ * B_SZ * 4);
  float* pgen_b = (float*)alloc((size_t)T_SZ * B_SZ * 4);
  float* pexp = (float*)alloc((size_t)T_SZ * B_SZ * S_SZ * 4);

  hipMemsetAsync(d_ws, 0, 4096, stream);

  cvt_kernel<<<2048, 256, 0, stream>>>(emb, emb_bf, V_SZ * D_SZ);
  cvt_kernel<<<2048, 256, 0, stream>>>(wih_f, wihf_bf, G4 * D_SZ);
  cvt_kernel<<<2048, 256, 0, stream>>>(wih_b, wihb_bf, G4 * D_SZ);
  cvt_kernel<<<2048, 256, 0, stream>>>(wproj, wproj_bf, H_SZ * 2 * H_SZ);
  gather_src_kernel<<<800, 256, 0, stream>>>(emb_bf, source, xs_bf);
  gemm_gates<<<dim3(8, 400, 2), 256, 0, stream>>>(xs_bf, wihf_bf, wihb_bf, b_f, b_b, gx_f, gx_b);
  enc_kernel<<<NB_ENC, 256, 0, stream>>>(gx_f, gx_b, whh_f, whh_b, source_len, h_hist, ys_cat,
                                         h_final, c_final, flags_enc);
  gemm_encout<<<dim3(2, 400), 256, 0, stream>>>(ys_cat, wproj_bf, bproj, enc_outs);
  seqmean_kernel<<<32, 256, 0, stream>>>(enc_outs, source_len, seq_mean);
  init_state_kernel<<<64, 256, 0, stream>>>(h_final, c_final, w2h, b2h, w2c, b2c, h_dec, c_init);
  tmp0_kernel<<<32, 256, 0, stream>>>(h_dec, seq_mean, wo1, bo1, tmp0);
  decout0_kernel<<<16, 256, 0, stream>>>(tmp0, wo2, dec_out_f);
  dec_kernel<<<NB_DEC, 256, 0, stream>>>(emb, target, source_len, dwih, dwhh, dbias, wpgen, bpgen,
                                         wo1, bo1, wo2, enc_outs, h_dec, c_init, dec_out_f,
                                         dec_out_bf, tmp_dec, ctx_part, ctx_f, z_part, zinv, pgen_b,
                                         pexp, flags_dec);
  gemm_logits<<<dim3(100, 125), 256, 0, stream>>>(dec_out_bf, emb_bf, out);
  finalize_kernel<<<1600, 1024, 0, stream>>>(out, pexp, zinv, pgen_b, source_ext);
}

// Round 2
// 11305.035 us; speedup vs baseline: 1.3267x; 1.3267x over previous
//
#include <hip/hip_runtime.h>

#define V_SZ 32000
#define D_SZ 256
#define H_SZ 512
#define B_SZ 16
#define S_SZ 400
#define T_SZ 100
#define NX   50
#define G4   2048
#define VX   32050
#define NB_ENC 256
#define NB_DEC 128

typedef unsigned short ushort_t;
typedef __attribute__((ext_vector_type(8))) __bf16 bf16x8;
typedef __attribute__((ext_vector_type(8))) unsigned short ushort8_t;
typedef __attribute__((ext_vector_type(4))) float f32x4;

__device__ __forceinline__ ushort_t f2bf(float x) {
  union { float f; unsigned u; } v; v.f = x;
  unsigned r = v.u + 0x7fffu + ((v.u >> 16) & 1u);
  return (ushort_t)(r >> 16);
}
__device__ __forceinline__ float sigf(float x) { return 1.0f / (1.0f + __expf(-x)); }
__device__ __forceinline__ float tanh_f(float x) {
  float e = __expf(2.0f * x);
  return 1.0f - 2.0f / (e + 1.0f);
}
__device__ __forceinline__ float dot4(f32x4 a, f32x4 b) {
  return a.x * b.x + a.y * b.y + a.z * b.z + a.w * b.w;
}
// write-through store to the device coherence point (global_store ... sc0 sc1):
// no wbl2 needed at the barrier, readers' cold misses fetch fresh data.
__device__ __forceinline__ void stg(float* p, float v) {
  __hip_atomic_store(p, v, __ATOMIC_RELAXED, __HIP_MEMORY_SCOPE_AGENT);
}

// Grid barrier via per-block flags, monotonic phase counter. Data written with
// stg() is already at the coherence point; __syncthreads() drains each wave's
// vmcnt before s_barrier, so a relaxed flag store suffices (no buffer_wbl2).
__device__ __forceinline__ void barrier_flags(int* flags, int base, int nf, int pc) {
  __syncthreads();
  asm volatile("s_waitcnt vmcnt(0)" ::: "memory");
  if (threadIdx.x == 0)
    __hip_atomic_store(&flags[blockIdx.x], pc, __ATOMIC_RELAXED, __HIP_MEMORY_SCOPE_AGENT);
  if ((int)threadIdx.x < nf) {
    while (__hip_atomic_load(&flags[base + threadIdx.x], __ATOMIC_RELAXED,
                             __HIP_MEMORY_SCOPE_AGENT) < pc)
      __builtin_amdgcn_s_sleep(1);
  }
  __syncthreads();
}

// ---------------- f32 -> bf16 convert ----------------
__global__ __launch_bounds__(256) void cvt_kernel(const float* in, ushort_t* outp, int n) {
  int i = blockIdx.x * 256 + threadIdx.x;
  int stride = gridDim.x * 256;
  for (; i < n; i += stride) outp[i] = f2bf(in[i]);
}

// cols [0,256) of a row-stride-512 matrix -> packed bf16 (2048 x 256)
__global__ __launch_bounds__(256) void cvt_strided_kernel(const float* in, ushort_t* outp) {
  int gid = blockIdx.x * 256 + threadIdx.x;  // 524288
  int r = gid >> 8, d = gid & 255;
  outp[gid] = f2bf(in[(size_t)r * 512 + d]);
}

// wo2t[h][d] = wo2[d][h]  (512 x 256 bf16)
__global__ __launch_bounds__(256) void cvt_wo2t_kernel(const float* wo2, ushort_t* outp) {
  int gid = blockIdx.x * 256 + threadIdx.x;  // 131072
  int h = gid >> 8, d = gid & 255;
  outp[gid] = f2bf(wo2[(size_t)d * 512 + h]);
}

// Wfused[r][c] = sum_d dwih[r][256+d] * wo2[d][c]   (2048 x 512 f32)
__global__ __launch_bounds__(256) void wfused_kernel(const float* dwih, const float* wo2,
                                                     float* wf) {
  __shared__ float xr_s[256];
  int r = blockIdx.x;
  xr_s[threadIdx.x] = dwih[(size_t)r * 512 + 256 + threadIdx.x];
  __syncthreads();
  float a0 = 0, a1 = 0;
  for (int d = 0; d < 256; ++d) {
    float x = xr_s[d];
    a0 += x * wo2[(size_t)d * 512 + threadIdx.x];
    a1 += x * wo2[(size_t)d * 512 + threadIdx.x + 256];
  }
  wf[(size_t)r * 512 + threadIdx.x] = a0;
  wf[(size_t)r * 512 + threadIdx.x + 256] = a1;
}

// wfp[h] = sum_d wpgen[1280+d] * wo2[d][h]   (512 f32)
__global__ __launch_bounds__(256) void wfp_kernel(const float* wpgen, const float* wo2,
                                                  float* wfp) {
  int h = blockIdx.x * 256 + threadIdx.x;  // 512
  float a = 0;
  for (int d = 0; d < 256; ++d) a += wpgen[1280 + d] * wo2[(size_t)d * 512 + h];
  wfp[h] = a;
}

// ---------------- gather embeddings (bf16) ----------------
__global__ __launch_bounds__(256) void gather_src_kernel(const ushort_t* emb_bf, const int* source,
                                                         ushort_t* xs_bf) {
  int gid = blockIdx.x * 256 + threadIdx.x;  // 204800
  int r = gid >> 5, e = gid & 31;
  int s = r >> 4, b = r & 15;
  int tok = source[b * S_SZ + s];
  ((ushort8_t*)xs_bf)[gid] = ((const ushort8_t*)emb_bf)[(size_t)tok * 32 + e];
}
__global__ __launch_bounds__(256) void gather_tgt_kernel(const ushort_t* emb_bf, const int* target,
                                                         ushort_t* xt_bf) {
  int gid = blockIdx.x * 256 + threadIdx.x;  // 51200
  int r = gid >> 5, e = gid & 31;
  int t = r >> 4, b = r & 15;
  int tok = target[b * T_SZ + t];
  ((ushort8_t*)xt_bf)[gid] = ((const ushort8_t*)emb_bf)[(size_t)tok * 32 + e];
}

// ---------------- MFMA helper: one wave computes a 16x64 tile of A(M,K) @ B(N,K)^T --------------
__device__ __forceinline__ void mfma_16x64(const ushort_t* A, const ushort_t* B_, int K,
                                           int m0, int n0, f32x4 acc[4]) {
  const int lane = threadIdx.x & 63;
  const int lr = lane & 15, kh = lane >> 4;
  const ushort_t* ap = A + (size_t)(m0 + lr) * K + kh * 8;
  const ushort_t* bp = B_ + (size_t)(n0 + lr) * K + kh * 8;
  for (int k0 = 0; k0 < K; k0 += 32) {
    bf16x8 av = *(const bf16x8*)(ap + k0);
#pragma unroll
    for (int s = 0; s < 4; ++s) {
      bf16x8 bv = *(const bf16x8*)(bp + (size_t)s * 16 * K + k0);
      acc[s] = __builtin_amdgcn_mfma_f32_16x16x32_bf16(av, bv, acc[s], 0, 0, 0);
    }
  }
}

// ---------------- generic gates GEMM: out[m][n] = A[m]·B[n] + bias[n], N=2048 ----------------
__global__ __launch_bounds__(256) void gemm_abt_bias(const ushort_t* A, const ushort_t* Bm,
                                                     const float* bias, float* out, int K) {
  int wave = threadIdx.x >> 6;
  int m0 = blockIdx.y * 16;
  int n0 = blockIdx.x * 256 + wave * 64;
  f32x4 acc[4] = {};
  mfma_16x64(A, Bm, K, m0, n0, acc);
  int lane = threadIdx.x & 63, lr = lane & 15, kh = lane >> 4;
#pragma unroll
  for (int s = 0; s < 4; ++s) {
    int n = n0 + s * 16 + lr;
    float bv = bias[n];
#pragma unroll
    for (int i = 0; i < 4; ++i) {
      int m = m0 + kh * 4 + i;
      out[(size_t)m * G4 + n] = acc[s][i] + bv;
    }
  }
}

// ---------------- enc_outs = ys_cat @ Wproj^T + bproj, out layout [b][s][h] ----------------
__global__ __launch_bounds__(256) void gemm_encout(const ushort_t* ys_cat, const ushort_t* wproj_bf,
                                                   const float* bproj, float* enc_outs) {
  int wave = threadIdx.x >> 6;
  int m0 = blockIdx.y * 16;
  int n0 = blockIdx.x * 256 + wave * 64;
  f32x4 acc[4] = {};
  mfma_16x64(ys_cat, wproj_bf, 2 * H_SZ, m0, n0, acc);
  int lane = threadIdx.x & 63, lr = lane & 15, kh = lane >> 4;
#pragma unroll
  for (int s = 0; s < 4; ++s) {
    int n = n0 + s * 16 + lr;
    float bv = bproj[n];
#pragma unroll
    for (int i = 0; i < 4; ++i) {
      int m = m0 + kh * 4 + i;
      int b = m & 15, si = m >> 4;
      enc_outs[((size_t)b * S_SZ + si) * H_SZ + n] = acc[s][i] + bv;
    }
  }
}

// ---------------- E2 = emb @ Wo2  (32000 x 512, bf16) ----------------
__global__ __launch_bounds__(256) void gemm_e2(const ushort_t* emb_bf, const ushort_t* wo2t_bf,
                                               ushort_t* e2) {
  int wave = threadIdx.x >> 6;
  int m0 = blockIdx.y * 16;
  int n0 = blockIdx.x * 256 + wave * 64;
  f32x4 acc[4] = {};
  mfma_16x64(emb_bf, wo2t_bf, 256, m0, n0, acc);
  int lane = threadIdx.x & 63, lr = lane & 15, kh = lane >> 4;
#pragma unroll
  for (int s = 0; s < 4; ++s) {
    int n = n0 + s * 16 + lr;
#pragma unroll
    for (int i = 0; i < 4; ++i) {
      int m = m0 + kh * 4 + i;
      e2[(size_t)m * 512 + n] = f2bf(acc[s][i]);
    }
  }
}

// ---------------- logits = tmp_bf @ E2^T  (K=512), into d_out cols [0,V) ----------------
__global__ __launch_bounds__(256) void gemm_logits(const ushort_t* tmp_bf, const ushort_t* e2_bf,
                                                   float* out) {
  int wave = threadIdx.x >> 6;
  int m0 = blockIdx.x * 16;
  int n0 = blockIdx.y * 256 + wave * 64;
  f32x4 acc[4] = {};
  mfma_16x64(tmp_bf, e2_bf, 512, m0, n0, acc);
  int lane = threadIdx.x & 63, lr = lane & 15, kh = lane >> 4;
#pragma unroll
  for (int s = 0; s < 4; ++s) {
    int n = n0 + s * 16 + lr;
#pragma unroll
    for (int i = 0; i < 4; ++i) {
      int m = m0 + kh * 4 + i;
      out[(size_t)m * VX + n] = acc[s][i];
    }
  }
}

// ---------------- persistent bidirectional encoder LSTM ----------------
__global__ __launch_bounds__(256) void enc_kernel(const float* gx_f, const float* gx_b,
                                                  const float* whh_f, const float* whh_b,
                                                  const int* src_len, float* h_hist,
                                                  ushort_t* ys_cat, float* h_final, float* c_final,
                                                  int* flags) {
  __shared__ f32x4 h_s4[16 * 129];
  __shared__ float gates_s[16 * 17];
  float* h_s = (float*)h_s4;

  const int blk = blockIdx.x;
  const int dir = blk >> 7;
  const int ub = blk & 127;
  const int j0 = ub * 4;
  const int tid = threadIdx.x;
  const int b = tid & 15;
  const int q = tid >> 4;
  const int jj = q >> 2, g = q & 3;
  const int row = g * H_SZ + j0 + jj;
  const float* gx = dir ? gx_b : gx_f;
  const float* whh = dir ? whh_b : whh_f;
  const f32x4* wr = (const f32x4*)(whh + (size_t)row * H_SZ);
  float* hh = h_hist + (size_t)dir * (S_SZ + 1) * (B_SZ * H_SZ);
  const int len_b = src_len[b];
  const bool owner = tid < 64;
  const int ob = tid & 15, ojj = tid >> 4;
  float c_reg = 0.0f;
  const f32x4 zv = {0.0f, 0.0f, 0.0f, 0.0f};

  for (int t = 0; t < S_SZ; ++t) {
    const int s_pos = dir ? (S_SZ - 1 - t) : t;
    const f32x4* hsrc = (const f32x4*)(hh + (size_t)t * (B_SZ * H_SZ));
    for (int i = tid; i < 2048; i += 256) {
      f32x4 v = (t == 0) ? zv : hsrc[i];
      h_s4[i + (i >> 7)] = v;
    }
    __syncthreads();
    float gxv = gx[(size_t)s_pos * (B_SZ * G4) + b * G4 + row];
    const f32x4* hr = h_s4 + b * 129;
    float a0 = 0, a1 = 0, a2 = 0, a3 = 0;
#pragma unroll 4
    for (int k = 0; k < 128; k += 4) {
      a0 += dot4(hr[k], wr[k]);
      a1 += dot4(hr[k + 1], wr[k + 1]);
      a2 += dot4(hr[k + 2], wr[k + 2]);
      a3 += dot4(hr[k + 3], wr[k + 3]);
    }
    gates_s[q * 17 + b] = gxv + ((a0 + a1) + (a2 + a3));
    __syncthreads();
    if (owner) {
      const int j = j0 + ojj;
      float gi = gates_s[(ojj * 4 + 0) * 17 + ob];
      float gf = gates_s[(ojj * 4 + 1) * 17 + ob];
      float gg = gates_s[(ojj * 4 + 2) * 17 + ob];
      float go = gates_s[(ojj * 4 + 3) * 17 + ob];
      bool msk = s_pos < len_b;
      float cn = sigf(gf) * c_reg + sigf(gi) * tanh_f(gg);
      float hn = sigf(go) * tanh_f(cn);
      float hprev = (t == 0) ? 0.0f : h_s[ob * 516 + j];
      float hout = msk ? hn : hprev;
      if (msk) c_reg = cn;
      stg(&hh[(size_t)(t + 1) * (B_SZ * H_SZ) + ob * 512 + j], hout);
      ys_cat[(size_t)(s_pos * 16 + ob) * (2 * H_SZ) + dir * 512 + j] = msk ? f2bf(hn) : (ushort_t)0;
      if (t == S_SZ - 1) {
        h_final[dir * 8192 + ob * 512 + j] = hout;
        c_final[dir * 8192 + ob * 512 + j] = c_reg;
      }
    }
    barrier_flags(flags, dir * 128, 128, t + 1);
  }
}

// ---------------- seq_mean ----------------
__global__ __launch_bounds__(256) void seqmean_kernel(const float* enc_outs, const int* src_len,
                                                      float* seq_mean) {
  int b = blockIdx.x >> 1;
  int j = (blockIdx.x & 1) * 256 + threadIdx.x;
  int L = src_len[b];
  float a = 0;
  for (int s = 0; s < L; ++s) a += enc_outs[((size_t)b * S_SZ + s) * H_SZ + j];
  seq_mean[b * 512 + j] = a / (float)L;
}

// ---------------- dec_h / dec_c init ----------------
__global__ __launch_bounds__(256) void init_state_kernel(const float* h_final, const float* c_final,
                                                         const float* w2h, const float* b2h,
                                                         const float* w2c, const float* b2c,
                                                         float* h_dec0, float* c_init) {
  int gid = blockIdx.x * 256 + threadIdx.x;  // 16384
  int half = gid >> 13;
  int idx = gid & 8191;
  int b = idx >> 9, j = idx & 511;
  const float* src = half ? c_final : h_final;
  const float* w = (half ? w2c : w2h) + (size_t)j * 1024;
  float acc = (half ? b2c : b2h)[j];
  const f32x4* s0 = (const f32x4*)(src + b * 512);
  const f32x4* s1 = (const f32x4*)(src + 8192 + b * 512);
  const f32x4* w0 = (const f32x4*)w;
  const f32x4* w1 = w0 + 128;
  float a = 0;
  for (int k = 0; k < 128; ++k) a += dot4(s0[k], w0[k]);
  for (int k = 0; k < 128; ++k) a += dot4(s1[k], w1[k]);
  acc += a;
  if (half) c_init[idx] = acc; else h_dec0[idx] = acc;
}

// ---------------- tmp0 = tanh([dec_h | seq_mean] @ Wo1^T + bo1) -> tmp_dec slot 0 -------------
__global__ __launch_bounds__(256) void tmp0_kernel(const float* h_dec0, const float* seq_mean,
                                                   const float* wo1, const float* bo1,
                                                   float* tmp_dec) {
  int gid = blockIdx.x * 256 + threadIdx.x;  // 8192
  int b = gid >> 9, j = gid & 511;
  const f32x4* x0 = (const f32x4*)(h_dec0 + b * 512);
  const f32x4* x1 = (const f32x4*)(seq_mean + b * 512);
  const f32x4* w0 = (const f32x4*)(wo1 + (size_t)j * 1024);
  const f32x4* w1 = w0 + 128;
  float a = bo1[j];
  float p = 0;
  for (int k = 0; k < 128; ++k) p += dot4(x0[k], w0[k]);
  for (int k = 0; k < 128; ++k) p += dot4(x1[k], w1[k]);
  tmp_dec[gid] = tanh_f(a + p);
}

// ---------------- persistent decoder: 100 steps x 3 phases ----------------
// PA: h_t = LSTMcell(gx_emb + h@Whh^T + tmp@Wfused^T)   [128 blocks x 16 gate rows]
// PB: score chunks (b, ch of 50) -> pexp, z_part, ctx_part
// PC: combine ctx + pgen + tmp_t = tanh([h|ctx]@Wo1^T+bo1)   [blocks (b, nc of 64 rows)]
__global__ __launch_bounds__(256) void dec_kernel(
    const float* emb, const int* target, const int* src_len, const float* dwhh,
    const float* wfused, const float* wpgen, const float* bpgen, const float* wfp,
    const float* wo1, const float* bo1, const float* enc_outs, const float* gx_dec,
    float* h_dec, const float* c_init, float* tmp_dec, ushort_t* tmp_bf, float* ctx_part,
    float* z_part, float* zinv, float* pgen_o, float* pexp, int* flags) {
  __shared__ f32x4 smem4[16 * 129];  // 33 KB staging / scratch
  __shared__ float gates_s[16 * 17];
  __shared__ float red_s[256];
  __shared__ float p_s[64];
  float* sm = (float*)smem4;

  const int blk = blockIdx.x, tid = threadIdx.x;
  // PA decomposition: block owns 4 hidden units (16 gate rows)
  const int j0 = blk * 4;
  const int b_a = tid & 15, q = tid >> 4, jj = q >> 2, g = q & 3;
  const int row = g * H_SZ + j0 + jj;
  const bool owner = tid < 64;
  const int ob = tid & 15, ojj = tid >> 4;
  float c_reg = owner ? c_init[ob * 512 + j0 + ojj] : 0.0f;
  const f32x4* w2r = (const f32x4*)(dwhh + (size_t)row * 512);
  const f32x4* wfr = (const f32x4*)(wfused + (size_t)row * 512);
  // PB decomposition
  const int b_pb = blk >> 3, ch = blk & 7, s0c = (blk & 7) * 50;
  const int len_pb = src_len[b_pb];
  // PC decomposition
  const int b_pc = blk >> 3, nc = blk & 7;
  int pc = 0;

  for (int t = 0; t < T_SZ; ++t) {
    // ---------- PA ----------
    {
      float a0 = 0, a1 = 0, a2 = 0, a3 = 0;
      // pass 1: h_{t-1}
      const f32x4* src = (const f32x4*)(h_dec + (size_t)t * 8192);
      for (int i = tid; i < 2048; i += 256)
        *(f32x4*)(sm + (i >> 7) * 516 + (i & 127) * 4) = src[i];
      __syncthreads();
      {
        const f32x4* xr = (const f32x4*)(sm + b_a * 516);
#pragma unroll 4
        for (int k = 0; k < 128; k += 4) {
          a0 += dot4(xr[k], w2r[k]);
          a1 += dot4(xr[k + 1], w2r[k + 1]);
          a2 += dot4(xr[k + 2], w2r[k + 2]);
          a3 += dot4(xr[k + 3], w2r[k + 3]);
        }
      }
      __syncthreads();
      // pass 2: tmp_{t-1}
      src = (const f32x4*)(tmp_dec + (size_t)t * 8192);
      for (int i = tid; i < 2048; i += 256)
        *(f32x4*)(sm + (i >> 7) * 516 + (i & 127) * 4) = src[i];
      __syncthreads();
      {
        const f32x4* xr = (const f32x4*)(sm + b_a * 516);
#pragma unroll 4
        for (int k = 0; k < 128; k += 4) {
          a0 += dot4(xr[k], wfr[k]);
          a1 += dot4(xr[k + 1], wfr[k + 1]);
          a2 += dot4(xr[k + 2], wfr[k + 2]);
          a3 += dot4(xr[k + 3], wfr[k + 3]);
        }
      }
      gates_s[q * 17 + b_a] =
          gx_dec[((size_t)t * 16 + b_a) * G4 + row] + ((a0 + a1) + (a2 + a3));
      __syncthreads();
      if (owner) {
        float gi = gates_s[(ojj * 4 + 0) * 17 + ob];
        float gf = gates_s[(ojj * 4 + 1) * 17 + ob];
        float gg = gates_s[(ojj * 4 + 2) * 17 + ob];
        float go = gates_s[(ojj * 4 + 3) * 17 + ob];
        float cn = sigf(gf) * c_reg + sigf(gi) * tanh_f(gg);
        c_reg = cn;
        float hn = sigf(go) * tanh_f(cn);
        stg(&h_dec[(size_t)(t + 1) * 8192 + ob * 512 + j0 + ojj], hn);
      }
    }
    barrier_flags(flags, 0, NB_DEC, ++pc);
    // ---------- PB ----------
    {
      if (tid < 128)
        ((f32x4*)sm)[tid] = ((const f32x4*)(h_dec + (size_t)(t + 1) * 8192 + b_pb * 512))[tid];
      __syncthreads();
      int st = tid >> 2, kq = tid & 3;
      if (st < 50) {
        const f32x4* er =
            (const f32x4*)(enc_outs + ((size_t)b_pb * S_SZ + s0c + st) * H_SZ) + kq * 32;
        const f32x4* hr = (const f32x4*)sm + kq * 32;
        float sc = 0;
        for (int k = 0; k < 32; ++k) sc += dot4(hr[k], er[k]);
        sc += __shfl_xor(sc, 1);
        sc += __shfl_xor(sc, 2);
        if (kq == 0) {
          int s_abs = s0c + st;
          float p = (s_abs < len_pb) ? __expf(sc) : 0.0f;
          p_s[st] = p;
          pexp[((size_t)t * 16 + b_pb) * S_SZ + s_abs] = p;
        }
      }
      __syncthreads();
      if (tid == 0) {
        float z = 0;
        for (int s = 0; s < 50; ++s) z += p_s[s];
        stg(&z_part[((size_t)t * 16 + b_pb) * 8 + ch], z);
      }
      float a0 = 0, a1 = 0;
      for (int s = 0; s < 50; ++s) {
        float p = p_s[s];
        const float* er = enc_outs + ((size_t)b_pb * S_SZ + s0c + s) * H_SZ;
        a0 += p * er[tid];
        a1 += p * er[tid + 256];
      }
      float* cp = ctx_part + (((size_t)t * 16 + b_pb) * 8 + ch) * 512;
      stg(&cp[tid], a0);
      stg(&cp[tid + 256], a1);
    }
    barrier_flags(flags, 0, NB_DEC, ++pc);
    // ---------- PC: combine ctx + pgen + tmp ----------
    {
      float* h_s = sm;            // 512 f32
      float* ctx_s = sm + 512;    // 512 f32
      const float* zp = z_part + ((size_t)t * 16 + b_pc) * 8;
      float z = 0;
#pragma unroll
      for (int c2 = 0; c2 < 8; ++c2) z += zp[c2];
      float inv = 1.0f / z;
      if (tid < 128)
        ((f32x4*)h_s)[tid] = ((const f32x4*)(h_dec + (size_t)(t + 1) * 8192 + b_pc * 512))[tid];
      const float* cpb = ctx_part + ((size_t)t * 16 + b_pc) * 8 * 512;
      float c0 = 0, c1 = 0;
#pragma unroll
      for (int c2 = 0; c2 < 8; ++c2) {
        c0 += cpb[c2 * 512 + tid];
        c1 += cpb[c2 * 512 + tid + 256];
      }
      ctx_s[tid] = c0 * inv;
      ctx_s[tid + 256] = c1 * inv;
      __syncthreads();
      // pgen partial (all blocks compute redundantly; nc==0 writes)
      int tok = target[b_pc * T_SZ + t];
      float tp0 = tmp_dec[(size_t)t * 8192 + b_pc * 512 + tid];
      float tp1 = tmp_dec[(size_t)t * 8192 + b_pc * 512 + tid + 256];
      float pg = wpgen[tid] * ctx_s[tid] + wpgen[tid + 256] * ctx_s[tid + 256] +
                 wpgen[512 + tid] * h_s[tid] + wpgen[512 + tid + 256] * h_s[tid + 256] +
                 wpgen[1024 + tid] * emb[(size_t)tok * 256 + tid] + wfp[tid] * tp0 +
                 wfp[tid + 256] * tp1;
      red_s[tid] = pg;
      __syncthreads();
      for (int o2 = 128; o2 > 0; o2 >>= 1) {
        if (tid < o2) red_s[tid] += red_s[tid + o2];
        __syncthreads();
      }
      if (nc == 0 && tid == 0) {
        pgen_o[t * 16 + b_pc] = sigf(red_s[0] + bpgen[0]);
        zinv[t * 16 + b_pc] = inv;
      }
      // tmp rows n = nc*64 + [0,64)
      int nidx = tid >> 2, kq = tid & 3;
      int n = nc * 64 + nidx;
      const f32x4* wrp = (const f32x4*)(wo1 + (size_t)n * 1024) + kq * 64;
      const f32x4* xr2 =
          (kq < 2) ? ((const f32x4*)h_s + kq * 64) : ((const f32x4*)ctx_s + (kq - 2) * 64);
      float a = 0;
#pragma unroll 4
      for (int k = 0; k < 64; ++k) a += dot4(xr2[k], wrp[k]);
      a += __shfl_xor(a, 1);
      a += __shfl_xor(a, 2);
      if (kq == 0) {
        float tv = tanh_f(a + bo1[n]);
        stg(&tmp_dec[(size_t)(t + 1) * 8192 + b_pc * 512 + n], tv);
        tmp_bf[((size_t)t * 16 + b_pc) * 512 + n] = f2bf(tv);
      }
    }
    barrier_flags(flags, 0, NB_DEC, ++pc);
  }
}

// ---------------- per (t,b) row softmax + copy-scatter + log ----------------
__global__ __launch_bounds__(1024) void finalize_kernel(float* out, const float* pexp,
                                                        const float* zinv, const float* pgen_i,
                                                        const int* src_ext) {
  __shared__ float scat[VX];
  __shared__ float red[64];
  const int row = blockIdx.x;
  const int b = row & 15;
  const int tid = threadIdx.x;
  for (int i = tid; i < VX; i += 1024) scat[i] = 0.0f;
  __syncthreads();
  const float pg = pgen_i[row];
  const float inv = zinv[row];
  if (tid < S_SZ) {
    float v = (1.0f - pg) * pexp[(size_t)row * S_SZ + tid] * inv;
    int col = src_ext[b * S_SZ + tid];
    atomicAdd(&scat[col], v);
  }
  float* orow = out + (size_t)row * VX;
  float l[32];
  float mx = -3.4e38f;
#pragma unroll
  for (int i2 = 0; i2 < 32; ++i2) {
    int col = tid + (i2 << 10);
    l[i2] = (col < V_SZ) ? orow[col] : -3.4e38f;
    mx = fmaxf(mx, l[i2]);
  }
#pragma unroll
  for (int o = 32; o; o >>= 1) mx = fmaxf(mx, __shfl_xor(mx, o));
  if ((tid & 63) == 0) red[16 + (tid >> 6)] = mx;
  __syncthreads();
  if (tid == 0) {
    float m2 = red[16];
    for (int w = 1; w < 16; ++w) m2 = fmaxf(m2, red[16 + w]);
    red[0] = m2;
  }
  __syncthreads();
  const float gmx = red[0];
  float se = 0.0f;
#pragma unroll
  for (int i2 = 0; i2 < 32; ++i2) {
    int col = tid + (i2 << 10);
    if (col < V_SZ) {
      l[i2] = __expf(l[i2] - gmx);
      se += l[i2];
    }
  }
#pragma unroll
  for (int o = 32; o; o >>= 1) se += __shfl_xor(se, o);
  if ((tid & 63) == 0) red[32 + (tid >> 6)] = se;
  __syncthreads();
  if (tid == 0) {
    float s2 = 0;
    for (int w = 0; w < 16; ++w) s2 += red[32 + w];
    red[1] = s2;
  }
  __syncthreads();
  const float scale = pg / red[1];
#pragma unroll
  for (int i2 = 0; i2 < 32; ++i2) {
    int col = tid + (i2 << 10);
    if (col < VX) {
      float base = (col < V_SZ) ? l[i2] * scale : 0.0f;
      orow[col] = __logf(base + scat[col] + 1e-20f);
    }
  }
}

extern "C" void kernel_launch(void* const* d_in, const int* in_sizes, int n_in, void* d_out,
                              int out_size, void* d_ws, size_t ws_size, hipStream_t stream) {
  (void)in_sizes; (void)n_in; (void)out_size; (void)ws_size;
  const int* source = (const int*)d_in[0];
  const int* source_ext = (const int*)d_in[1];
  const int* source_len = (const int*)d_in[2];
  const int* target = (const int*)d_in[3];
  const float* emb = (const float*)d_in[4];
  const float* wih_f = (const float*)d_in[5];
  const float* whh_f = (const float*)d_in[6];
  const float* b_f = (const float*)d_in[7];
  const float* wih_b = (const float*)d_in[8];
  const float* whh_b = (const float*)d_in[9];
  const float* b_b = (const float*)d_in[10];
  const float* wproj = (const float*)d_in[11];
  const float* bproj = (const float*)d_in[12];
  const float* w2h = (const float*)d_in[13];
  const float* b2h = (const float*)d_in[14];
  const float* w2c = (const float*)d_in[15];
  const float* b2c = (const float*)d_in[16];
  const float* wo1 = (const float*)d_in[17];
  const float* bo1 = (const float*)d_in[18];
  const float* wo2 = (const float*)d_in[19];
  const float* dwih = (const float*)d_in[20];
  const float* dwhh = (const float*)d_in[21];
  const float* dbias = (const float*)d_in[22];
  const float* wpgen = (const float*)d_in[23];
  const float* bpgen = (const float*)d_in[24];
  float* out = (float*)d_out;

  size_t off = 0;
  char* wsb = (char*)d_ws;
  auto alloc = [&](size_t bytes) -> void* {
    void* p = wsb + off;
    off += (bytes + 255) & ~(size_t)255;
    return p;
  };
  int* flags_enc = (int*)alloc(NB_ENC * 4);
  int* flags_dec = (int*)alloc(NB_DEC * 4);
  ushort_t* emb_bf = (ushort_t*)alloc((size_t)V_SZ * D_SZ * 2);
  ushort_t* wihf_bf = (ushort_t*)alloc((size_t)G4 * D_SZ * 2);
  ushort_t* wihb_bf = (ushort_t*)alloc((size_t)G4 * D_SZ * 2);
  ushort_t* wihd_bf = (ushort_t*)alloc((size_t)G4 * D_SZ * 2);
  ushort_t* wproj_bf = (ushort_t*)alloc((size_t)H_SZ * 2 * H_SZ * 2);
  ushort_t* wo2t_bf = (ushort_t*)alloc((size_t)H_SZ * D_SZ * 2);
  float* wfused = (float*)alloc((size_t)G4 * H_SZ * 4);
  float* wfp = (float*)alloc(512 * 4);
  ushort_t* xs_bf = (ushort_t*)alloc((size_t)S_SZ * B_SZ * D_SZ * 2);
  ushort_t* xt_bf = (ushort_t*)alloc((size_t)T_SZ * B_SZ * D_SZ * 2);
  float* gx_f = (float*)alloc((size_t)S_SZ * B_SZ * G4 * 4);  // also E2_bf after enc
  float* gx_b = (float*)alloc((size_t)S_SZ * B_SZ * G4 * 4);  // also gx_dec after enc
  float* h_hist = (float*)alloc((size_t)2 * (S_SZ + 1) * B_SZ * H_SZ * 4);  // also ctx_part
  ushort_t* ys_cat = (ushort_t*)alloc((size_t)S_SZ * B_SZ * 2 * H_SZ * 2);
  float* h_final = (float*)alloc((size_t)2 * B_SZ * H_SZ * 4);
  float* c_final = (float*)alloc((size_t)2 * B_SZ * H_SZ * 4);
  float* enc_outs = (float*)alloc((size_t)B_SZ * S_SZ * H_SZ * 4);
  float* seq_mean = (float*)alloc((size_t)B_SZ * H_SZ * 4);
  float* h_dec = (float*)alloc((size_t)(T_SZ + 1) * B_SZ * H_SZ * 4);
  float* c_init = (float*)alloc((size_t)B_SZ * H_SZ * 4);
  float* tmp_dec = (float*)alloc((size_t)(T_SZ + 1) * B_SZ * H_SZ * 4);
  ushort_t* tmp_bf = (ushort_t*)alloc((size_t)T_SZ * B_SZ * H_SZ * 2);
  float* z_part = (float*)alloc((size_t)T_SZ * B_SZ * 8 * 4);
  float* zinv = (float*)alloc((size_t)T_SZ * B_SZ * 4);
  float* pgen_b = (float*)alloc((size_t)T_SZ * B_SZ * 4);
  float* pexp = (float*)alloc((size_t)T_SZ * B_SZ * S_SZ * 4);
  // aliases (dead-after-encoder regions)
  ushort_t* e2_bf = (ushort_t*)gx_f;   // 32000*512*2 = 32.8 MB <= 52.4 MB
  float* gx_dec = gx_b;                // 1600*2048*4 = 13.1 MB <= 52.4 MB
  float* ctx_part = h_hist;            // 100*16*8*512*4 = 26.2 MB <= 26.3 MB

  hipMemsetAsync(d_ws, 0, 4096, stream);

  cvt_kernel<<<2048, 256, 0, stream>>>(emb, emb_bf, V_SZ * D_SZ);
  cvt_kernel<<<2048, 256, 0, stream>>>(wih_f, wihf_bf, G4 * D_SZ);
  cvt_kernel<<<2048, 256, 0, stream>>>(wih_b, wihb_bf, G4 * D_SZ);
  cvt_kernel<<<2048, 256, 0, stream>>>(wproj, wproj_bf, H_SZ * 2 * H_SZ);
  cvt_strided_kernel<<<2048, 256, 0, stream>>>(dwih, wihd_bf);
  cvt_wo2t_kernel<<<512, 256, 0, stream>>>(wo2, wo2t_bf);
  wfused_kernel<<<2048, 256, 0, stream>>>(dwih, wo2, wfused);
  wfp_kernel<<<2, 256, 0, stream>>>(wpgen, wo2, wfp);
  gather_src_kernel<<<800, 256, 0, stream>>>(emb_bf, source, xs_bf);
  gather_tgt_kernel<<<200, 256, 0, stream>>>(emb_bf, target, xt_bf);
  gemm_abt_bias<<<dim3(8, 400), 256, 0, stream>>>(xs_bf, wihf_bf, b_f, gx_f, 256);
  gemm_abt_bias<<<dim3(8, 400), 256, 0, stream>>>(xs_bf, wihb_bf, b_b, gx_b, 256);
  enc_kernel<<<NB_ENC, 256, 0, stream>>>(gx_f, gx_b, whh_f, whh_b, source_len, h_hist, ys_cat,
                                         h_final, c_final, flags_enc);
  gemm_encout<<<dim3(2, 400), 256, 0, stream>>>(ys_cat, wproj_bf, bproj, enc_outs);
  seqmean_kernel<<<32, 256, 0, stream>>>(enc_outs, source_len, seq_mean);
  init_state_kernel<<<64, 256, 0, stream>>>(h_final, c_final, w2h, b2h, w2c, b2c, h_dec, c_init);
  tmp0_kernel<<<32, 256, 0, stream>>>(h_dec, seq_mean, wo1, bo1, tmp_dec);
  gemm_abt_bias<<<dim3(8, 100), 256, 0, stream>>>(xt_bf, wihd_bf, dbias, gx_dec, 256);
  gemm_e2<<<dim3(2, 2000), 256, 0, stream>>>(emb_bf, wo2t_bf, e2_bf);
  dec_kernel<<<NB_DEC, 256, 0, stream>>>(emb, target, source_len, dwhh, wfused, wpgen, bpgen, wfp,
                                         wo1, bo1, enc_outs, gx_dec, h_dec, c_init, tmp_dec,
                                         tmp_bf, ctx_part, z_part, zinv, pgen_b, pexp, flags_dec);
  gemm_logits<<<dim3(100, 125), 256, 0, stream>>>(tmp_bf, e2_bf, out);
  finalize_kernel<<<1600, 1024, 0, stream>>>(out, pexp, zinv, pgen_b, source_ext);
}

// Round 3
// 8361.469 us; speedup vs baseline: 1.7938x; 1.3520x over previous
//
#include <hip/hip_runtime.h>

#define V_SZ 32000
#define D_SZ 256
#define H_SZ 512
#define B_SZ 16
#define S_SZ 400
#define T_SZ 100
#define G4   2048
#define VX   32050

typedef unsigned short ushort_t;
typedef __attribute__((ext_vector_type(8))) __bf16 bf16x8;
typedef __attribute__((ext_vector_type(8))) unsigned short ushort8_t;
typedef __attribute__((ext_vector_type(4))) float f32x4;

__device__ __forceinline__ ushort_t f2bf(float x) {
  union { float f; unsigned u; } v; v.f = x;
  unsigned r = v.u + 0x7fffu + ((v.u >> 16) & 1u);
  return (ushort_t)(r >> 16);
}
__device__ __forceinline__ float bf2f(ushort_t x) {
  union { unsigned u; float f; } v; v.u = ((unsigned)x) << 16; return v.f;
}
__device__ __forceinline__ float bfu2f(unsigned x) {
  union { unsigned u; float f; } v; v.u = x << 16; return v.f;
}
__device__ __forceinline__ float sigf(float x) { return 1.0f / (1.0f + __expf(-x)); }
__device__ __forceinline__ float tanh_f(float x) {
  float e = __expf(2.0f * x);
  return 1.0f - 2.0f / (e + 1.0f);
}
__device__ __forceinline__ float dot4(f32x4 a, f32x4 b) {
  return a.x * b.x + a.y * b.y + a.z * b.z + a.w * b.w;
}
// write-through store to device coherence point; readers cold-miss fresh data.
__device__ __forceinline__ void stg(float* p, float v) {
  __hip_atomic_store(p, v, __ATOMIC_RELAXED, __HIP_MEMORY_SCOPE_AGENT);
}
__device__ __forceinline__ void stg_u32(unsigned* p, unsigned v) {
  __hip_atomic_store(p, v, __ATOMIC_RELAXED, __HIP_MEMORY_SCOPE_AGENT);
}

// Grid barrier: single counter (one 128B line), arrival atomicAdd, all lanes
// poll the same word (1 request/wave -> no poll storm). Data stores are
// write-through (stg); vmcnt(0) drains each wave's stores before arrival.
__device__ __forceinline__ void barrier_ctr(unsigned* ctr, unsigned target) {
  asm volatile("s_waitcnt vmcnt(0)" ::: "memory");
  __syncthreads();
  if (threadIdx.x == 0)
    __hip_atomic_fetch_add(ctr, 1u, __ATOMIC_RELAXED, __HIP_MEMORY_SCOPE_AGENT);
  for (;;) {
    unsigned v = __hip_atomic_load(ctr, __ATOMIC_RELAXED, __HIP_MEMORY_SCOPE_AGENT);
    if (v >= target) break;
    __builtin_amdgcn_s_sleep(2);
  }
  __syncthreads();
}

// ---------------- f32 -> bf16 convert ----------------
__global__ __launch_bounds__(256) void cvt_kernel(const float* in, ushort_t* outp, int n) {
  int i = blockIdx.x * 256 + threadIdx.x;
  int stride = gridDim.x * 256;
  for (; i < n; i += stride) outp[i] = f2bf(in[i]);
}

// cols [0,256) of a row-stride-512 matrix -> packed bf16 (2048 x 256)
__global__ __launch_bounds__(256) void cvt_strided_kernel(const float* in, ushort_t* outp) {
  int gid = blockIdx.x * 256 + threadIdx.x;  // 524288
  int r = gid >> 8, d = gid & 255;
  outp[gid] = f2bf(in[(size_t)r * 512 + d]);
}

// wo2t[h][d] = wo2[d][h]  (512 x 256 bf16)
__global__ __launch_bounds__(256) void cvt_wo2t_kernel(const float* wo2, ushort_t* outp) {
  int gid = blockIdx.x * 256 + threadIdx.x;  // 131072
  int h = gid >> 8, d = gid & 255;
  outp[gid] = f2bf(wo2[(size_t)d * 512 + h]);
}

// Wfused[r][c] = sum_d dwih[r][256+d] * wo2[d][c]   (2048 x 512 f32)
__global__ __launch_bounds__(256) void wfused_kernel(const float* dwih, const float* wo2,
                                                     float* wf) {
  __shared__ float xr_s[256];
  int r = blockIdx.x;
  xr_s[threadIdx.x] = dwih[(size_t)r * 512 + 256 + threadIdx.x];
  __syncthreads();
  float a0 = 0, a1 = 0;
  for (int d = 0; d < 256; ++d) {
    float x = xr_s[d];
    a0 += x * wo2[(size_t)d * 512 + threadIdx.x];
    a1 += x * wo2[(size_t)d * 512 + threadIdx.x + 256];
  }
  wf[(size_t)r * 512 + threadIdx.x] = a0;
  wf[(size_t)r * 512 + threadIdx.x + 256] = a1;
}

// wfp[h] = sum_d wpgen[1280+d] * wo2[d][h]
__global__ __launch_bounds__(256) void wfp_kernel(const float* wpgen, const float* wo2,
                                                  float* wfp) {
  int h = blockIdx.x * 256 + threadIdx.x;
  float a = 0;
  for (int d = 0; d < 256; ++d) a += wpgen[1280 + d] * wo2[(size_t)d * 512 + h];
  wfp[h] = a;
}

// pack Whh (both dirs) into per-block wave-major bf16 rows:
// packed row p (per dir): ub=p>>6 (unit blk of 16), g=(p>>4)&3, u=p&15 -> row g*512+ub*16+u
__global__ __launch_bounds__(256) void pack_whh_kernel(const float* whh_f, const float* whh_b,
                                                       ushort_t* outp) {
  int gid = blockIdx.x * 256 + threadIdx.x;  // 2*2048*512
  int col = gid & 511;
  int p_g = gid >> 9;
  int dir = p_g >> 11, p = p_g & 2047;
  int ub = p >> 6, g = (p >> 4) & 3, u = p & 15;
  const float* src = dir ? whh_b : whh_f;
  outp[gid] = f2bf(src[(size_t)(g * 512 + ub * 16 + u) * 512 + col]);
}

// pack decoder recurrent weights [Whh_dec | Wfused] (2048 x 1024 bf16):
// packed row p: ub=p>>4 (unit blk of 4), g=(p>>2)&3, u=p&3 -> row g*512+ub*4+u
__global__ __launch_bounds__(256) void pack_wdec_kernel(const float* dwhh, const float* wfused,
                                                        ushort_t* outp) {
  int gid = blockIdx.x * 256 + threadIdx.x;  // 2048*1024
  int col = gid & 1023;
  int p = gid >> 10;
  int ub = p >> 4, g = (p >> 2) & 3, u = p & 3;
  int row = g * 512 + ub * 4 + u;
  float v = (col < 512) ? dwhh[(size_t)row * 512 + col] : wfused[(size_t)row * 512 + (col - 512)];
  outp[gid] = f2bf(v);
}

// ---------------- gather embeddings (bf16) ----------------
__global__ __launch_bounds__(256) void gather_src_kernel(const ushort_t* emb_bf, const int* source,
                                                         ushort_t* xs_bf) {
  int gid = blockIdx.x * 256 + threadIdx.x;  // 204800
  int r = gid >> 5, e = gid & 31;
  int s = r >> 4, b = r & 15;
  int tok = source[b * S_SZ + s];
  ((ushort8_t*)xs_bf)[gid] = ((const ushort8_t*)emb_bf)[(size_t)tok * 32 + e];
}
__global__ __launch_bounds__(256) void gather_tgt_kernel(const ushort_t* emb_bf, const int* target,
                                                         ushort_t* xt_bf) {
  int gid = blockIdx.x * 256 + threadIdx.x;  // 51200
  int r = gid >> 5, e = gid & 31;
  int t = r >> 4, b = r & 15;
  int tok = target[b * T_SZ + t];
  ((ushort8_t*)xt_bf)[gid] = ((const ushort8_t*)emb_bf)[(size_t)tok * 32 + e];
}

// ---------------- MFMA helper: one wave computes a 16x64 tile of A(M,K) @ B(N,K)^T ------------
__device__ __forceinline__ void mfma_16x64(const ushort_t* A, const ushort_t* B_, int K,
                                           int m0, int n0, f32x4 acc[4]) {
  const int lane = threadIdx.x & 63;
  const int lr = lane & 15, kh = lane >> 4;
  const ushort_t* ap = A + (size_t)(m0 + lr) * K + kh * 8;
  const ushort_t* bp = B_ + (size_t)(n0 + lr) * K + kh * 8;
  for (int k0 = 0; k0 < K; k0 += 32) {
    bf16x8 av = *(const bf16x8*)(ap + k0);
#pragma unroll
    for (int s = 0; s < 4; ++s) {
      bf16x8 bv = *(const bf16x8*)(bp + (size_t)s * 16 * K + k0);
      acc[s] = __builtin_amdgcn_mfma_f32_16x16x32_bf16(av, bv, acc[s], 0, 0, 0);
    }
  }
}

// ---------------- gates GEMM: out[m][n] = A[m]·B[n] + bias[n], N=2048 ----------------
__global__ __launch_bounds__(256) void gemm_abt_bias(const ushort_t* A, const ushort_t* Bm,
                                                     const float* bias, float* out, int K) {
  int wave = threadIdx.x >> 6;
  int m0 = blockIdx.y * 16;
  int n0 = blockIdx.x * 256 + wave * 64;
  f32x4 acc[4] = {};
  mfma_16x64(A, Bm, K, m0, n0, acc);
  int lane = threadIdx.x & 63, lr = lane & 15, kh = lane >> 4;
#pragma unroll
  for (int s = 0; s < 4; ++s) {
    int n = n0 + s * 16 + lr;
    float bv = bias[n];
#pragma unroll
    for (int i = 0; i < 4; ++i) {
      int m = m0 + kh * 4 + i;
      out[(size_t)m * G4 + n] = acc[s][i] + bv;
    }
  }
}

// ---------------- enc_outs = ys_cat @ Wproj^T + bproj, out layout [b][s][h] ----------------
__global__ __launch_bounds__(256) void gemm_encout(const ushort_t* ys_cat, const ushort_t* wproj_bf,
                                                   const float* bproj, float* enc_outs) {
  int wave = threadIdx.x >> 6;
  int m0 = blockIdx.y * 16;
  int n0 = blockIdx.x * 256 + wave * 64;
  f32x4 acc[4] = {};
  mfma_16x64(ys_cat, wproj_bf, 2 * H_SZ, m0, n0, acc);
  int lane = threadIdx.x & 63, lr = lane & 15, kh = lane >> 4;
#pragma unroll
  for (int s = 0; s < 4; ++s) {
    int n = n0 + s * 16 + lr;
    float bv = bproj[n];
#pragma unroll
    for (int i = 0; i < 4; ++i) {
      int m = m0 + kh * 4 + i;
      int b = m & 15, si = m >> 4;
      enc_outs[((size_t)b * S_SZ + si) * H_SZ + n] = acc[s][i] + bv;
    }
  }
}

// ---------------- E2 = emb @ Wo2  (32000 x 512, bf16) ----------------
__global__ __launch_bounds__(256) void gemm_e2(const ushort_t* emb_bf, const ushort_t* wo2t_bf,
                                               ushort_t* e2) {
  int wave = threadIdx.x >> 6;
  int m0 = blockIdx.y * 16;
  int n0 = blockIdx.x * 256 + wave * 64;
  f32x4 acc[4] = {};
  mfma_16x64(emb_bf, wo2t_bf, 256, m0, n0, acc);
  int lane = threadIdx.x & 63, lr = lane & 15, kh = lane >> 4;
#pragma unroll
  for (int s = 0; s < 4; ++s) {
    int n = n0 + s * 16 + lr;
#pragma unroll
    for (int i = 0; i < 4; ++i) {
      int m = m0 + kh * 4 + i;
      e2[(size_t)m * 512 + n] = f2bf(acc[s][i]);
    }
  }
}

// ---------------- logits = tmp @ E2^T  (K=512), into d_out cols [0,V) ----------------
__global__ __launch_bounds__(256) void gemm_logits(const ushort_t* tmp_bf, const ushort_t* e2_bf,
                                                   float* out) {
  int wave = threadIdx.x >> 6;
  int m0 = blockIdx.x * 16;
  int n0 = blockIdx.y * 256 + wave * 64;
  f32x4 acc[4] = {};
  mfma_16x64(tmp_bf, e2_bf, 512, m0, n0, acc);
  int lane = threadIdx.x & 63, lr = lane & 15, kh = lane >> 4;
#pragma unroll
  for (int s = 0; s < 4; ++s) {
    int n = n0 + s * 16 + lr;
#pragma unroll
    for (int i = 0; i < 4; ++i) {
      int m = m0 + kh * 4 + i;
      out[(size_t)m * VX + n] = acc[s][i];
    }
  }
}

// ---------------- persistent bidirectional encoder LSTM (MFMA) ----------------
// 64 blocks: dir = blk>>5, ub = blk&31 -> units j0=ub*16 .. +16. Wave g handles gate g.
// h state kept as bf16 pairs in hbf_[fb]: [t][b][256 u32].
__global__ __launch_bounds__(256) void enc_kernel(const float* gx_f, const float* gx_b,
                                                  const ushort_t* whh_pk, const int* src_len,
                                                  unsigned* hbf_f, unsigned* hbf_b,
                                                  unsigned* ys_cat_u32, float* h_final,
                                                  float* c_final, unsigned* ctrs) {
  __shared__ float gates_s[4 * 16 * 17];
  const int blk = blockIdx.x, tid = threadIdx.x;
  const int dir = blk >> 5, ub = blk & 31, j0 = ub * 16;
  const int g = tid >> 6, lane = tid & 63, lr = lane & 15, kh = lane >> 4;
  const float* gx = dir ? gx_b : gx_f;
  unsigned* hb = dir ? hbf_b : hbf_f;
  unsigned* ctr = ctrs + dir * 32;
  const ushort_t* wrow =
      whh_pk + (size_t)(((dir * 32 + ub) * 4 + g) * 16 + lr) * 512 + kh * 8;
  const int b = tid & 15, u = tid >> 4;
  const int len_b = src_len[b];
  float c_reg = 0.0f;

  for (int t = 0; t < S_SZ; ++t) {
    const int s_pos = dir ? (S_SZ - 1 - t) : t;
    f32x4 acc = {0.f, 0.f, 0.f, 0.f};
    const ushort_t* ap = (const ushort_t*)(hb + (size_t)t * 4096) + lr * 512 + kh * 8;
#pragma unroll
    for (int k0 = 0; k0 < 512; k0 += 32)
      acc = __builtin_amdgcn_mfma_f32_16x16x32_bf16(*(const bf16x8*)(ap + k0),
                                                    *(const bf16x8*)(wrow + k0), acc, 0, 0, 0);
    const float* gxr = gx + (size_t)s_pos * (16 * 2048) + g * 512 + j0 + lr;
#pragma unroll
    for (int i = 0; i < 4; ++i)
      gates_s[(g * 16 + lr) * 17 + kh * 4 + i] = acc[i] + gxr[(size_t)(kh * 4 + i) * 2048];
    __syncthreads();
    // cell update: thread (b, u) owns unit j0+u
    float gi = gates_s[u * 17 + b];
    float gf = gates_s[(16 + u) * 17 + b];
    float gg = gates_s[(32 + u) * 17 + b];
    float go = gates_s[(48 + u) * 17 + b];
    bool msk = s_pos < len_b;
    float cn = sigf(gf) * c_reg + sigf(gi) * tanh_f(gg);
    float hn = sigf(go) * tanh_f(cn);
    float hprev = bf2f(((const ushort_t*)(hb + (size_t)t * 4096))[b * 512 + j0 + u]);
    float hout = msk ? hn : hprev;
    if (msk) c_reg = cn;
    unsigned hbits = (unsigned)f2bf(hout);
    unsigned hpart = __shfl_xor(hbits, 16);
    unsigned ybits = msk ? (unsigned)f2bf(hn) : 0u;
    unsigned ypart = __shfl_xor(ybits, 16);
    if ((u & 1) == 0) {
      stg_u32(&hb[(size_t)(t + 1) * 4096 + b * 256 + ((j0 + u) >> 1)], hbits | (hpart << 16));
      ys_cat_u32[(size_t)(s_pos * 16 + b) * 512 + dir * 256 + ((j0 + u) >> 1)] =
          ybits | (ypart << 16);
    }
    if (t == S_SZ - 1) {
      h_final[dir * 8192 + b * 512 + j0 + u] = hout;
      c_final[dir * 8192 + b * 512 + j0 + u] = c_reg;
    }
    if (t + 1 < S_SZ) barrier_ctr(ctr, 32u * (unsigned)(t + 1));
  }
}

// ---------------- seq_mean ----------------
__global__ __launch_bounds__(256) void seqmean_kernel(const float* enc_outs, const int* src_len,
                                                      float* seq_mean) {
  int b = blockIdx.x >> 1;
  int j = (blockIdx.x & 1) * 256 + threadIdx.x;
  int L = src_len[b];
  float a = 0;
  for (int s = 0; s < L; ++s) a += enc_outs[((size_t)b * S_SZ + s) * H_SZ + j];
  seq_mean[b * 512 + j] = a / (float)L;
}

// ---------------- dec state init: h (bf16 packed) + c (f32) ----------------
__global__ __launch_bounds__(256) void init_state_kernel(const float* h_final, const float* c_final,
                                                         const float* w2h, const float* b2h,
                                                         const float* w2c, const float* b2c,
                                                         unsigned* h_u32, float* c_init) {
  int gid = blockIdx.x * 256 + threadIdx.x;  // 16384
  int half = gid >> 13;
  int idx = gid & 8191;
  int b = idx >> 9, j = idx & 511;
  const float* src = half ? c_final : h_final;
  const float* w = (half ? w2c : w2h) + (size_t)j * 1024;
  float acc = (half ? b2c : b2h)[j];
  const f32x4* s0 = (const f32x4*)(src + b * 512);
  const f32x4* s1 = (const f32x4*)(src + 8192 + b * 512);
  const f32x4* w0 = (const f32x4*)w;
  const f32x4* w1 = w0 + 128;
  float a = 0;
  for (int k = 0; k < 128; ++k) a += dot4(s0[k], w0[k]);
  for (int k = 0; k < 128; ++k) a += dot4(s1[k], w1[k]);
  acc += a;
  if (half) {
    c_init[idx] = acc;
  } else {
    unsigned bits = (unsigned)f2bf(acc);
    unsigned pb2 = __shfl_xor(bits, 1);
    if ((j & 1) == 0) h_u32[b * 256 + (j >> 1)] = bits | (pb2 << 16);
  }
}

// ---------------- tmp0 = tanh([dec_h | seq_mean] @ Wo1^T + bo1) -> tmp slot 0 (bf16) ---------
__global__ __launch_bounds__(256) void tmp0_kernel(const float* h_final_unused,
                                                   const unsigned* h0_u32, const float* seq_mean,
                                                   const float* wo1, const float* bo1,
                                                   unsigned* tmp_u32) {
  int gid = blockIdx.x * 256 + threadIdx.x;  // 8192
  int b = gid >> 9, j = gid & 511;
  const f32x4* x1 = (const f32x4*)(seq_mean + b * 512);
  const f32x4* w0 = (const f32x4*)(wo1 + (size_t)j * 1024);
  const f32x4* w1 = w0 + 128;
  float a = bo1[j];
  float p = 0;
  const ushort_t* h0 = (const ushort_t*)(h0_u32) + b * 512;
  for (int k = 0; k < 128; ++k) {
    f32x4 hv = {bf2f(h0[k * 4]), bf2f(h0[k * 4 + 1]), bf2f(h0[k * 4 + 2]), bf2f(h0[k * 4 + 3])};
    p += dot4(hv, w0[k]);
  }
  for (int k = 0; k < 128; ++k) p += dot4(x1[k], w1[k]);
  float tv = tanh_f(a + p);
  unsigned bits = (unsigned)f2bf(tv);
  unsigned pb2 = __shfl_xor(bits, 1);
  if ((j & 1) == 0) tmp_u32[b * 256 + (j >> 1)] = bits | (pb2 << 16);
}

// ---------------- persistent decoder: 100 steps x 3 phases ----------------
__global__ __launch_bounds__(256) void dec_kernel(
    const float* emb, const int* target, const int* src_len, const ushort_t* wdec_pk,
    const float* wpgen, const float* bpgen, const float* wfp, const float* wo1, const float* bo1,
    const float* enc_outs, const float* gx_dec, unsigned* h_u32, const float* c_init,
    unsigned* tmp_u32, float* ctx_part, float* z_part, float* zinv, float* pgen_o, float* pexp,
    unsigned* ctrs) {
  __shared__ float part_s[4 * 16 * 17];
  __shared__ f32x4 smem4[272];  // h_s(512) + ctx_s(512) + pad
  __shared__ float red_s[256];
  __shared__ float p_s[64];
  float* sm = (float*)smem4;
  unsigned* ctr = ctrs + 64;

  const int blk = blockIdx.x, tid = threadIdx.x;
  const int w = tid >> 6, lane = tid & 63, lr = lane & 15, kh = lane >> 4;
  const int j0 = blk * 4;
  const ushort_t* wrow = wdec_pk + (size_t)(blk * 16 + lr) * 1024 + w * 256 + kh * 8;
  const int b_c = tid & 15, u_c = (tid >> 4) & 3;
  float c_reg = (tid < 64) ? c_init[b_c * 512 + j0 + u_c] : 0.0f;
  const int b_pb = blk >> 3, ch = blk & 7, s0c = ch * 50;
  const int len_pb = src_len[b_pb];
  const int nc = ch;
  unsigned pc = 0;

  for (int t = 0; t < T_SZ; ++t) {
    // ---------- PA: gates via MFMA (K=1024 split over 4 waves) ----------
    {
      f32x4 acc = {0.f, 0.f, 0.f, 0.f};
      const unsigned* asrc = (w < 2) ? (h_u32 + (size_t)t * 4096) : (tmp_u32 + (size_t)t * 4096);
      const ushort_t* ap = (const ushort_t*)asrc + lr * 512 + (w & 1) * 256 + kh * 8;
#pragma unroll
      for (int k0 = 0; k0 < 256; k0 += 32)
        acc = __builtin_amdgcn_mfma_f32_16x16x32_bf16(*(const bf16x8*)(ap + k0),
                                                      *(const bf16x8*)(wrow + k0), acc, 0, 0, 0);
#pragma unroll
      for (int i = 0; i < 4; ++i) part_s[(w * 16 + lr) * 17 + kh * 4 + i] = acc[i];
      __syncthreads();
      if (tid < 64) {
        float gt[4];
#pragma unroll
        for (int g2 = 0; g2 < 4; ++g2) {
          int p = g2 * 4 + u_c;
          float a = gx_dec[((size_t)t * 16 + b_c) * 2048 + g2 * 512 + j0 + u_c];
#pragma unroll
          for (int w2 = 0; w2 < 4; ++w2) a += part_s[(w2 * 16 + p) * 17 + b_c];
          gt[g2] = a;
        }
        float cn = sigf(gt[1]) * c_reg + sigf(gt[0]) * tanh_f(gt[2]);
        c_reg = cn;
        float hn = sigf(gt[3]) * tanh_f(cn);
        unsigned bits = (unsigned)f2bf(hn);
        unsigned pb2 = __shfl_xor(bits, 16);
        if ((u_c & 1) == 0)
          stg_u32(&h_u32[(size_t)(t + 1) * 4096 + b_c * 256 + ((j0 + u_c) >> 1)],
                  bits | (pb2 << 16));
      }
    }
    barrier_ctr(ctr, 128u * (++pc));
    // ---------- PB: score chunks -> pexp, z_part, ctx_part ----------
    {
      if (tid < 128) {
        unsigned v0 = h_u32[(size_t)(t + 1) * 4096 + b_pb * 256 + tid * 2];
        unsigned v1 = h_u32[(size_t)(t + 1) * 4096 + b_pb * 256 + tid * 2 + 1];
        f32x4 hv = {bfu2f(v0 & 0xffffu), bfu2f(v0 >> 16), bfu2f(v1 & 0xffffu), bfu2f(v1 >> 16)};
        ((f32x4*)sm)[tid] = hv;
      }
      __syncthreads();
      int st = tid >> 2, kq = tid & 3;
      if (st < 50) {
        const f32x4* er =
            (const f32x4*)(enc_outs + ((size_t)b_pb * S_SZ + s0c + st) * H_SZ) + kq * 32;
        const f32x4* hr = (const f32x4*)sm + kq * 32;
        float sc = 0;
        for (int k = 0; k < 32; ++k) sc += dot4(hr[k], er[k]);
        sc += __shfl_xor(sc, 1);
        sc += __shfl_xor(sc, 2);
        if (kq == 0) {
          int s_abs = s0c + st;
          float p = (s_abs < len_pb) ? __expf(sc) : 0.0f;
          p_s[st] = p;
          pexp[((size_t)t * 16 + b_pb) * S_SZ + s_abs] = p;
        }
      }
      __syncthreads();
      if (tid == 0) {
        float z = 0;
        for (int s = 0; s < 50; ++s) z += p_s[s];
        stg(&z_part[((size_t)t * 16 + b_pb) * 8 + ch], z);
      }
      float a0 = 0, a1 = 0;
      for (int s = 0; s < 50; ++s) {
        float p = p_s[s];
        const float* er = enc_outs + ((size_t)b_pb * S_SZ + s0c + s) * H_SZ;
        a0 += p * er[tid];
        a1 += p * er[tid + 256];
      }
      float* cp = ctx_part + (((size_t)t * 16 + b_pb) * 8 + ch) * 512;
      stg(&cp[tid], a0);
      stg(&cp[tid + 256], a1);
    }
    barrier_ctr(ctr, 128u * (++pc));
    // ---------- PC: combine ctx + pgen + tmp ----------
    {
      float* h_s = sm;
      float* ctx_s = sm + 512;
      const float* zp = z_part + ((size_t)t * 16 + b_pb) * 8;
      float z = 0;
#pragma unroll
      for (int c2 = 0; c2 < 8; ++c2) z += zp[c2];
      float inv = 1.0f / z;
      if (tid < 128) {
        unsigned v0 = h_u32[(size_t)(t + 1) * 4096 + b_pb * 256 + tid * 2];
        unsigned v1 = h_u32[(size_t)(t + 1) * 4096 + b_pb * 256 + tid * 2 + 1];
        f32x4 hv = {bfu2f(v0 & 0xffffu), bfu2f(v0 >> 16), bfu2f(v1 & 0xffffu), bfu2f(v1 >> 16)};
        ((f32x4*)h_s)[tid] = hv;
      }
      const float* cpb = ctx_part + ((size_t)t * 16 + b_pb) * 8 * 512;
      float c0 = 0, c1 = 0;
#pragma unroll
      for (int c2 = 0; c2 < 8; ++c2) {
        c0 += cpb[c2 * 512 + tid];
        c1 += cpb[c2 * 512 + tid + 256];
      }
      ctx_s[tid] = c0 * inv;
      ctx_s[tid + 256] = c1 * inv;
      __syncthreads();
      int tok = target[b_pb * T_SZ + t];
      const ushort_t* tmpp = (const ushort_t*)(tmp_u32 + (size_t)t * 4096) + b_pb * 512;
      float tp0 = bf2f(tmpp[tid]);
      float tp1 = bf2f(tmpp[tid + 256]);
      float pg = wpgen[tid] * ctx_s[tid] + wpgen[tid + 256] * ctx_s[tid + 256] +
                 wpgen[512 + tid] * h_s[tid] + wpgen[512 + tid + 256] * h_s[tid + 256] +
                 wpgen[1024 + tid] * emb[(size_t)tok * 256 + tid] + wfp[tid] * tp0 +
                 wfp[tid + 256] * tp1;
      red_s[tid] = pg;
      __syncthreads();
      for (int o2 = 128; o2 > 0; o2 >>= 1) {
        if (tid < o2) red_s[tid] += red_s[tid + o2];
        __syncthreads();
      }
      if (nc == 0 && tid == 0) {
        pgen_o[t * 16 + b_pb] = sigf(red_s[0] + bpgen[0]);
        zinv[t * 16 + b_pb] = inv;
      }
      int nidx = tid >> 2, kq = tid & 3;
      int n = nc * 64 + nidx;
      const f32x4* wrp = (const f32x4*)(wo1 + (size_t)n * 1024) + kq * 64;
      const f32x4* xr2 =
          (kq < 2) ? ((const f32x4*)h_s + kq * 64) : ((const f32x4*)ctx_s + (kq - 2) * 64);
      float a = 0;
#pragma unroll 4
      for (int k = 0; k < 64; ++k) a += dot4(xr2[k], wrp[k]);
      a += __shfl_xor(a, 1);
      a += __shfl_xor(a, 2);
      float tv = tanh_f(a + bo1[n]);
      unsigned bits = (unsigned)f2bf(tv);
      unsigned pbits = __shfl_xor(bits, 4);
      if (kq == 0 && (nidx & 1) == 0)
        stg_u32(&tmp_u32[(size_t)(t + 1) * 4096 + b_pb * 256 + ((nc * 64 + nidx) >> 1)],
                bits | (pbits << 16));
    }
    if (t + 1 < T_SZ) barrier_ctr(ctr, 128u * (++pc));
  }
}

// ---------------- per (t,b) row softmax + copy-scatter + log ----------------
__global__ __launch_bounds__(1024) void finalize_kernel(float* out, const float* pexp,
                                                        const float* zinv, const float* pgen_i,
                                                        const int* src_ext) {
  __shared__ float scat[VX];
  __shared__ float red[64];
  const int row = blockIdx.x;
  const int b = row & 15;
  const int tid = threadIdx.x;
  for (int i = tid; i < VX; i += 1024) scat[i] = 0.0f;
  __syncthreads();
  const float pg = pgen_i[row];
  const float inv = zinv[row];
  if (tid < S_SZ) {
    float v = (1.0f - pg) * pexp[(size_t)row * S_SZ + tid] * inv;
    int col = src_ext[b * S_SZ + tid];
    atomicAdd(&scat[col], v);
  }
  float* orow = out + (size_t)row * VX;
  float l[32];
  float mx = -3.4e38f;
#pragma unroll
  for (int i2 = 0; i2 < 32; ++i2) {
    int col = tid + (i2 << 10);
    l[i2] = (col < V_SZ) ? orow[col] : -3.4e38f;
    mx = fmaxf(mx, l[i2]);
  }
#pragma unroll
  for (int o = 32; o; o >>= 1) mx = fmaxf(mx, __shfl_xor(mx, o));
  if ((tid & 63) == 0) red[16 + (tid >> 6)] = mx;
  __syncthreads();
  if (tid == 0) {
    float m2 = red[16];
    for (int w = 1; w < 16; ++w) m2 = fmaxf(m2, red[16 + w]);
    red[0] = m2;
  }
  __syncthreads();
  const float gmx = red[0];
  float se = 0.0f;
#pragma unroll
  for (int i2 = 0; i2 < 32; ++i2) {
    int col = tid + (i2 << 10);
    if (col < V_SZ) {
      l[i2] = __expf(l[i2] - gmx);
      se += l[i2];
    }
  }
#pragma unroll
  for (int o = 32; o; o >>= 1) se += __shfl_xor(se, o);
  if ((tid & 63) == 0) red[32 + (tid >> 6)] = se;
  __syncthreads();
  if (tid == 0) {
    float s2 = 0;
    for (int w = 0; w < 16; ++w) s2 += red[32 + w];
    red[1] = s2;
  }
  __syncthreads();
  const float scale = pg / red[1];
#pragma unroll
  for (int i2 = 0; i2 < 32; ++i2) {
    int col = tid + (i2 << 10);
    if (col < VX) {
      float base = (col < V_SZ) ? l[i2] * scale : 0.0f;
      orow[col] = __logf(base + scat[col] + 1e-20f);
    }
  }
}

extern "C" void kernel_launch(void* const* d_in, const int* in_sizes, int n_in, void* d_out,
                              int out_size, void* d_ws, size_t ws_size, hipStream_t stream) {
  (void)in_sizes; (void)n_in; (void)out_size; (void)ws_size;
  const int* source = (const int*)d_in[0];
  const int* source_ext = (const int*)d_in[1];
  const int* source_len = (const int*)d_in[2];
  const int* target = (const int*)d_in[3];
  const float* emb = (const float*)d_in[4];
  const float* wih_f = (const float*)d_in[5];
  const float* whh_f = (const float*)d_in[6];
  const float* b_f = (const float*)d_in[7];
  const float* wih_b = (const float*)d_in[8];
  const float* whh_b = (const float*)d_in[9];
  const float* b_b = (const float*)d_in[10];
  const float* wproj = (const float*)d_in[11];
  const float* bproj = (const float*)d_in[12];
  const float* w2h = (const float*)d_in[13];
  const float* b2h = (const float*)d_in[14];
  const float* w2c = (const float*)d_in[15];
  const float* b2c = (const float*)d_in[16];
  const float* wo1 = (const float*)d_in[17];
  const float* bo1 = (const float*)d_in[18];
  const float* wo2 = (const float*)d_in[19];
  const float* dwih = (const float*)d_in[20];
  const float* dwhh = (const float*)d_in[21];
  const float* dbias = (const float*)d_in[22];
  const float* wpgen = (const float*)d_in[23];
  const float* bpgen = (const float*)d_in[24];
  float* out = (float*)d_out;

  size_t off = 0;
  char* wsb = (char*)d_ws;
  auto alloc = [&](size_t bytes) -> void* {
    void* p = wsb + off;
    off += (bytes + 255) & ~(size_t)255;
    return p;
  };
  unsigned* ctrs = (unsigned*)alloc(512);  // enc_f @0, enc_b @32 words, dec @64 words
  ushort_t* emb_bf = (ushort_t*)alloc((size_t)V_SZ * D_SZ * 2);
  ushort_t* wihf_bf = (ushort_t*)alloc((size_t)G4 * D_SZ * 2);
  ushort_t* wihb_bf = (ushort_t*)alloc((size_t)G4 * D_SZ * 2);
  ushort_t* wihd_bf = (ushort_t*)alloc((size_t)G4 * D_SZ * 2);
  ushort_t* wproj_bf = (ushort_t*)alloc((size_t)H_SZ * 2 * H_SZ * 2);
  ushort_t* wo2t_bf = (ushort_t*)alloc((size_t)H_SZ * D_SZ * 2);
  float* wfused = (float*)alloc((size_t)G4 * H_SZ * 4);
  float* wfp = (float*)alloc(512 * 4);
  ushort_t* whh_pk = (ushort_t*)alloc((size_t)2 * G4 * H_SZ * 2);
  ushort_t* wdec_pk = (ushort_t*)alloc((size_t)G4 * 1024 * 2);
  ushort_t* xs_bf = (ushort_t*)alloc((size_t)S_SZ * B_SZ * D_SZ * 2);
  ushort_t* xt_bf = (ushort_t*)alloc((size_t)T_SZ * B_SZ * D_SZ * 2);
  float* gx_f = (float*)alloc((size_t)S_SZ * B_SZ * G4 * 4);  // aliased by e2_bf after enc
  float* gx_b = (float*)alloc((size_t)S_SZ * B_SZ * G4 * 4);  // aliased by gx_dec/ctx_part
  unsigned* hbf_f = (unsigned*)alloc((size_t)(S_SZ + 1) * 4096 * 4);
  unsigned* hbf_b = (unsigned*)alloc((size_t)(S_SZ + 1) * 4096 * 4);
  unsigned* ys_cat_u32 = (unsigned*)alloc((size_t)S_SZ * B_SZ * 512 * 4);
  float* h_final = (float*)alloc((size_t)2 * B_SZ * H_SZ * 4);
  float* c_final = (float*)alloc((size_t)2 * B_SZ * H_SZ * 4);
  float* enc_outs = (float*)alloc((size_t)B_SZ * S_SZ * H_SZ * 4);
  float* seq_mean = (float*)alloc((size_t)B_SZ * H_SZ * 4);
  unsigned* h_u32 = (unsigned*)alloc((size_t)(T_SZ + 1) * 4096 * 4);
  float* c_init = (float*)alloc((size_t)B_SZ * H_SZ * 4);
  unsigned* tmp_u32 = (unsigned*)alloc((size_t)(T_SZ + 1) * 4096 * 4);
  float* z_part = (float*)alloc((size_t)T_SZ * B_SZ * 8 * 4);
  float* zinv = (float*)alloc((size_t)T_SZ * B_SZ * 4);
  float* pgen_b = (float*)alloc((size_t)T_SZ * B_SZ * 4);
  float* pexp = (float*)alloc((size_t)T_SZ * B_SZ * S_SZ * 4);
  // aliases into dead-after-encoder regions
  ushort_t* e2_bf = (ushort_t*)gx_f;                     // 32.8 MB <= 52.4 MB
  float* gx_dec = gx_b;                                  // 13.1 MB
  float* ctx_part = gx_b + (size_t)1600 * 2048;          // 26.2 MB (fits in 52.4-13.1)

  hipMemsetAsync(d_ws, 0, 4096, stream);               // counters
  hipMemsetAsync(hbf_f, 0, 4096 * 4, stream);          // enc h slot 0 (dir f)
  hipMemsetAsync(hbf_b, 0, 4096 * 4, stream);          // enc h slot 0 (dir b)

  cvt_kernel<<<2048, 256, 0, stream>>>(emb, emb_bf, V_SZ * D_SZ);
  cvt_kernel<<<2048, 256, 0, stream>>>(wih_f, wihf_bf, G4 * D_SZ);
  cvt_kernel<<<2048, 256, 0, stream>>>(wih_b, wihb_bf, G4 * D_SZ);
  cvt_kernel<<<2048, 256, 0, stream>>>(wproj, wproj_bf, H_SZ * 2 * H_SZ);
  cvt_strided_kernel<<<2048, 256, 0, stream>>>(dwih, wihd_bf);
  cvt_wo2t_kernel<<<512, 256, 0, stream>>>(wo2, wo2t_bf);
  wfused_kernel<<<2048, 256, 0, stream>>>(dwih, wo2, wfused);
  wfp_kernel<<<2, 256, 0, stream>>>(wpgen, wo2, wfp);
  pack_whh_kernel<<<8192, 256, 0, stream>>>(whh_f, whh_b, whh_pk);
  pack_wdec_kernel<<<8192, 256, 0, stream>>>(dwhh, wfused, wdec_pk);
  gather_src_kernel<<<800, 256, 0, stream>>>(emb_bf, source, xs_bf);
  gather_tgt_kernel<<<200, 256, 0, stream>>>(emb_bf, target, xt_bf);
  gemm_abt_bias<<<dim3(8, 400), 256, 0, stream>>>(xs_bf, wihf_bf, b_f, gx_f, 256);
  gemm_abt_bias<<<dim3(8, 400), 256, 0, stream>>>(xs_bf, wihb_bf, b_b, gx_b, 256);
  enc_kernel<<<64, 256, 0, stream>>>(gx_f, gx_b, whh_pk, source_len, hbf_f, hbf_b, ys_cat_u32,
                                     h_final, c_final, ctrs);
  gemm_encout<<<dim3(2, 400), 256, 0, stream>>>((const ushort_t*)ys_cat_u32, wproj_bf, bproj,
                                                enc_outs);
  seqmean_kernel<<<32, 256, 0, stream>>>(enc_outs, source_len, seq_mean);
  init_state_kernel<<<64, 256, 0, stream>>>(h_final, c_final, w2h, b2h, w2c, b2c, h_u32, c_init);
  tmp0_kernel<<<32, 256, 0, stream>>>(h_final, h_u32, seq_mean, wo1, bo1, tmp_u32);
  gemm_abt_bias<<<dim3(8, 100), 256, 0, stream>>>(xt_bf, wihd_bf, dbias, gx_dec, 256);
  gemm_e2<<<dim3(2, 2000), 256, 0, stream>>>(emb_bf, wo2t_bf, e2_bf);
  dec_kernel<<<128, 256, 0, stream>>>(emb, target, source_len, wdec_pk, wpgen, bpgen, wfp, wo1,
                                      bo1, enc_outs, gx_dec, h_u32, c_init, tmp_u32, ctx_part,
                                      z_part, zinv, pgen_b, pexp, ctrs);
  gemm_logits<<<dim3(100, 125), 256, 0, stream>>>((const ushort_t*)(tmp_u32 + 4096), e2_bf, out);
  finalize_kernel<<<1600, 1024, 0, stream>>>(out, pexp, zinv, pgen_b, source_ext);
}

// Round 4
// 6865.089 us; speedup vs baseline: 2.1847x; 1.2180x over previous
//
#include <hip/hip_runtime.h>

#define V_SZ 32000
#define D_SZ 256
#define H_SZ 512
#define B_SZ 16
#define S_SZ 400
#define T_SZ 100
#define G4   2048
#define VX   32050
#define LINE 32  // words per 128B line

typedef unsigned short ushort_t;
typedef __attribute__((ext_vector_type(8))) __bf16 bf16x8;
typedef __attribute__((ext_vector_type(8))) unsigned short ushort8_t;
typedef __attribute__((ext_vector_type(4))) float f32x4;

__device__ __forceinline__ ushort_t f2bf(float x) {
  union { float f; unsigned u; } v; v.f = x;
  unsigned r = v.u + 0x7fffu + ((v.u >> 16) & 1u);
  return (ushort_t)(r >> 16);
}
__device__ __forceinline__ float bf2f(ushort_t x) {
  union { unsigned u; float f; } v; v.u = ((unsigned)x) << 16; return v.f;
}
__device__ __forceinline__ float bfu2f(unsigned x) {
  union { unsigned u; float f; } v; v.u = x << 16; return v.f;
}
__device__ __forceinline__ float sigf(float x) { return 1.0f / (1.0f + __expf(-x)); }
__device__ __forceinline__ float tanh_f(float x) {
  float e = __expf(2.0f * x);
  return 1.0f - 2.0f / (e + 1.0f);
}
__device__ __forceinline__ float dot4(f32x4 a, f32x4 b) {
  return a.x * b.x + a.y * b.y + a.z * b.z + a.w * b.w;
}
// write-through store to device coherence point; readers cold-miss fresh data.
__device__ __forceinline__ void stg(float* p, float v) {
  __hip_atomic_store(p, v, __ATOMIC_RELAXED, __HIP_MEMORY_SCOPE_AGENT);
}
__device__ __forceinline__ void stg_u32(unsigned* p, unsigned v) {
  __hip_atomic_store(p, v, __ATOMIC_RELAXED, __HIP_MEMORY_SCOPE_AGENT);
}

// Grid barrier, broadcast design. Region layout: arrival ctr @ word 0,
// GO line i @ word (i+1)*LINE (16 lines, 128B apart). Blocks fire-and-forget
// atomicAdd arrival; master (cid==0) alone polls arrivals, then broadcasts
// epoch to the 16 GO lines; each block polls one GO line with one wave.
// Per-line contention <= 8 pollers -> no poll storm on the arrival line.
__device__ __forceinline__ void grid_barrier(unsigned* region, int cid, int nb, unsigned pc) {
  asm volatile("s_waitcnt vmcnt(0)" ::: "memory");
  __syncthreads();
  const int tid = threadIdx.x;
  if (tid == 0)
    __hip_atomic_fetch_add(region, 1u, __ATOMIC_RELAXED, __HIP_MEMORY_SCOPE_AGENT);
  if (cid == 0) {
    if (tid < 64) {
      const unsigned tgt = (unsigned)nb * pc;
      for (;;) {
        unsigned v = __hip_atomic_load(region, __ATOMIC_RELAXED, __HIP_MEMORY_SCOPE_AGENT);
        if (v >= tgt) break;
        __builtin_amdgcn_s_sleep(1);
      }
      if (tid < 16)
        __hip_atomic_store(&region[(tid + 1) * LINE], pc, __ATOMIC_RELAXED,
                           __HIP_MEMORY_SCOPE_AGENT);
    }
  } else {
    unsigned* go = &region[((cid & 15) + 1) * LINE];
    if (tid < 64) {
      for (;;) {
        unsigned v = __hip_atomic_load(go, __ATOMIC_RELAXED, __HIP_MEMORY_SCOPE_AGENT);
        if (v >= pc) break;
        __builtin_amdgcn_s_sleep(1);
      }
    }
  }
  __syncthreads();
}

// ---------------- f32 -> bf16 convert ----------------
__global__ __launch_bounds__(256) void cvt_kernel(const float* in, ushort_t* outp, int n) {
  int i = blockIdx.x * 256 + threadIdx.x;
  int stride = gridDim.x * 256;
  for (; i < n; i += stride) outp[i] = f2bf(in[i]);
}

// cols [0,256) of a row-stride-512 matrix -> packed bf16 (2048 x 256)
__global__ __launch_bounds__(256) void cvt_strided_kernel(const float* in, ushort_t* outp) {
  int gid = blockIdx.x * 256 + threadIdx.x;  // 524288
  int r = gid >> 8, d = gid & 255;
  outp[gid] = f2bf(in[(size_t)r * 512 + d]);
}

// wo2t[h][d] = wo2[d][h]  (512 x 256 bf16)
__global__ __launch_bounds__(256) void cvt_wo2t_kernel(const float* wo2, ushort_t* outp) {
  int gid = blockIdx.x * 256 + threadIdx.x;  // 131072
  int h = gid >> 8, d = gid & 255;
  outp[gid] = f2bf(wo2[(size_t)d * 512 + h]);
}

// Wfused[r][c] = sum_d dwih[r][256+d] * wo2[d][c]   (2048 x 512 f32)
__global__ __launch_bounds__(256) void wfused_kernel(const float* dwih, const float* wo2,
                                                     float* wf) {
  __shared__ float xr_s[256];
  int r = blockIdx.x;
  xr_s[threadIdx.x] = dwih[(size_t)r * 512 + 256 + threadIdx.x];
  __syncthreads();
  float a0 = 0, a1 = 0;
  for (int d = 0; d < 256; ++d) {
    float x = xr_s[d];
    a0 += x * wo2[(size_t)d * 512 + threadIdx.x];
    a1 += x * wo2[(size_t)d * 512 + threadIdx.x + 256];
  }
  wf[(size_t)r * 512 + threadIdx.x] = a0;
  wf[(size_t)r * 512 + threadIdx.x + 256] = a1;
}

// wfp[h] = sum_d wpgen[1280+d] * wo2[d][h]
__global__ __launch_bounds__(256) void wfp_kernel(const float* wpgen, const float* wo2,
                                                  float* wfp) {
  int h = blockIdx.x * 256 + threadIdx.x;
  float a = 0;
  for (int d = 0; d < 256; ++d) a += wpgen[1280 + d] * wo2[(size_t)d * 512 + h];
  wfp[h] = a;
}

// pack Whh (both dirs) into per-block wave-major bf16 rows
__global__ __launch_bounds__(256) void pack_whh_kernel(const float* whh_f, const float* whh_b,
                                                       ushort_t* outp) {
  int gid = blockIdx.x * 256 + threadIdx.x;  // 2*2048*512
  int col = gid & 511;
  int p_g = gid >> 9;
  int dir = p_g >> 11, p = p_g & 2047;
  int ub = p >> 6, g = (p >> 4) & 3, u = p & 15;
  const float* src = dir ? whh_b : whh_f;
  outp[gid] = f2bf(src[(size_t)(g * 512 + ub * 16 + u) * 512 + col]);
}

// pack decoder recurrent weights [Whh_dec | Wfused] (2048 x 1024 bf16)
__global__ __launch_bounds__(256) void pack_wdec_kernel(const float* dwhh, const float* wfused,
                                                        ushort_t* outp) {
  int gid = blockIdx.x * 256 + threadIdx.x;  // 2048*1024
  int col = gid & 1023;
  int p = gid >> 10;
  int ub = p >> 4, g = (p >> 2) & 3, u = p & 3;
  int row = g * 512 + ub * 4 + u;
  float v = (col < 512) ? dwhh[(size_t)row * 512 + col] : wfused[(size_t)row * 512 + (col - 512)];
  outp[gid] = f2bf(v);
}

// ---------------- gather embeddings (bf16) ----------------
__global__ __launch_bounds__(256) void gather_src_kernel(const ushort_t* emb_bf, const int* source,
                                                         ushort_t* xs_bf) {
  int gid = blockIdx.x * 256 + threadIdx.x;  // 204800
  int r = gid >> 5, e = gid & 31;
  int s = r >> 4, b = r & 15;
  int tok = source[b * S_SZ + s];
  ((ushort8_t*)xs_bf)[gid] = ((const ushort8_t*)emb_bf)[(size_t)tok * 32 + e];
}
__global__ __launch_bounds__(256) void gather_tgt_kernel(const ushort_t* emb_bf, const int* target,
                                                         ushort_t* xt_bf) {
  int gid = blockIdx.x * 256 + threadIdx.x;  // 51200
  int r = gid >> 5, e = gid & 31;
  int t = r >> 4, b = r & 15;
  int tok = target[b * T_SZ + t];
  ((ushort8_t*)xt_bf)[gid] = ((const ushort8_t*)emb_bf)[(size_t)tok * 32 + e];
}

// ---------------- MFMA helper: one wave computes a 16x64 tile of A(M,K) @ B(N,K)^T ------------
__device__ __forceinline__ void mfma_16x64(const ushort_t* A, const ushort_t* B_, int K,
                                           int m0, int n0, f32x4 acc[4]) {
  const int lane = threadIdx.x & 63;
  const int lr = lane & 15, kh = lane >> 4;
  const ushort_t* ap = A + (size_t)(m0 + lr) * K + kh * 8;
  const ushort_t* bp = B_ + (size_t)(n0 + lr) * K + kh * 8;
  for (int k0 = 0; k0 < K; k0 += 32) {
    bf16x8 av = *(const bf16x8*)(ap + k0);
#pragma unroll
    for (int s = 0; s < 4; ++s) {
      bf16x8 bv = *(const bf16x8*)(bp + (size_t)s * 16 * K + k0);
      acc[s] = __builtin_amdgcn_mfma_f32_16x16x32_bf16(av, bv, acc[s], 0, 0, 0);
    }
  }
}

// ---------------- gates GEMM: out[m][n] = A[m]·B[n] + bias[n], N=2048 ----------------
__global__ __launch_bounds__(256) void gemm_abt_bias(const ushort_t* A, const ushort_t* Bm,
                                                     const float* bias, float* out, int K) {
  int wave = threadIdx.x >> 6;
  int m0 = blockIdx.y * 16;
  int n0 = blockIdx.x * 256 + wave * 64;
  f32x4 acc[4] = {};
  mfma_16x64(A, Bm, K, m0, n0, acc);
  int lane = threadIdx.x & 63, lr = lane & 15, kh = lane >> 4;
#pragma unroll
  for (int s = 0; s < 4; ++s) {
    int n = n0 + s * 16 + lr;
    float bv = bias[n];
#pragma unroll
    for (int i = 0; i < 4; ++i) {
      int m = m0 + kh * 4 + i;
      out[(size_t)m * G4 + n] = acc[s][i] + bv;
    }
  }
}

// ---------------- enc_outs = ys_cat @ Wproj^T + bproj, out layout [b][s][h] ----------------
__global__ __launch_bounds__(256) void gemm_encout(const ushort_t* ys_cat, const ushort_t* wproj_bf,
                                                   const float* bproj, float* enc_outs) {
  int wave = threadIdx.x >> 6;
  int m0 = blockIdx.y * 16;
  int n0 = blockIdx.x * 256 + wave * 64;
  f32x4 acc[4] = {};
  mfma_16x64(ys_cat, wproj_bf, 2 * H_SZ, m0, n0, acc);
  int lane = threadIdx.x & 63, lr = lane & 15, kh = lane >> 4;
#pragma unroll
  for (int s = 0; s < 4; ++s) {
    int n = n0 + s * 16 + lr;
    float bv = bproj[n];
#pragma unroll
    for (int i = 0; i < 4; ++i) {
      int m = m0 + kh * 4 + i;
      int b = m & 15, si = m >> 4;
      enc_outs[((size_t)b * S_SZ + si) * H_SZ + n] = acc[s][i] + bv;
    }
  }
}

// ---------------- E2 = emb @ Wo2  (32000 x 512, bf16) ----------------
__global__ __launch_bounds__(256) void gemm_e2(const ushort_t* emb_bf, const ushort_t* wo2t_bf,
                                               ushort_t* e2) {
  int wave = threadIdx.x >> 6;
  int m0 = blockIdx.y * 16;
  int n0 = blockIdx.x * 256 + wave * 64;
  f32x4 acc[4] = {};
  mfma_16x64(emb_bf, wo2t_bf, 256, m0, n0, acc);
  int lane = threadIdx.x & 63, lr = lane & 15, kh = lane >> 4;
#pragma unroll
  for (int s = 0; s < 4; ++s) {
    int n = n0 + s * 16 + lr;
#pragma unroll
    for (int i = 0; i < 4; ++i) {
      int m = m0 + kh * 4 + i;
      e2[(size_t)m * 512 + n] = f2bf(acc[s][i]);
    }
  }
}

// ---------------- logits = tmp @ E2^T  (K=512), into d_out cols [0,V) ----------------
__global__ __launch_bounds__(256) void gemm_logits(const ushort_t* tmp_bf, const ushort_t* e2_bf,
                                                   float* out) {
  int wave = threadIdx.x >> 6;
  int m0 = blockIdx.x * 16;
  int n0 = blockIdx.y * 256 + wave * 64;
  f32x4 acc[4] = {};
  mfma_16x64(tmp_bf, e2_bf, 512, m0, n0, acc);
  int lane = threadIdx.x & 63, lr = lane & 15, kh = lane >> 4;
#pragma unroll
  for (int s = 0; s < 4; ++s) {
    int n = n0 + s * 16 + lr;
#pragma unroll
    for (int i = 0; i < 4; ++i) {
      int m = m0 + kh * 4 + i;
      out[(size_t)m * VX + n] = acc[s][i];
    }
  }
}

// ---------------- persistent bidirectional encoder LSTM (MFMA) ----------------
// 64 blocks: dir = blk>>5, ub = blk&31 -> units j0=ub*16 .. +16. Wave g handles gate g.
__global__ __launch_bounds__(256) void enc_kernel(const float* gx_f, const float* gx_b,
                                                  const ushort_t* whh_pk, const int* src_len,
                                                  unsigned* hbf_f, unsigned* hbf_b,
                                                  unsigned* ys_cat_u32, float* h_final,
                                                  float* c_final, unsigned* ctrs) {
  __shared__ float gates_s[4 * 16 * 17];
  const int blk = blockIdx.x, tid = threadIdx.x;
  const int dir = blk >> 5, ub = blk & 31, j0 = ub * 16;
  const int g = tid >> 6, lane = tid & 63, lr = lane & 15, kh = lane >> 4;
  const float* gx = dir ? gx_b : gx_f;
  unsigned* hb = dir ? hbf_b : hbf_f;
  unsigned* region = ctrs + dir * 1024;
  const ushort_t* wrow =
      whh_pk + (size_t)(((dir * 32 + ub) * 4 + g) * 16 + lr) * 512 + kh * 8;
  const int b = tid & 15, u = tid >> 4;
  const int len_b = src_len[b];
  float c_reg = 0.0f;

  // prefetch gx for t=0
  float gxa[4];
  {
    const int s0 = dir ? (S_SZ - 1) : 0;
    const float* g0 = gx + (size_t)s0 * (16 * 2048) + g * 512 + j0 + lr;
#pragma unroll
    for (int i = 0; i < 4; ++i) gxa[i] = g0[(size_t)(kh * 4 + i) * 2048];
  }

  for (int t = 0; t < S_SZ; ++t) {
    const int s_pos = dir ? (S_SZ - 1 - t) : t;
    // issue prefetch for t+1 early (hidden under MFMA chain + barrier drain)
    float gxn[4] = {0.f, 0.f, 0.f, 0.f};
    if (t + 1 < S_SZ) {
      const int sn = dir ? (S_SZ - 2 - t) : (t + 1);
      const float* gn = gx + (size_t)sn * (16 * 2048) + g * 512 + j0 + lr;
#pragma unroll
      for (int i = 0; i < 4; ++i) gxn[i] = gn[(size_t)(kh * 4 + i) * 2048];
    }
    f32x4 acc = {0.f, 0.f, 0.f, 0.f};
    const ushort_t* ap = (const ushort_t*)(hb + (size_t)t * 4096) + lr * 512 + kh * 8;
#pragma unroll
    for (int k0 = 0; k0 < 512; k0 += 32)
      acc = __builtin_amdgcn_mfma_f32_16x16x32_bf16(*(const bf16x8*)(ap + k0),
                                                    *(const bf16x8*)(wrow + k0), acc, 0, 0, 0);
#pragma unroll
    for (int i = 0; i < 4; ++i)
      gates_s[(g * 16 + lr) * 17 + kh * 4 + i] = acc[i] + gxa[i];
    __syncthreads();
    // cell update: thread (b, u) owns unit j0+u
    float gi = gates_s[u * 17 + b];
    float gf = gates_s[(16 + u) * 17 + b];
    float gg = gates_s[(32 + u) * 17 + b];
    float go = gates_s[(48 + u) * 17 + b];
    bool msk = s_pos < len_b;
    float cn = sigf(gf) * c_reg + sigf(gi) * tanh_f(gg);
    float hn = sigf(go) * tanh_f(cn);
    float hprev = bf2f(((const ushort_t*)(hb + (size_t)t * 4096))[b * 512 + j0 + u]);
    float hout = msk ? hn : hprev;
    if (msk) c_reg = cn;
    unsigned hbits = (unsigned)f2bf(hout);
    unsigned hpart = __shfl_xor(hbits, 16);
    unsigned ybits = msk ? (unsigned)f2bf(hn) : 0u;
    unsigned ypart = __shfl_xor(ybits, 16);
    if ((u & 1) == 0) {
      stg_u32(&hb[(size_t)(t + 1) * 4096 + b * 256 + ((j0 + u) >> 1)], hbits | (hpart << 16));
      ys_cat_u32[(size_t)(s_pos * 16 + b) * 512 + dir * 256 + ((j0 + u) >> 1)] =
          ybits | (ypart << 16);
    }
    if (t == S_SZ - 1) {
      h_final[dir * 8192 + b * 512 + j0 + u] = hout;
      c_final[dir * 8192 + b * 512 + j0 + u] = c_reg;
    }
    if (t + 1 < S_SZ) grid_barrier(region, ub, 32, (unsigned)(t + 1));
#pragma unroll
    for (int i = 0; i < 4; ++i) gxa[i] = gxn[i];
  }
}

// ---------------- seq_mean ----------------
__global__ __launch_bounds__(256) void seqmean_kernel(const float* enc_outs, const int* src_len,
                                                      float* seq_mean) {
  int b = blockIdx.x >> 1;
  int j = (blockIdx.x & 1) * 256 + threadIdx.x;
  int L = src_len[b];
  float a = 0;
  for (int s = 0; s < L; ++s) a += enc_outs[((size_t)b * S_SZ + s) * H_SZ + j];
  seq_mean[b * 512 + j] = a / (float)L;
}

// ---------------- dec state init: h (bf16 packed) + c (f32) ----------------
__global__ __launch_bounds__(256) void init_state_kernel(const float* h_final, const float* c_final,
                                                         const float* w2h, const float* b2h,
                                                         const float* w2c, const float* b2c,
                                                         unsigned* h_u32, float* c_init) {
  int gid = blockIdx.x * 256 + threadIdx.x;  // 16384
  int half = gid >> 13;
  int idx = gid & 8191;
  int b = idx >> 9, j = idx & 511;
  const float* src = half ? c_final : h_final;
  const float* w = (half ? w2c : w2h) + (size_t)j * 1024;
  float acc = (half ? b2c : b2h)[j];
  const f32x4* s0 = (const f32x4*)(src + b * 512);
  const f32x4* s1 = (const f32x4*)(src + 8192 + b * 512);
  const f32x4* w0 = (const f32x4*)w;
  const f32x4* w1 = w0 + 128;
  float a = 0;
  for (int k = 0; k < 128; ++k) a += dot4(s0[k], w0[k]);
  for (int k = 0; k < 128; ++k) a += dot4(s1[k], w1[k]);
  acc += a;
  if (half) {
    c_init[idx] = acc;
  } else {
    unsigned bits = (unsigned)f2bf(acc);
    unsigned pb2 = __shfl_xor(bits, 1);
    if ((j & 1) == 0) h_u32[b * 256 + (j >> 1)] = bits | (pb2 << 16);
  }
}

// ---------------- tmp0 = tanh([dec_h | seq_mean] @ Wo1^T + bo1) -> tmp slot 0 (bf16) ---------
__global__ __launch_bounds__(256) void tmp0_kernel(const unsigned* h0_u32, const float* seq_mean,
                                                   const float* wo1, const float* bo1,
                                                   unsigned* tmp_u32) {
  int gid = blockIdx.x * 256 + threadIdx.x;  // 8192
  int b = gid >> 9, j = gid & 511;
  const f32x4* x1 = (const f32x4*)(seq_mean + b * 512);
  const f32x4* w0 = (const f32x4*)(wo1 + (size_t)j * 1024);
  const f32x4* w1 = w0 + 128;
  float a = bo1[j];
  float p = 0;
  const ushort_t* h0 = (const ushort_t*)(h0_u32) + b * 512;
  for (int k = 0; k < 128; ++k) {
    f32x4 hv = {bf2f(h0[k * 4]), bf2f(h0[k * 4 + 1]), bf2f(h0[k * 4 + 2]), bf2f(h0[k * 4 + 3])};
    p += dot4(hv, w0[k]);
  }
  for (int k = 0; k < 128; ++k) p += dot4(x1[k], w1[k]);
  float tv = tanh_f(a + p);
  unsigned bits = (unsigned)f2bf(tv);
  unsigned pb2 = __shfl_xor(bits, 1);
  if ((j & 1) == 0) tmp_u32[b * 256 + (j >> 1)] = bits | (pb2 << 16);
}

// ---------------- persistent decoder: 100 steps x 3 phases ----------------
__global__ __launch_bounds__(256) void dec_kernel(
    const float* emb, const int* target, const int* src_len, const ushort_t* wdec_pk,
    const float* wpgen, const float* bpgen, const float* wfp, const float* wo1, const float* bo1,
    const float* enc_outs, const float* gx_dec, unsigned* h_u32, const float* c_init,
    unsigned* tmp_u32, float* ctx_part, float* z_part, float* zinv, float* pgen_o, float* pexp,
    unsigned* ctrs) {
  __shared__ float part_s[4 * 16 * 17];
  __shared__ f32x4 smem4[272];  // h_s(512) + ctx_s(512) + pad
  __shared__ float red_s[8];
  __shared__ float p_s[64];
  float* sm = (float*)smem4;
  unsigned* region = ctrs + 2 * 1024;

  const int blk = blockIdx.x, tid = threadIdx.x;
  const int w = tid >> 6, lane = tid & 63, lr = lane & 15, kh = lane >> 4;
  const int j0 = blk * 4;
  const ushort_t* wrow = wdec_pk + (size_t)(blk * 16 + lr) * 1024 + w * 256 + kh * 8;
  const int b_c = tid & 15, u_c = (tid >> 4) & 3;
  float c_reg = (tid < 64) ? c_init[b_c * 512 + j0 + u_c] : 0.0f;
  const int b_pb = blk >> 3, ch = blk & 7, s0c = ch * 50;
  const int len_pb = src_len[b_pb];
  const int nc = ch;
  unsigned pc = 0;

  for (int t = 0; t < T_SZ; ++t) {
    // ---------- PA: gates via MFMA (K=1024 split over 4 waves) ----------
    {
      // prefetch gx for this step first (independent of MFMA inputs)
      float gxv[4] = {0.f, 0.f, 0.f, 0.f};
      if (tid < 64) {
#pragma unroll
        for (int g2 = 0; g2 < 4; ++g2)
          gxv[g2] = gx_dec[((size_t)t * 16 + b_c) * 2048 + g2 * 512 + j0 + u_c];
      }
      f32x4 acc = {0.f, 0.f, 0.f, 0.f};
      const unsigned* asrc = (w < 2) ? (h_u32 + (size_t)t * 4096) : (tmp_u32 + (size_t)t * 4096);
      const ushort_t* ap = (const ushort_t*)asrc + lr * 512 + (w & 1) * 256 + kh * 8;
#pragma unroll
      for (int k0 = 0; k0 < 256; k0 += 32)
        acc = __builtin_amdgcn_mfma_f32_16x16x32_bf16(*(const bf16x8*)(ap + k0),
                                                      *(const bf16x8*)(wrow + k0), acc, 0, 0, 0);
#pragma unroll
      for (int i = 0; i < 4; ++i) part_s[(w * 16 + lr) * 17 + kh * 4 + i] = acc[i];
      __syncthreads();
      if (tid < 64) {
        float gt[4];
#pragma unroll
        for (int g2 = 0; g2 < 4; ++g2) {
          int p = g2 * 4 + u_c;
          float a = gxv[g2];
#pragma unroll
          for (int w2 = 0; w2 < 4; ++w2) a += part_s[(w2 * 16 + p) * 17 + b_c];
          gt[g2] = a;
        }
        float cn = sigf(gt[1]) * c_reg + sigf(gt[0]) * tanh_f(gt[2]);
        c_reg = cn;
        float hn = sigf(gt[3]) * tanh_f(cn);
        unsigned bits = (unsigned)f2bf(hn);
        unsigned pb2 = __shfl_xor(bits, 16);
        if ((u_c & 1) == 0)
          stg_u32(&h_u32[(size_t)(t + 1) * 4096 + b_c * 256 + ((j0 + u_c) >> 1)],
                  bits | (pb2 << 16));
      }
    }
    grid_barrier(region, blk, 128, ++pc);
    // ---------- PB: score chunks -> pexp, z_part, ctx_part ----------
    {
      if (tid < 128) {
        unsigned v0 = h_u32[(size_t)(t + 1) * 4096 + b_pb * 256 + tid * 2];
        unsigned v1 = h_u32[(size_t)(t + 1) * 4096 + b_pb * 256 + tid * 2 + 1];
        f32x4 hv = {bfu2f(v0 & 0xffffu), bfu2f(v0 >> 16), bfu2f(v1 & 0xffffu), bfu2f(v1 >> 16)};
        ((f32x4*)sm)[tid] = hv;
      }
      __syncthreads();
      int st = tid >> 2, kq = tid & 3;
      if (st < 50) {
        const f32x4* er =
            (const f32x4*)(enc_outs + ((size_t)b_pb * S_SZ + s0c + st) * H_SZ) + kq * 32;
        const f32x4* hr = (const f32x4*)sm + kq * 32;
        float sc = 0;
        for (int k = 0; k < 32; ++k) sc += dot4(hr[k], er[k]);
        sc += __shfl_xor(sc, 1);
        sc += __shfl_xor(sc, 2);
        if (kq == 0) {
          int s_abs = s0c + st;
          float p = (s_abs < len_pb) ? __expf(sc) : 0.0f;
          p_s[st] = p;
          pexp[((size_t)t * 16 + b_pb) * S_SZ + s_abs] = p;
        }
      }
      __syncthreads();
      if (tid == 0) {
        float z = 0;
        for (int s = 0; s < 50; ++s) z += p_s[s];
        stg(&z_part[((size_t)t * 16 + b_pb) * 8 + ch], z);
      }
      float a0 = 0, a1 = 0;
      for (int s = 0; s < 50; ++s) {
        float p = p_s[s];
        const float* er = enc_outs + ((size_t)b_pb * S_SZ + s0c + s) * H_SZ;
        a0 += p * er[tid];
        a1 += p * er[tid + 256];
      }
      float* cp = ctx_part + (((size_t)t * 16 + b_pb) * 8 + ch) * 512;
      stg(&cp[tid], a0);
      stg(&cp[tid + 256], a1);
    }
    grid_barrier(region, blk, 128, ++pc);
    // ---------- PC: combine ctx + pgen + tmp ----------
    {
      float* h_s = sm;
      float* ctx_s = sm + 512;
      const float* zp = z_part + ((size_t)t * 16 + b_pb) * 8;
      float z = 0;
#pragma unroll
      for (int c2 = 0; c2 < 8; ++c2) z += zp[c2];
      float inv = 1.0f / z;
      if (tid < 128) {
        unsigned v0 = h_u32[(size_t)(t + 1) * 4096 + b_pb * 256 + tid * 2];
        unsigned v1 = h_u32[(size_t)(t + 1) * 4096 + b_pb * 256 + tid * 2 + 1];
        f32x4 hv = {bfu2f(v0 & 0xffffu), bfu2f(v0 >> 16), bfu2f(v1 & 0xffffu), bfu2f(v1 >> 16)};
        ((f32x4*)h_s)[tid] = hv;
      }
      const float* cpb = ctx_part + ((size_t)t * 16 + b_pb) * 8 * 512;
      float c0 = 0, c1 = 0;
#pragma unroll
      for (int c2 = 0; c2 < 8; ++c2) {
        c0 += cpb[c2 * 512 + tid];
        c1 += cpb[c2 * 512 + tid + 256];
      }
      ctx_s[tid] = c0 * inv;
      ctx_s[tid + 256] = c1 * inv;
      __syncthreads();
      int tok = target[b_pb * T_SZ + t];
      const ushort_t* tmpp = (const ushort_t*)(tmp_u32 + (size_t)t * 4096) + b_pb * 512;
      float tp0 = bf2f(tmpp[tid]);
      float tp1 = bf2f(tmpp[tid + 256]);
      float pg = wpgen[tid] * ctx_s[tid] + wpgen[tid + 256] * ctx_s[tid + 256] +
                 wpgen[512 + tid] * h_s[tid] + wpgen[512 + tid + 256] * h_s[tid + 256] +
                 wpgen[1024 + tid] * emb[(size_t)tok * 256 + tid] + wfp[tid] * tp0 +
                 wfp[tid + 256] * tp1;
#pragma unroll
      for (int o = 32; o; o >>= 1) pg += __shfl_xor(pg, o);
      if (lane == 0) red_s[w] = pg;
      __syncthreads();
      if (nc == 0 && tid == 0) {
        pgen_o[t * 16 + b_pb] = sigf(red_s[0] + red_s[1] + red_s[2] + red_s[3] + bpgen[0]);
        zinv[t * 16 + b_pb] = inv;
      }
      int nidx = tid >> 2, kq = tid & 3;
      int n = nc * 64 + nidx;
      const f32x4* wrp = (const f32x4*)(wo1 + (size_t)n * 1024) + kq * 64;
      const f32x4* xr2 =
          (kq < 2) ? ((const f32x4*)h_s + kq * 64) : ((const f32x4*)ctx_s + (kq - 2) * 64);
      float a = 0;
#pragma unroll 4
      for (int k = 0; k < 64; ++k) a += dot4(xr2[k], wrp[k]);
      a += __shfl_xor(a, 1);
      a += __shfl_xor(a, 2);
      float tv = tanh_f(a + bo1[n]);
      unsigned bits = (unsigned)f2bf(tv);
      unsigned pbits = __shfl_xor(bits, 4);
      if (kq == 0 && (nidx & 1) == 0)
        stg_u32(&tmp_u32[(size_t)(t + 1) * 4096 + b_pb * 256 + ((nc * 64 + nidx) >> 1)],
                bits | (pbits << 16));
    }
    if (t + 1 < T_SZ) grid_barrier(region, blk, 128, ++pc);
  }
}

// ---------------- per (t,b) row softmax + copy-scatter + log ----------------
__global__ __launch_bounds__(1024) void finalize_kernel(float* out, const float* pexp,
                                                        const float* zinv, const float* pgen_i,
                                                        const int* src_ext) {
  __shared__ float scat[VX];
  __shared__ float red[64];
  const int row = blockIdx.x;
  const int b = row & 15;
  const int tid = threadIdx.x;
  for (int i = tid; i < VX; i += 1024) scat[i] = 0.0f;
  __syncthreads();
  const float pg = pgen_i[row];
  const float inv = zinv[row];
  if (tid < S_SZ) {
    float v = (1.0f - pg) * pexp[(size_t)row * S_SZ + tid] * inv;
    int col = src_ext[b * S_SZ + tid];
    atomicAdd(&scat[col], v);
  }
  float* orow = out + (size_t)row * VX;
  float l[32];
  float mx = -3.4e38f;
#pragma unroll
  for (int i2 = 0; i2 < 32; ++i2) {
    int col = tid + (i2 << 10);
    l[i2] = (col < V_SZ) ? orow[col] : -3.4e38f;
    mx = fmaxf(mx, l[i2]);
  }
#pragma unroll
  for (int o = 32; o; o >>= 1) mx = fmaxf(mx, __shfl_xor(mx, o));
  if ((tid & 63) == 0) red[16 + (tid >> 6)] = mx;
  __syncthreads();
  if (tid == 0) {
    float m2 = red[16];
    for (int w = 1; w < 16; ++w) m2 = fmaxf(m2, red[16 + w]);
    red[0] = m2;
  }
  __syncthreads();
  const float gmx = red[0];
  float se = 0.0f;
#pragma unroll
  for (int i2 = 0; i2 < 32; ++i2) {
    int col = tid + (i2 << 10);
    if (col < V_SZ) {
      l[i2] = __expf(l[i2] - gmx);
      se += l[i2];
    }
  }
#pragma unroll
  for (int o = 32; o; o >>= 1) se += __shfl_xor(se, o);
  if ((tid & 63) == 0) red[32 + (tid >> 6)] = se;
  __syncthreads();
  if (tid == 0) {
    float s2 = 0;
    for (int w = 0; w < 16; ++w) s2 += red[32 + w];
    red[1] = s2;
  }
  __syncthreads();
  const float scale = pg / red[1];
#pragma unroll
  for (int i2 = 0; i2 < 32; ++i2) {
    int col = tid + (i2 << 10);
    if (col < VX) {
      float base = (col < V_SZ) ? l[i2] * scale : 0.0f;
      orow[col] = __logf(base + scat[col] + 1e-20f);
    }
  }
}

extern "C" void kernel_launch(void* const* d_in, const int* in_sizes, int n_in, void* d_out,
                              int out_size, void* d_ws, size_t ws_size, hipStream_t stream) {
  (void)in_sizes; (void)n_in; (void)out_size; (void)ws_size;
  const int* source = (const int*)d_in[0];
  const int* source_ext = (const int*)d_in[1];
  const int* source_len = (const int*)d_in[2];
  const int* target = (const int*)d_in[3];
  const float* emb = (const float*)d_in[4];
  const float* wih_f = (const float*)d_in[5];
  const float* whh_f = (const float*)d_in[6];
  const float* b_f = (const float*)d_in[7];
  const float* wih_b = (const float*)d_in[8];
  const float* whh_b = (const float*)d_in[9];
  const float* b_b = (const float*)d_in[10];
  const float* wproj = (const float*)d_in[11];
  const float* bproj = (const float*)d_in[12];
  const float* w2h = (const float*)d_in[13];
  const float* b2h = (const float*)d_in[14];
  const float* w2c = (const float*)d_in[15];
  const float* b2c = (const float*)d_in[16];
  const float* wo1 = (const float*)d_in[17];
  const float* bo1 = (const float*)d_in[18];
  const float* wo2 = (const float*)d_in[19];
  const float* dwih = (const float*)d_in[20];
  const float* dwhh = (const float*)d_in[21];
  const float* dbias = (const float*)d_in[22];
  const float* wpgen = (const float*)d_in[23];
  const float* bpgen = (const float*)d_in[24];
  float* out = (float*)d_out;

  size_t off = 0;
  char* wsb = (char*)d_ws;
  auto alloc = [&](size_t bytes) -> void* {
    void* p = wsb + off;
    off += (bytes + 255) & ~(size_t)255;
    return p;
  };
  unsigned* ctrs = (unsigned*)alloc(3 * 4096);  // cohorts: enc_f, enc_b, dec (4KB each)
  ushort_t* emb_bf = (ushort_t*)alloc((size_t)V_SZ * D_SZ * 2);
  ushort_t* wihf_bf = (ushort_t*)alloc((size_t)G4 * D_SZ * 2);
  ushort_t* wihb_bf = (ushort_t*)alloc((size_t)G4 * D_SZ * 2);
  ushort_t* wihd_bf = (ushort_t*)alloc((size_t)G4 * D_SZ * 2);
  ushort_t* wproj_bf = (ushort_t*)alloc((size_t)H_SZ * 2 * H_SZ * 2);
  ushort_t* wo2t_bf = (ushort_t*)alloc((size_t)H_SZ * D_SZ * 2);
  float* wfused = (float*)alloc((size_t)G4 * H_SZ * 4);
  float* wfp = (float*)alloc(512 * 4);
  ushort_t* whh_pk = (ushort_t*)alloc((size_t)2 * G4 * H_SZ * 2);
  ushort_t* wdec_pk = (ushort_t*)alloc((size_t)G4 * 1024 * 2);
  ushort_t* xs_bf = (ushort_t*)alloc((size_t)S_SZ * B_SZ * D_SZ * 2);
  ushort_t* xt_bf = (ushort_t*)alloc((size_t)T_SZ * B_SZ * D_SZ * 2);
  float* gx_f = (float*)alloc((size_t)S_SZ * B_SZ * G4 * 4);  // aliased by e2_bf after enc
  float* gx_b = (float*)alloc((size_t)S_SZ * B_SZ * G4 * 4);  // aliased by gx_dec/ctx_part
  unsigned* hbf_f = (unsigned*)alloc((size_t)(S_SZ + 1) * 4096 * 4);
  unsigned* hbf_b = (unsigned*)alloc((size_t)(S_SZ + 1) * 4096 * 4);
  unsigned* ys_cat_u32 = (unsigned*)alloc((size_t)S_SZ * B_SZ * 512 * 4);
  float* h_final = (float*)alloc((size_t)2 * B_SZ * H_SZ * 4);
  float* c_final = (float*)alloc((size_t)2 * B_SZ * H_SZ * 4);
  float* enc_outs = (float*)alloc((size_t)B_SZ * S_SZ * H_SZ * 4);
  float* seq_mean = (float*)alloc((size_t)B_SZ * H_SZ * 4);
  unsigned* h_u32 = (unsigned*)alloc((size_t)(T_SZ + 1) * 4096 * 4);
  float* c_init = (float*)alloc((size_t)B_SZ * H_SZ * 4);
  unsigned* tmp_u32 = (unsigned*)alloc((size_t)(T_SZ + 1) * 4096 * 4);
  float* z_part = (float*)alloc((size_t)T_SZ * B_SZ * 8 * 4);
  float* zinv = (float*)alloc((size_t)T_SZ * B_SZ * 4);
  float* pgen_b = (float*)alloc((size_t)T_SZ * B_SZ * 4);
  float* pexp = (float*)alloc((size_t)T_SZ * B_SZ * S_SZ * 4);
  // aliases into dead-after-encoder regions
  ushort_t* e2_bf = (ushort_t*)gx_f;                     // 32.8 MB <= 52.4 MB
  float* gx_dec = gx_b;                                  // 13.1 MB
  float* ctx_part = gx_b + (size_t)1600 * 2048;          // 26.2 MB (fits in 52.4-13.1)

  hipMemsetAsync(ctrs, 0, 3 * 4096, stream);           // barrier regions
  hipMemsetAsync(hbf_f, 0, 4096 * 4, stream);          // enc h slot 0 (dir f)
  hipMemsetAsync(hbf_b, 0, 4096 * 4, stream);          // enc h slot 0 (dir b)

  cvt_kernel<<<2048, 256, 0, stream>>>(emb, emb_bf, V_SZ * D_SZ);
  cvt_kernel<<<2048, 256, 0, stream>>>(wih_f, wihf_bf, G4 * D_SZ);
  cvt_kernel<<<2048, 256, 0, stream>>>(wih_b, wihb_bf, G4 * D_SZ);
  cvt_kernel<<<2048, 256, 0, stream>>>(wproj, wproj_bf, H_SZ * 2 * H_SZ);
  cvt_strided_kernel<<<2048, 256, 0, stream>>>(dwih, wihd_bf);
  cvt_wo2t_kernel<<<512, 256, 0, stream>>>(wo2, wo2t_bf);
  wfused_kernel<<<2048, 256, 0, stream>>>(dwih, wo2, wfused);
  wfp_kernel<<<2, 256, 0, stream>>>(wpgen, wo2, wfp);
  pack_whh_kernel<<<8192, 256, 0, stream>>>(whh_f, whh_b, whh_pk);
  pack_wdec_kernel<<<8192, 256, 0, stream>>>(dwhh, wfused, wdec_pk);
  gather_src_kernel<<<800, 256, 0, stream>>>(emb_bf, source, xs_bf);
  gather_tgt_kernel<<<200, 256, 0, stream>>>(emb_bf, target, xt_bf);
  gemm_abt_bias<<<dim3(8, 400), 256, 0, stream>>>(xs_bf, wihf_bf, b_f, gx_f, 256);
  gemm_abt_bias<<<dim3(8, 400), 256, 0, stream>>>(xs_bf, wihb_bf, b_b, gx_b, 256);
  enc_kernel<<<64, 256, 0, stream>>>(gx_f, gx_b, whh_pk, source_len, hbf_f, hbf_b, ys_cat_u32,
                                     h_final, c_final, ctrs);
  gemm_encout<<<dim3(2, 400), 256, 0, stream>>>((const ushort_t*)ys_cat_u32, wproj_bf, bproj,
                                                enc_outs);
  seqmean_kernel<<<32, 256, 0, stream>>>(enc_outs, source_len, seq_mean);
  init_state_kernel<<<64, 256, 0, stream>>>(h_final, c_final, w2h, b2h, w2c, b2c, h_u32, c_init);
  tmp0_kernel<<<32, 256, 0, stream>>>(h_u32, seq_mean, wo1, bo1, tmp_u32);
  gemm_abt_bias<<<dim3(8, 100), 256, 0, stream>>>(xt_bf, wihd_bf, dbias, gx_dec, 256);
  gemm_e2<<<dim3(2, 2000), 256, 0, stream>>>(emb_bf, wo2t_bf, e2_bf);
  dec_kernel<<<128, 256, 0, stream>>>(emb, target, source_len, wdec_pk, wpgen, bpgen, wfp, wo1,
                                      bo1, enc_outs, gx_dec, h_u32, c_init, tmp_u32, ctx_part,
                                      z_part, zinv, pgen_b, pexp, ctrs);
  gemm_logits<<<dim3(100, 125), 256, 0, stream>>>((const ushort_t*)(tmp_u32 + 4096), e2_bf, out);
  finalize_kernel<<<1600, 1024, 0, stream>>>(out, pexp, zinv, pgen_b, source_ext);
}

// Round 5
// 6620.596 us; speedup vs baseline: 2.2654x; 1.0369x over previous
//
#include <hip/hip_runtime.h>

#define V_SZ 32000
#define D_SZ 256
#define H_SZ 512
#define B_SZ 16
#define S_SZ 400
#define T_SZ 100
#define G4   2048
#define VX   32050
#define LINE 32  // words per 128B line

typedef unsigned short ushort_t;
typedef __attribute__((ext_vector_type(8))) __bf16 bf16x8;
typedef __attribute__((ext_vector_type(8))) unsigned short ushort8_t;
typedef __attribute__((ext_vector_type(4))) float f32x4;

__device__ __forceinline__ ushort_t f2bf(float x) {
  union { float f; unsigned u; } v; v.f = x;
  unsigned r = v.u + 0x7fffu + ((v.u >> 16) & 1u);
  return (ushort_t)(r >> 16);
}
__device__ __forceinline__ float bf2f(ushort_t x) {
  union { unsigned u; float f; } v; v.u = ((unsigned)x) << 16; return v.f;
}
__device__ __forceinline__ float bfu2f(unsigned x) {
  union { unsigned u; float f; } v; v.u = x << 16; return v.f;
}
__device__ __forceinline__ float sigf(float x) { return 1.0f / (1.0f + __expf(-x)); }
__device__ __forceinline__ float tanh_f(float x) {
  float e = __expf(2.0f * x);
  return 1.0f - 2.0f / (e + 1.0f);
}
__device__ __forceinline__ float dot4(f32x4 a, f32x4 b) {
  return a.x * b.x + a.y * b.y + a.z * b.z + a.w * b.w;
}
// write-through store to device coherence point; readers cold-miss fresh data.
__device__ __forceinline__ void stg(float* p, float v) {
  __hip_atomic_store(p, v, __ATOMIC_RELAXED, __HIP_MEMORY_SCOPE_AGENT);
}
__device__ __forceinline__ void stg_u32(unsigned* p, unsigned v) {
  __hip_atomic_store(p, v, __ATOMIC_RELAXED, __HIP_MEMORY_SCOPE_AGENT);
}

// Grid barrier, broadcast design v2. Region layout (128B lines):
//   arrival line i  @ word i*LINE,      i in [0,8)   (block cid adds to line cid&7)
//   GO line j       @ word (8+j)*LINE,  j in [0,16)
// Arrivals spread over 8 lines (16 adds/line at nb=128 -> parallel IC slices).
// Master (cid 0) polls all 8 lines with 8 lanes, then broadcasts epoch to the
// 16 GO lines; every other block polls one GO line with one wave (1 req/wave).
__device__ __forceinline__ void grid_barrier(unsigned* region, int cid, int nb, unsigned pc) {
  asm volatile("s_waitcnt vmcnt(0)" ::: "memory");
  __syncthreads();
  const int tid = threadIdx.x;
  if (tid == 0)
    __hip_atomic_fetch_add(&region[(cid & 7) * LINE], 1u, __ATOMIC_RELAXED,
                           __HIP_MEMORY_SCOPE_AGENT);
  if (cid == 0) {
    if (tid < 64) {
      const unsigned tgt = (unsigned)(nb >> 3) * pc;
      for (;;) {
        unsigned v = tgt;
        if (tid < 8)
          v = __hip_atomic_load(&region[tid * LINE], __ATOMIC_RELAXED, __HIP_MEMORY_SCOPE_AGENT);
        if (__all(v >= tgt)) break;
        __builtin_amdgcn_s_sleep(1);
      }
      if (tid < 16)
        __hip_atomic_store(&region[(8 + tid) * LINE], pc, __ATOMIC_RELAXED,
                           __HIP_MEMORY_SCOPE_AGENT);
    }
  } else {
    unsigned* go = &region[(8 + (cid & 15)) * LINE];
    if (tid < 64) {
      while (__hip_atomic_load(go, __ATOMIC_RELAXED, __HIP_MEMORY_SCOPE_AGENT) < pc)
        __builtin_amdgcn_s_sleep(1);
    }
  }
  __syncthreads();
}

// ---------------- f32 -> bf16 convert ----------------
__global__ __launch_bounds__(256) void cvt_kernel(const float* in, ushort_t* outp, int n) {
  int i = blockIdx.x * 256 + threadIdx.x;
  int stride = gridDim.x * 256;
  for (; i < n; i += stride) outp[i] = f2bf(in[i]);
}

// cols [0,256) of a row-stride-512 matrix -> packed bf16 (2048 x 256)
__global__ __launch_bounds__(256) void cvt_strided_kernel(const float* in, ushort_t* outp) {
  int gid = blockIdx.x * 256 + threadIdx.x;  // 524288
  int r = gid >> 8, d = gid & 255;
  outp[gid] = f2bf(in[(size_t)r * 512 + d]);
}

// wo2t[h][d] = wo2[d][h]  (512 x 256 bf16)
__global__ __launch_bounds__(256) void cvt_wo2t_kernel(const float* wo2, ushort_t* outp) {
  int gid = blockIdx.x * 256 + threadIdx.x;  // 131072
  int h = gid >> 8, d = gid & 255;
  outp[gid] = f2bf(wo2[(size_t)d * 512 + h]);
}

// Wfused[r][c] = sum_d dwih[r][256+d] * wo2[d][c]   (2048 x 512 f32)
__global__ __launch_bounds__(256) void wfused_kernel(const float* dwih, const float* wo2,
                                                     float* wf) {
  __shared__ float xr_s[256];
  int r = blockIdx.x;
  xr_s[threadIdx.x] = dwih[(size_t)r * 512 + 256 + threadIdx.x];
  __syncthreads();
  float a0 = 0, a1 = 0;
  for (int d = 0; d < 256; ++d) {
    float x = xr_s[d];
    a0 += x * wo2[(size_t)d * 512 + threadIdx.x];
    a1 += x * wo2[(size_t)d * 512 + threadIdx.x + 256];
  }
  wf[(size_t)r * 512 + threadIdx.x] = a0;
  wf[(size_t)r * 512 + threadIdx.x + 256] = a1;
}

// wfp[h] = sum_d wpgen[1280+d] * wo2[d][h]
__global__ __launch_bounds__(256) void wfp_kernel(const float* wpgen, const float* wo2,
                                                  float* wfp) {
  int h = blockIdx.x * 256 + threadIdx.x;
  float a = 0;
  for (int d = 0; d < 256; ++d) a += wpgen[1280 + d] * wo2[(size_t)d * 512 + h];
  wfp[h] = a;
}

// pack Whh (both dirs) into per-block wave-major bf16 rows
__global__ __launch_bounds__(256) void pack_whh_kernel(const float* whh_f, const float* whh_b,
                                                       ushort_t* outp) {
  int gid = blockIdx.x * 256 + threadIdx.x;  // 2*2048*512
  int col = gid & 511;
  int p_g = gid >> 9;
  int dir = p_g >> 11, p = p_g & 2047;
  int ub = p >> 6, g = (p >> 4) & 3, u = p & 15;
  const float* src = dir ? whh_b : whh_f;
  outp[gid] = f2bf(src[(size_t)(g * 512 + ub * 16 + u) * 512 + col]);
}

// pack decoder recurrent weights [Whh_dec | Wfused] (2048 x 1024 bf16)
__global__ __launch_bounds__(256) void pack_wdec_kernel(const float* dwhh, const float* wfused,
                                                        ushort_t* outp) {
  int gid = blockIdx.x * 256 + threadIdx.x;  // 2048*1024
  int col = gid & 1023;
  int p = gid >> 10;
  int ub = p >> 4, g = (p >> 2) & 3, u = p & 3;
  int row = g * 512 + ub * 4 + u;
  float v = (col < 512) ? dwhh[(size_t)row * 512 + col] : wfused[(size_t)row * 512 + (col - 512)];
  outp[gid] = f2bf(v);
}

// gxT[(t*2048 + r)*16 + b] = gx_dec[(t*16+b)*2048 + r]
__global__ __launch_bounds__(256) void gxT_kernel(const float* gx, float* gxT) {
  int t = blockIdx.y;
  int r = blockIdx.x * 256 + threadIdx.x;
  float v[16];
#pragma unroll
  for (int b = 0; b < 16; ++b) v[b] = gx[((size_t)t * 16 + b) * G4 + r];
  f32x4* dst = (f32x4*)(gxT + ((size_t)t * G4 + r) * 16);
#pragma unroll
  for (int q = 0; q < 4; ++q) {
    f32x4 w = {v[q * 4], v[q * 4 + 1], v[q * 4 + 2], v[q * 4 + 3]};
    dst[q] = w;
  }
}

// ---------------- gather embeddings (bf16) ----------------
__global__ __launch_bounds__(256) void gather_src_kernel(const ushort_t* emb_bf, const int* source,
                                                         ushort_t* xs_bf) {
  int gid = blockIdx.x * 256 + threadIdx.x;  // 204800
  int r = gid >> 5, e = gid & 31;
  int s = r >> 4, b = r & 15;
  int tok = source[b * S_SZ + s];
  ((ushort8_t*)xs_bf)[gid] = ((const ushort8_t*)emb_bf)[(size_t)tok * 32 + e];
}
__global__ __launch_bounds__(256) void gather_tgt_kernel(const ushort_t* emb_bf, const int* target,
                                                         ushort_t* xt_bf) {
  int gid = blockIdx.x * 256 + threadIdx.x;  // 51200
  int r = gid >> 5, e = gid & 31;
  int t = r >> 4, b = r & 15;
  int tok = target[b * T_SZ + t];
  ((ushort8_t*)xt_bf)[gid] = ((const ushort8_t*)emb_bf)[(size_t)tok * 32 + e];
}

// ---------------- MFMA helper: one wave computes a 16x64 tile of A(M,K) @ B(N,K)^T ------------
__device__ __forceinline__ void mfma_16x64(const ushort_t* A, const ushort_t* B_, int K,
                                           int m0, int n0, f32x4 acc[4]) {
  const int lane = threadIdx.x & 63;
  const int lr = lane & 15, kh = lane >> 4;
  const ushort_t* ap = A + (size_t)(m0 + lr) * K + kh * 8;
  const ushort_t* bp = B_ + (size_t)(n0 + lr) * K + kh * 8;
  for (int k0 = 0; k0 < K; k0 += 32) {
    bf16x8 av = *(const bf16x8*)(ap + k0);
#pragma unroll
    for (int s = 0; s < 4; ++s) {
      bf16x8 bv = *(const bf16x8*)(bp + (size_t)s * 16 * K + k0);
      acc[s] = __builtin_amdgcn_mfma_f32_16x16x32_bf16(av, bv, acc[s], 0, 0, 0);
    }
  }
}

// ---------------- gates GEMM: out[m][n] = A[m]·B[n] + bias[n], N=2048 ----------------
__global__ __launch_bounds__(256) void gemm_abt_bias(const ushort_t* A, const ushort_t* Bm,
                                                     const float* bias, float* out, int K) {
  int wave = threadIdx.x >> 6;
  int m0 = blockIdx.y * 16;
  int n0 = blockIdx.x * 256 + wave * 64;
  f32x4 acc[4] = {};
  mfma_16x64(A, Bm, K, m0, n0, acc);
  int lane = threadIdx.x & 63, lr = lane & 15, kh = lane >> 4;
#pragma unroll
  for (int s = 0; s < 4; ++s) {
    int n = n0 + s * 16 + lr;
    float bv = bias[n];
#pragma unroll
    for (int i = 0; i < 4; ++i) {
      int m = m0 + kh * 4 + i;
      out[(size_t)m * G4 + n] = acc[s][i] + bv;
    }
  }
}

// ---------------- enc_outs = ys_cat @ Wproj^T + bproj, out layout [b][s][h] ----------------
__global__ __launch_bounds__(256) void gemm_encout(const ushort_t* ys_cat, const ushort_t* wproj_bf,
                                                   const float* bproj, float* enc_outs) {
  int wave = threadIdx.x >> 6;
  int m0 = blockIdx.y * 16;
  int n0 = blockIdx.x * 256 + wave * 64;
  f32x4 acc[4] = {};
  mfma_16x64(ys_cat, wproj_bf, 2 * H_SZ, m0, n0, acc);
  int lane = threadIdx.x & 63, lr = lane & 15, kh = lane >> 4;
#pragma unroll
  for (int s = 0; s < 4; ++s) {
    int n = n0 + s * 16 + lr;
    float bv = bproj[n];
#pragma unroll
    for (int i = 0; i < 4; ++i) {
      int m = m0 + kh * 4 + i;
      int b = m & 15, si = m >> 4;
      enc_outs[((size_t)b * S_SZ + si) * H_SZ + n] = acc[s][i] + bv;
    }
  }
}

// ---------------- E2 = emb @ Wo2  (32000 x 512, bf16) ----------------
__global__ __launch_bounds__(256) void gemm_e2(const ushort_t* emb_bf, const ushort_t* wo2t_bf,
                                               ushort_t* e2) {
  int wave = threadIdx.x >> 6;
  int m0 = blockIdx.y * 16;
  int n0 = blockIdx.x * 256 + wave * 64;
  f32x4 acc[4] = {};
  mfma_16x64(emb_bf, wo2t_bf, 256, m0, n0, acc);
  int lane = threadIdx.x & 63, lr = lane & 15, kh = lane >> 4;
#pragma unroll
  for (int s = 0; s < 4; ++s) {
    int n = n0 + s * 16 + lr;
#pragma unroll
    for (int i = 0; i < 4; ++i) {
      int m = m0 + kh * 4 + i;
      e2[(size_t)m * 512 + n] = f2bf(acc[s][i]);
    }
  }
}

// ---------------- logits = tmp @ E2^T  (K=512), into d_out cols [0,V) ----------------
__global__ __launch_bounds__(256) void gemm_logits(const ushort_t* tmp_bf, const ushort_t* e2_bf,
                                                   float* out) {
  int wave = threadIdx.x >> 6;
  int m0 = blockIdx.x * 16;
  int n0 = blockIdx.y * 256 + wave * 64;
  f32x4 acc[4] = {};
  mfma_16x64(tmp_bf, e2_bf, 512, m0, n0, acc);
  int lane = threadIdx.x & 63, lr = lane & 15, kh = lane >> 4;
#pragma unroll
  for (int s = 0; s < 4; ++s) {
    int n = n0 + s * 16 + lr;
#pragma unroll
    for (int i = 0; i < 4; ++i) {
      int m = m0 + kh * 4 + i;
      out[(size_t)m * VX + n] = acc[s][i];
    }
  }
}

// ---------------- persistent bidirectional encoder LSTM (MFMA) ----------------
// 64 blocks: dir = blk>>5, ub = blk&31 -> units j0=ub*16 .. +16. Wave g handles gate g.
__global__ __launch_bounds__(256) void enc_kernel(const float* gx_f, const float* gx_b,
                                                  const ushort_t* whh_pk, const int* src_len,
                                                  unsigned* hbf_f, unsigned* hbf_b,
                                                  unsigned* ys_cat_u32, float* h_final,
                                                  float* c_final, unsigned* ctrs) {
  __shared__ float gates_s[4 * 16 * 17];
  const int blk = blockIdx.x, tid = threadIdx.x;
  const int dir = blk >> 5, ub = blk & 31, j0 = ub * 16;
  const int g = tid >> 6, lane = tid & 63, lr = lane & 15, kh = lane >> 4;
  const float* gx = dir ? gx_b : gx_f;
  unsigned* hb = dir ? hbf_b : hbf_f;
  unsigned* region = ctrs + dir * 1024;
  const ushort_t* wrow =
      whh_pk + (size_t)(((dir * 32 + ub) * 4 + g) * 16 + lr) * 512 + kh * 8;
  const int b = tid & 15, u = tid >> 4;
  const int len_b = src_len[b];
  float c_reg = 0.0f, h_reg = 0.0f;

  // prefetch gx for t=0
  float gxa[4];
  {
    const int s0 = dir ? (S_SZ - 1) : 0;
    const float* g0 = gx + (size_t)s0 * (16 * 2048) + g * 512 + j0 + lr;
#pragma unroll
    for (int i = 0; i < 4; ++i) gxa[i] = g0[(size_t)(kh * 4 + i) * 2048];
  }

  for (int t = 0; t < S_SZ; ++t) {
    const int s_pos = dir ? (S_SZ - 1 - t) : t;
    // issue prefetch for t+1 early (hidden under MFMA chain + barrier drain)
    float gxn[4] = {0.f, 0.f, 0.f, 0.f};
    if (t + 1 < S_SZ) {
      const int sn = dir ? (S_SZ - 2 - t) : (t + 1);
      const float* gn = gx + (size_t)sn * (16 * 2048) + g * 512 + j0 + lr;
#pragma unroll
      for (int i = 0; i < 4; ++i) gxn[i] = gn[(size_t)(kh * 4 + i) * 2048];
    }
    f32x4 acc = {0.f, 0.f, 0.f, 0.f};
    const ushort_t* ap = (const ushort_t*)(hb + (size_t)t * 4096) + lr * 512 + kh * 8;
#pragma unroll
    for (int k0 = 0; k0 < 512; k0 += 32)
      acc = __builtin_amdgcn_mfma_f32_16x16x32_bf16(*(const bf16x8*)(ap + k0),
                                                    *(const bf16x8*)(wrow + k0), acc, 0, 0, 0);
#pragma unroll
    for (int i = 0; i < 4; ++i)
      gates_s[(g * 16 + lr) * 17 + kh * 4 + i] = acc[i] + gxa[i];
    __syncthreads();
    // cell update: thread (b, u) owns unit j0+u; h_reg carries masked h
    float gi = gates_s[u * 17 + b];
    float gf = gates_s[(16 + u) * 17 + b];
    float gg = gates_s[(32 + u) * 17 + b];
    float go = gates_s[(48 + u) * 17 + b];
    bool msk = s_pos < len_b;
    float cn = sigf(gf) * c_reg + sigf(gi) * tanh_f(gg);
    float hn = sigf(go) * tanh_f(cn);
    float hout = msk ? hn : h_reg;
    if (msk) c_reg = cn;
    h_reg = hout;
    unsigned hbits = (unsigned)f2bf(hout);
    unsigned hpart = __shfl_xor(hbits, 16);
    unsigned ybits = msk ? (unsigned)f2bf(hn) : 0u;
    unsigned ypart = __shfl_xor(ybits, 16);
    if ((u & 1) == 0) {
      stg_u32(&hb[(size_t)(t + 1) * 4096 + b * 256 + ((j0 + u) >> 1)], hbits | (hpart << 16));
      ys_cat_u32[(size_t)(s_pos * 16 + b) * 512 + dir * 256 + ((j0 + u) >> 1)] =
          ybits | (ypart << 16);
    }
    if (t == S_SZ - 1) {
      h_final[dir * 8192 + b * 512 + j0 + u] = hout;
      c_final[dir * 8192 + b * 512 + j0 + u] = c_reg;
    }
    if (t + 1 < S_SZ) grid_barrier(region, ub, 32, (unsigned)(t + 1));
#pragma unroll
    for (int i = 0; i < 4; ++i) gxa[i] = gxn[i];
  }
}

// ---------------- seq_mean ----------------
__global__ __launch_bounds__(256) void seqmean_kernel(const float* enc_outs, const int* src_len,
                                                      float* seq_mean) {
  int b = blockIdx.x >> 1;
  int j = (blockIdx.x & 1) * 256 + threadIdx.x;
  int L = src_len[b];
  float a = 0;
  for (int s = 0; s < L; ++s) a += enc_outs[((size_t)b * S_SZ + s) * H_SZ + j];
  seq_mean[b * 512 + j] = a / (float)L;
}

// ---------------- dec state init: h (bf16 packed) + c (f32) ----------------
__global__ __launch_bounds__(256) void init_state_kernel(const float* h_final, const float* c_final,
                                                         const float* w2h, const float* b2h,
                                                         const float* w2c, const float* b2c,
                                                         unsigned* h_u32, float* c_init) {
  int gid = blockIdx.x * 256 + threadIdx.x;  // 16384
  int half = gid >> 13;
  int idx = gid & 8191;
  int b = idx >> 9, j = idx & 511;
  const float* src = half ? c_final : h_final;
  const float* w = (half ? w2c : w2h) + (size_t)j * 1024;
  float acc = (half ? b2c : b2h)[j];
  const f32x4* s0 = (const f32x4*)(src + b * 512);
  const f32x4* s1 = (const f32x4*)(src + 8192 + b * 512);
  const f32x4* w0 = (const f32x4*)w;
  const f32x4* w1 = w0 + 128;
  float a = 0;
  for (int k = 0; k < 128; ++k) a += dot4(s0[k], w0[k]);
  for (int k = 0; k < 128; ++k) a += dot4(s1[k], w1[k]);
  acc += a;
  if (half) {
    c_init[idx] = acc;
  } else {
    unsigned bits = (unsigned)f2bf(acc);
    unsigned pb2 = __shfl_xor(bits, 1);
    if ((j & 1) == 0) h_u32[b * 256 + (j >> 1)] = bits | (pb2 << 16);
  }
}

// ---------------- tmp0 = tanh([dec_h | seq_mean] @ Wo1^T + bo1) -> tmp slot 0 (bf16) ---------
__global__ __launch_bounds__(256) void tmp0_kernel(const unsigned* h0_u32, const float* seq_mean,
                                                   const float* wo1, const float* bo1,
                                                   unsigned* tmp_u32) {
  int gid = blockIdx.x * 256 + threadIdx.x;  // 8192
  int b = gid >> 9, j = gid & 511;
  const f32x4* x1 = (const f32x4*)(seq_mean + b * 512);
  const f32x4* w0 = (const f32x4*)(wo1 + (size_t)j * 1024);
  const f32x4* w1 = w0 + 128;
  float a = bo1[j];
  float p = 0;
  const ushort_t* h0 = (const ushort_t*)(h0_u32) + b * 512;
  for (int k = 0; k < 128; ++k) {
    f32x4 hv = {bf2f(h0[k * 4]), bf2f(h0[k * 4 + 1]), bf2f(h0[k * 4 + 2]), bf2f(h0[k * 4 + 3])};
    p += dot4(hv, w0[k]);
  }
  for (int k = 0; k < 128; ++k) p += dot4(x1[k], w1[k]);
  float tv = tanh_f(a + p);
  unsigned bits = (unsigned)f2bf(tv);
  unsigned pb2 = __shfl_xor(bits, 1);
  if ((j & 1) == 0) tmp_u32[b * 256 + (j >> 1)] = bits | (pb2 << 16);
}

// ---------------- persistent decoder: 100 steps x 3 phases ----------------
__global__ __launch_bounds__(256) void dec_kernel(
    const ushort_t* xt_bf, const int* src_len, const ushort_t* wdec_pk,
    const float* wpgen, const float* bpgen, const float* wfp, const ushort_t* wo1_bf,
    const float* bo1, const float* enc_outs, const float* gxT, unsigned* h_u32,
    const float* c_init, unsigned* tmp_u32, float* ctx_part, float* z_part, float* zinv,
    float* pgen_o, float* pexp, unsigned* ctrs) {
  __shared__ float part_s[4 * 16 * 17];
  __shared__ f32x4 smem4[272];  // h_s(512) + ctx_s(512) + pad
  __shared__ float red_s[8];
  __shared__ float p_s[64];
  float* sm = (float*)smem4;
  unsigned* region = ctrs + 2 * 1024;

  const int blk = blockIdx.x, tid = threadIdx.x;
  const int w = tid >> 6, lane = tid & 63, lr = lane & 15, kh = lane >> 4;
  const int j0 = blk * 4;
  const ushort_t* wrow = wdec_pk + (size_t)(blk * 16 + lr) * 1024 + w * 256 + kh * 8;
  const int b_c = tid & 15, u_c = (tid >> 4) & 3;
  float c_reg = (tid < 64) ? c_init[b_c * 512 + j0 + u_c] : 0.0f;
  const int b_pb = blk >> 3, ch = blk & 7, s0c = ch * 50;
  const int len_pb = src_len[b_pb];
  const int nc = ch;
  unsigned pc = 0;

  // prefetch gx for t=0 (coalesced gxT layout [t][row][b])
  float gxa[4] = {0.f, 0.f, 0.f, 0.f};
  if (tid < 64) {
#pragma unroll
    for (int g2 = 0; g2 < 4; ++g2)
      gxa[g2] = gxT[((size_t)(g2 * 512 + j0 + u_c)) * 16 + b_c];
  }

  for (int t = 0; t < T_SZ; ++t) {
    // ---------- PA: gates via MFMA (K=1024 split over 4 waves) ----------
    {
      f32x4 acc = {0.f, 0.f, 0.f, 0.f};
      const unsigned* asrc = (w < 2) ? (h_u32 + (size_t)t * 4096) : (tmp_u32 + (size_t)t * 4096);
      const ushort_t* ap = (const ushort_t*)asrc + lr * 512 + (w & 1) * 256 + kh * 8;
#pragma unroll
      for (int k0 = 0; k0 < 256; k0 += 32)
        acc = __builtin_amdgcn_mfma_f32_16x16x32_bf16(*(const bf16x8*)(ap + k0),
                                                      *(const bf16x8*)(wrow + k0), acc, 0, 0, 0);
#pragma unroll
      for (int i = 0; i < 4; ++i) part_s[(w * 16 + lr) * 17 + kh * 4 + i] = acc[i];
      __syncthreads();
      if (tid < 64) {
        float gt[4];
#pragma unroll
        for (int g2 = 0; g2 < 4; ++g2) {
          int p = g2 * 4 + u_c;
          float a = gxa[g2];
#pragma unroll
          for (int w2 = 0; w2 < 4; ++w2) a += part_s[(w2 * 16 + p) * 17 + b_c];
          gt[g2] = a;
        }
        float cn = sigf(gt[1]) * c_reg + sigf(gt[0]) * tanh_f(gt[2]);
        c_reg = cn;
        float hn = sigf(gt[3]) * tanh_f(cn);
        unsigned bits = (unsigned)f2bf(hn);
        unsigned pb2 = __shfl_xor(bits, 16);
        if ((u_c & 1) == 0)
          stg_u32(&h_u32[(size_t)(t + 1) * 4096 + b_c * 256 + ((j0 + u_c) >> 1)],
                  bits | (pb2 << 16));
      }
    }
    grid_barrier(region, blk, 128, ++pc);
    // ---------- PB: score chunks -> pexp, z_part, ctx_part ----------
    {
      // prefetch next step's gx while waiting on nothing (pure L2/HBM latency hide)
      if (tid < 64 && t + 1 < T_SZ) {
#pragma unroll
        for (int g2 = 0; g2 < 4; ++g2)
          gxa[g2] = gxT[((size_t)(t + 1) * G4 + g2 * 512 + j0 + u_c) * 16 + b_c];
      }
      if (tid < 128) {
        unsigned v0 = h_u32[(size_t)(t + 1) * 4096 + b_pb * 256 + tid * 2];
        unsigned v1 = h_u32[(size_t)(t + 1) * 4096 + b_pb * 256 + tid * 2 + 1];
        f32x4 hv = {bfu2f(v0 & 0xffffu), bfu2f(v0 >> 16), bfu2f(v1 & 0xffffu), bfu2f(v1 >> 16)};
        ((f32x4*)sm)[tid] = hv;
      }
      __syncthreads();
      int st = tid >> 2, kq = tid & 3;
      if (st < 50) {
        const f32x4* er =
            (const f32x4*)(enc_outs + ((size_t)b_pb * S_SZ + s0c + st) * H_SZ) + kq * 32;
        const f32x4* hr = (const f32x4*)sm + kq * 32;
        float sc = 0;
        for (int k = 0; k < 32; ++k) sc += dot4(hr[k], er[k]);
        sc += __shfl_xor(sc, 1);
        sc += __shfl_xor(sc, 2);
        if (kq == 0) {
          int s_abs = s0c + st;
          float p = (s_abs < len_pb) ? __expf(sc) : 0.0f;
          p_s[st] = p;
          pexp[((size_t)t * 16 + b_pb) * S_SZ + s_abs] = p;
        }
      }
      __syncthreads();
      if (tid == 0) {
        float z = 0;
        for (int s = 0; s < 50; ++s) z += p_s[s];
        stg(&z_part[((size_t)t * 16 + b_pb) * 8 + ch], z);
      }
      float a0 = 0, a1 = 0;
      for (int s = 0; s < 50; ++s) {
        float p = p_s[s];
        const float* er = enc_outs + ((size_t)b_pb * S_SZ + s0c + s) * H_SZ;
        a0 += p * er[tid];
        a1 += p * er[tid + 256];
      }
      float* cp = ctx_part + (((size_t)t * 16 + b_pb) * 8 + ch) * 512;
      stg(&cp[tid], a0);
      stg(&cp[tid + 256], a1);
    }
    grid_barrier(region, blk, 128, ++pc);
    // ---------- PC: combine ctx + pgen + tmp (h already staged in sm by PB) ----------
    {
      float* h_s = sm;
      float* ctx_s = sm + 512;
      const float* zp = z_part + ((size_t)t * 16 + b_pb) * 8;
      float z = 0;
#pragma unroll
      for (int c2 = 0; c2 < 8; ++c2) z += zp[c2];
      float inv = 1.0f / z;
      const float* cpb = ctx_part + ((size_t)t * 16 + b_pb) * 8 * 512;
      float c0 = 0, c1 = 0;
#pragma unroll
      for (int c2 = 0; c2 < 8; ++c2) {
        c0 += cpb[c2 * 512 + tid];
        c1 += cpb[c2 * 512 + tid + 256];
      }
      ctx_s[tid] = c0 * inv;
      ctx_s[tid + 256] = c1 * inv;
      __syncthreads();
      const ushort_t* tmpp = (const ushort_t*)(tmp_u32 + (size_t)t * 4096) + b_pb * 512;
      float tp0 = bf2f(tmpp[tid]);
      float tp1 = bf2f(tmpp[tid + 256]);
      float xe = bf2f(xt_bf[((size_t)t * 16 + b_pb) * 256 + tid]);
      float pg = wpgen[tid] * ctx_s[tid] + wpgen[tid + 256] * ctx_s[tid + 256] +
                 wpgen[512 + tid] * h_s[tid] + wpgen[512 + tid + 256] * h_s[tid + 256] +
                 wpgen[1024 + tid] * xe + wfp[tid] * tp0 + wfp[tid + 256] * tp1;
#pragma unroll
      for (int o = 32; o; o >>= 1) pg += __shfl_xor(pg, o);
      if (lane == 0) red_s[w] = pg;
      __syncthreads();
      if (nc == 0 && tid == 0) {
        pgen_o[t * 16 + b_pb] = sigf(red_s[0] + red_s[1] + red_s[2] + red_s[3] + bpgen[0]);
        zinv[t * 16 + b_pb] = inv;
      }
      int nidx = tid >> 2, kq = tid & 3;
      int n = nc * 64 + nidx;
      const ushort8_t* wrp = (const ushort8_t*)(wo1_bf + (size_t)n * 1024) + kq * 32;
      const f32x4* xr2 =
          (kq < 2) ? ((const f32x4*)h_s + kq * 64) : ((const f32x4*)ctx_s + (kq - 2) * 64);
      float a = 0;
#pragma unroll 4
      for (int k = 0; k < 32; ++k) {
        ushort8_t w8 = wrp[k];
        f32x4 w0 = {bf2f(w8[0]), bf2f(w8[1]), bf2f(w8[2]), bf2f(w8[3])};
        f32x4 w1 = {bf2f(w8[4]), bf2f(w8[5]), bf2f(w8[6]), bf2f(w8[7])};
        a += dot4(xr2[2 * k], w0) + dot4(xr2[2 * k + 1], w1);
      }
      a += __shfl_xor(a, 1);
      a += __shfl_xor(a, 2);
      float tv = tanh_f(a + bo1[n]);
      unsigned bits = (unsigned)f2bf(tv);
      unsigned pbits = __shfl_xor(bits, 4);
      if (kq == 0 && (nidx & 1) == 0)
        stg_u32(&tmp_u32[(size_t)(t + 1) * 4096 + b_pb * 256 + ((nc * 64 + nidx) >> 1)],
                bits | (pbits << 16));
    }
    if (t + 1 < T_SZ) grid_barrier(region, blk, 128, ++pc);
  }
}

// ---------------- per (t,b) row softmax + copy-scatter + log ----------------
__global__ __launch_bounds__(1024) void finalize_kernel(float* out, const float* pexp,
                                                        const float* zinv, const float* pgen_i,
                                                        const int* src_ext) {
  __shared__ float scat[VX];
  __shared__ float red[64];
  const int row = blockIdx.x;
  const int b = row & 15;
  const int tid = threadIdx.x;
  for (int i = tid; i < VX; i += 1024) scat[i] = 0.0f;
  __syncthreads();
  const float pg = pgen_i[row];
  const float inv = zinv[row];
  if (tid < S_SZ) {
    float v = (1.0f - pg) * pexp[(size_t)row * S_SZ + tid] * inv;
    int col = src_ext[b * S_SZ + tid];
    atomicAdd(&scat[col], v);
  }
  float* orow = out + (size_t)row * VX;
  float l[32];
  float mx = -3.4e38f;
#pragma unroll
  for (int i2 = 0; i2 < 32; ++i2) {
    int col = tid + (i2 << 10);
    l[i2] = (col < V_SZ) ? orow[col] : -3.4e38f;
    mx = fmaxf(mx, l[i2]);
  }
#pragma unroll
  for (int o = 32; o; o >>= 1) mx = fmaxf(mx, __shfl_xor(mx, o));
  if ((tid & 63) == 0) red[16 + (tid >> 6)] = mx;
  __syncthreads();
  if (tid == 0) {
    float m2 = red[16];
    for (int w = 1; w < 16; ++w) m2 = fmaxf(m2, red[16 + w]);
    red[0] = m2;
  }
  __syncthreads();
  const float gmx = red[0];
  float se = 0.0f;
#pragma unroll
  for (int i2 = 0; i2 < 32; ++i2) {
    int col = tid + (i2 << 10);
    if (col < V_SZ) {
      l[i2] = __expf(l[i2] - gmx);
      se += l[i2];
    }
  }
#pragma unroll
  for (int o = 32; o; o >>= 1) se += __shfl_xor(se, o);
  if ((tid & 63) == 0) red[32 + (tid >> 6)] = se;
  __syncthreads();
  if (tid == 0) {
    float s2 = 0;
    for (int w = 0; w < 16; ++w) s2 += red[32 + w];
    red[1] = s2;
  }
  __syncthreads();
  const float scale = pg / red[1];
#pragma unroll
  for (int i2 = 0; i2 < 32; ++i2) {
    int col = tid + (i2 << 10);
    if (col < VX) {
      float base = (col < V_SZ) ? l[i2] * scale : 0.0f;
      orow[col] = __logf(base + scat[col] + 1e-20f);
    }
  }
}

extern "C" void kernel_launch(void* const* d_in, const int* in_sizes, int n_in, void* d_out,
                              int out_size, void* d_ws, size_t ws_size, hipStream_t stream) {
  (void)in_sizes; (void)n_in; (void)out_size; (void)ws_size;
  const int* source = (const int*)d_in[0];
  const int* source_ext = (const int*)d_in[1];
  const int* source_len = (const int*)d_in[2];
  const int* target = (const int*)d_in[3];
  const float* emb = (const float*)d_in[4];
  const float* wih_f = (const float*)d_in[5];
  const float* whh_f = (const float*)d_in[6];
  const float* b_f = (const float*)d_in[7];
  const float* wih_b = (const float*)d_in[8];
  const float* whh_b = (const float*)d_in[9];
  const float* b_b = (const float*)d_in[10];
  const float* wproj = (const float*)d_in[11];
  const float* bproj = (const float*)d_in[12];
  const float* w2h = (const float*)d_in[13];
  const float* b2h = (const float*)d_in[14];
  const float* w2c = (const float*)d_in[15];
  const float* b2c = (const float*)d_in[16];
  const float* wo1 = (const float*)d_in[17];
  const float* bo1 = (const float*)d_in[18];
  const float* wo2 = (const float*)d_in[19];
  const float* dwih = (const float*)d_in[20];
  const float* dwhh = (const float*)d_in[21];
  const float* dbias = (const float*)d_in[22];
  const float* wpgen = (const float*)d_in[23];
  const float* bpgen = (const float*)d_in[24];
  float* out = (float*)d_out;

  size_t off = 0;
  char* wsb = (char*)d_ws;
  auto alloc = [&](size_t bytes) -> void* {
    void* p = wsb + off;
    off += (bytes + 255) & ~(size_t)255;
    return p;
  };
  unsigned* ctrs = (unsigned*)alloc(3 * 4096);  // cohorts: enc_f, enc_b, dec (4KB each)
  ushort_t* emb_bf = (ushort_t*)alloc((size_t)V_SZ * D_SZ * 2);
  ushort_t* wihf_bf = (ushort_t*)alloc((size_t)G4 * D_SZ * 2);
  ushort_t* wihb_bf = (ushort_t*)alloc((size_t)G4 * D_SZ * 2);
  ushort_t* wihd_bf = (ushort_t*)alloc((size_t)G4 * D_SZ * 2);
  ushort_t* wproj_bf = (ushort_t*)alloc((size_t)H_SZ * 2 * H_SZ * 2);
  ushort_t* wo2t_bf = (ushort_t*)alloc((size_t)H_SZ * D_SZ * 2);
  ushort_t* wo1_bf = (ushort_t*)alloc((size_t)H_SZ * 1024 * 2);
  float* wfused = (float*)alloc((size_t)G4 * H_SZ * 4);
  float* wfp = (float*)alloc(512 * 4);
  ushort_t* whh_pk = (ushort_t*)alloc((size_t)2 * G4 * H_SZ * 2);
  ushort_t* wdec_pk = (ushort_t*)alloc((size_t)G4 * 1024 * 2);
  ushort_t* xs_bf = (ushort_t*)alloc((size_t)S_SZ * B_SZ * D_SZ * 2);
  ushort_t* xt_bf = (ushort_t*)alloc((size_t)T_SZ * B_SZ * D_SZ * 2);
  float* gx_f = (float*)alloc((size_t)S_SZ * B_SZ * G4 * 4);  // aliased by e2_bf after enc
  float* gx_b = (float*)alloc((size_t)S_SZ * B_SZ * G4 * 4);  // aliased by gx_dec/ctx_part/gxT
  unsigned* hbf_f = (unsigned*)alloc((size_t)(S_SZ + 1) * 4096 * 4);
  unsigned* hbf_b = (unsigned*)alloc((size_t)(S_SZ + 1) * 4096 * 4);
  unsigned* ys_cat_u32 = (unsigned*)alloc((size_t)S_SZ * B_SZ * 512 * 4);
  float* h_final = (float*)alloc((size_t)2 * B_SZ * H_SZ * 4);
  float* c_final = (float*)alloc((size_t)2 * B_SZ * H_SZ * 4);
  float* enc_outs = (float*)alloc((size_t)B_SZ * S_SZ * H_SZ * 4);
  float* seq_mean = (float*)alloc((size_t)B_SZ * H_SZ * 4);
  unsigned* h_u32 = (unsigned*)alloc((size_t)(T_SZ + 1) * 4096 * 4);
  float* c_init = (float*)alloc((size_t)B_SZ * H_SZ * 4);
  unsigned* tmp_u32 = (unsigned*)alloc((size_t)(T_SZ + 1) * 4096 * 4);
  float* z_part = (float*)alloc((size_t)T_SZ * B_SZ * 8 * 4);
  float* zinv = (float*)alloc((size_t)T_SZ * B_SZ * 4);
  float* pgen_b = (float*)alloc((size_t)T_SZ * B_SZ * 4);
  float* pexp = (float*)alloc((size_t)T_SZ * B_SZ * S_SZ * 4);
  // aliases into dead-after-encoder regions (gx_b = 13,107,200 floats)
  ushort_t* e2_bf = (ushort_t*)gx_f;                     // 32.8 MB
  float* gx_dec = gx_b;                                  // 3,276,800 floats
  float* ctx_part = gx_b + (size_t)3276800;              // 6,553,600 floats
  float* gxT = gx_b + (size_t)9830400;                   // 3,276,800 floats (fits exactly)

  hipMemsetAsync(ctrs, 0, 3 * 4096, stream);           // barrier regions
  hipMemsetAsync(hbf_f, 0, 4096 * 4, stream);          // enc h slot 0 (dir f)
  hipMemsetAsync(hbf_b, 0, 4096 * 4, stream);          // enc h slot 0 (dir b)

  cvt_kernel<<<2048, 256, 0, stream>>>(emb, emb_bf, V_SZ * D_SZ);
  cvt_kernel<<<2048, 256, 0, stream>>>(wih_f, wihf_bf, G4 * D_SZ);
  cvt_kernel<<<2048, 256, 0, stream>>>(wih_b, wihb_bf, G4 * D_SZ);
  cvt_kernel<<<2048, 256, 0, stream>>>(wproj, wproj_bf, H_SZ * 2 * H_SZ);
  cvt_kernel<<<2048, 256, 0, stream>>>(wo1, wo1_bf, H_SZ * 1024);
  cvt_strided_kernel<<<2048, 256, 0, stream>>>(dwih, wihd_bf);
  cvt_wo2t_kernel<<<512, 256, 0, stream>>>(wo2, wo2t_bf);
  wfused_kernel<<<2048, 256, 0, stream>>>(dwih, wo2, wfused);
  wfp_kernel<<<2, 256, 0, stream>>>(wpgen, wo2, wfp);
  pack_whh_kernel<<<8192, 256, 0, stream>>>(whh_f, whh_b, whh_pk);
  pack_wdec_kernel<<<8192, 256, 0, stream>>>(dwhh, wfused, wdec_pk);
  gather_src_kernel<<<800, 256, 0, stream>>>(emb_bf, source, xs_bf);
  gather_tgt_kernel<<<200, 256, 0, stream>>>(emb_bf, target, xt_bf);
  gemm_abt_bias<<<dim3(8, 400), 256, 0, stream>>>(xs_bf, wihf_bf, b_f, gx_f, 256);
  gemm_abt_bias<<<dim3(8, 400), 256, 0, stream>>>(xs_bf, wihb_bf, b_b, gx_b, 256);
  enc_kernel<<<64, 256, 0, stream>>>(gx_f, gx_b, whh_pk, source_len, hbf_f, hbf_b, ys_cat_u32,
                                     h_final, c_final, ctrs);
  gemm_encout<<<dim3(2, 400), 256, 0, stream>>>((const ushort_t*)ys_cat_u32, wproj_bf, bproj,
                                                enc_outs);
  seqmean_kernel<<<32, 256, 0, stream>>>(enc_outs, source_len, seq_mean);
  init_state_kernel<<<64, 256, 0, stream>>>(h_final, c_final, w2h, b2h, w2c, b2c, h_u32, c_init);
  tmp0_kernel<<<32, 256, 0, stream>>>(h_u32, seq_mean, wo1, bo1, tmp_u32);
  gemm_abt_bias<<<dim3(8, 100), 256, 0, stream>>>(xt_bf, wihd_bf, dbias, gx_dec, 256);
  gxT_kernel<<<dim3(8, 100), 256, 0, stream>>>(gx_dec, gxT);
  gemm_e2<<<dim3(2, 2000), 256, 0, stream>>>(emb_bf, wo2t_bf, e2_bf);
  dec_kernel<<<128, 256, 0, stream>>>(xt_bf, source_len, wdec_pk, wpgen, bpgen, wfp, wo1_bf, bo1,
                                      enc_outs, gxT, h_u32, c_init, tmp_u32, ctx_part, z_part,
                                      zinv, pgen_b, pexp, ctrs);
  gemm_logits<<<dim3(100, 125), 256, 0, stream>>>((const ushort_t*)(tmp_u32 + 4096), e2_bf, out);
  finalize_kernel<<<1600, 1024, 0, stream>>>(out, pexp, zinv, pgen_b, source_ext);
}

// Round 6
// 5217.581 us; speedup vs baseline: 2.8746x; 1.2689x over previous
//
#include <hip/hip_runtime.h>

#define V_SZ 32000
#define D_SZ 256
#define H_SZ 512
#define B_SZ 16
#define S_SZ 400
#define T_SZ 100
#define G4   2048
#define VX   32050
#define LINE 32  // words per 128B line

typedef unsigned short ushort_t;
typedef __attribute__((ext_vector_type(8))) __bf16 bf16x8;
typedef __attribute__((ext_vector_type(8))) unsigned short ushort8_t;
typedef __attribute__((ext_vector_type(4))) float f32x4;

__device__ __forceinline__ ushort_t f2bf(float x) {
  union { float f; unsigned u; } v; v.f = x;
  unsigned r = v.u + 0x7fffu + ((v.u >> 16) & 1u);
  return (ushort_t)(r >> 16);
}
__device__ __forceinline__ float bf2f(ushort_t x) {
  union { unsigned u; float f; } v; v.u = ((unsigned)x) << 16; return v.f;
}
__device__ __forceinline__ float bfu2f(unsigned x) {
  union { unsigned u; float f; } v; v.u = x << 16; return v.f;
}
__device__ __forceinline__ float sigf(float x) { return 1.0f / (1.0f + __expf(-x)); }
__device__ __forceinline__ float tanh_f(float x) {
  float e = __expf(2.0f * x);
  return 1.0f - 2.0f / (e + 1.0f);
}
__device__ __forceinline__ float dot4(f32x4 a, f32x4 b) {
  return a.x * b.x + a.y * b.y + a.z * b.z + a.w * b.w;
}
// write-through store to device coherence point; readers cold-miss fresh data.
__device__ __forceinline__ void stg(float* p, float v) {
  __hip_atomic_store(p, v, __ATOMIC_RELAXED, __HIP_MEMORY_SCOPE_AGENT);
}
__device__ __forceinline__ void stg_u32(unsigned* p, unsigned v) {
  __hip_atomic_store(p, v, __ATOMIC_RELAXED, __HIP_MEMORY_SCOPE_AGENT);
}

// Grid barrier, last-man-broadcast. Region layout (128B lines):
//   arrival counter @ word 0; GO line j @ word (8+j)*LINE, j in [0,16).
// Every block fetch_adds the arrival counter (no pollers on it -> adds just
// pipeline at the IC slice). The block whose add completes the epoch writes
// all 16 GO lines itself (saves the master-poll hop). Each block polls one
// GO line with one wave (all 64 lanes same word -> 1 request/wave).
__device__ __forceinline__ void grid_barrier(unsigned* region, int cid, int nb, unsigned pc) {
  asm volatile("s_waitcnt vmcnt(0)" ::: "memory");
  __syncthreads();
  if (threadIdx.x == 0) {
    unsigned old =
        __hip_atomic_fetch_add(&region[0], 1u, __ATOMIC_RELAXED, __HIP_MEMORY_SCOPE_AGENT);
    if (old + 1 == (unsigned)nb * pc) {
#pragma unroll
      for (int j = 0; j < 16; ++j)
        __hip_atomic_store(&region[(8 + j) * LINE], pc, __ATOMIC_RELAXED,
                           __HIP_MEMORY_SCOPE_AGENT);
    }
  }
  unsigned* go = &region[(8 + (cid & 15)) * LINE];
  if (threadIdx.x < 64) {
    while (__hip_atomic_load(go, __ATOMIC_RELAXED, __HIP_MEMORY_SCOPE_AGENT) < pc)
      __builtin_amdgcn_s_sleep(1);
  }
  __syncthreads();
}

// 8-block group barrier (per-batch-row attention groups), last-man-broadcast.
// greg[0] = arrival counter, greg[LINE] = GO word.
__device__ __forceinline__ void group_barrier(unsigned* greg, unsigned pc) {
  asm volatile("s_waitcnt vmcnt(0)" ::: "memory");
  __syncthreads();
  if (threadIdx.x == 0) {
    unsigned old =
        __hip_atomic_fetch_add(&greg[0], 1u, __ATOMIC_RELAXED, __HIP_MEMORY_SCOPE_AGENT);
    if (old + 1 == 8u * pc)
      __hip_atomic_store(&greg[LINE], pc, __ATOMIC_RELAXED, __HIP_MEMORY_SCOPE_AGENT);
  }
  if (threadIdx.x < 64) {
    while (__hip_atomic_load(&greg[LINE], __ATOMIC_RELAXED, __HIP_MEMORY_SCOPE_AGENT) < pc)
      __builtin_amdgcn_s_sleep(1);
  }
  __syncthreads();
}

// ---------------- f32 -> bf16 convert ----------------
__global__ __launch_bounds__(256) void cvt_kernel(const float* in, ushort_t* outp, int n) {
  int i = blockIdx.x * 256 + threadIdx.x;
  int stride = gridDim.x * 256;
  for (; i < n; i += stride) outp[i] = f2bf(in[i]);
}

// cols [0,256) of a row-stride-512 matrix -> packed bf16 (2048 x 256)
__global__ __launch_bounds__(256) void cvt_strided_kernel(const float* in, ushort_t* outp) {
  int gid = blockIdx.x * 256 + threadIdx.x;  // 524288
  int r = gid >> 8, d = gid & 255;
  outp[gid] = f2bf(in[(size_t)r * 512 + d]);
}

// wo2t[h][d] = wo2[d][h]  (512 x 256 bf16)
__global__ __launch_bounds__(256) void cvt_wo2t_kernel(const float* wo2, ushort_t* outp) {
  int gid = blockIdx.x * 256 + threadIdx.x;  // 131072
  int h = gid >> 8, d = gid & 255;
  outp[gid] = f2bf(wo2[(size_t)d * 512 + h]);
}

// Wfused[r][c] = sum_d dwih[r][256+d] * wo2[d][c]   (2048 x 512 f32)
__global__ __launch_bounds__(256) void wfused_kernel(const float* dwih, const float* wo2,
                                                     float* wf) {
  __shared__ float xr_s[256];
  int r = blockIdx.x;
  xr_s[threadIdx.x] = dwih[(size_t)r * 512 + 256 + threadIdx.x];
  __syncthreads();
  float a0 = 0, a1 = 0;
  for (int d = 0; d < 256; ++d) {
    float x = xr_s[d];
    a0 += x * wo2[(size_t)d * 512 + threadIdx.x];
    a1 += x * wo2[(size_t)d * 512 + threadIdx.x + 256];
  }
  wf[(size_t)r * 512 + threadIdx.x] = a0;
  wf[(size_t)r * 512 + threadIdx.x + 256] = a1;
}

// wfp[h] = sum_d wpgen[1280+d] * wo2[d][h]
__global__ __launch_bounds__(256) void wfp_kernel(const float* wpgen, const float* wo2,
                                                  float* wfp) {
  int h = blockIdx.x * 256 + threadIdx.x;
  float a = 0;
  for (int d = 0; d < 256; ++d) a += wpgen[1280 + d] * wo2[(size_t)d * 512 + h];
  wfp[h] = a;
}

// pack Whh (both dirs) into per-block wave-major bf16 rows
__global__ __launch_bounds__(256) void pack_whh_kernel(const float* whh_f, const float* whh_b,
                                                       ushort_t* outp) {
  int gid = blockIdx.x * 256 + threadIdx.x;  // 2*2048*512
  int col = gid & 511;
  int p_g = gid >> 9;
  int dir = p_g >> 11, p = p_g & 2047;
  int ub = p >> 6, g = (p >> 4) & 3, u = p & 15;
  const float* src = dir ? whh_b : whh_f;
  outp[gid] = f2bf(src[(size_t)(g * 512 + ub * 16 + u) * 512 + col]);
}

// pack decoder recurrent weights [Whh_dec | Wfused] (2048 x 1024 bf16)
__global__ __launch_bounds__(256) void pack_wdec_kernel(const float* dwhh, const float* wfused,
                                                        ushort_t* outp) {
  int gid = blockIdx.x * 256 + threadIdx.x;  // 2048*1024
  int col = gid & 1023;
  int p = gid >> 10;
  int ub = p >> 4, g = (p >> 2) & 3, u = p & 3;
  int row = g * 512 + ub * 4 + u;
  float v = (col < 512) ? dwhh[(size_t)row * 512 + col] : wfused[(size_t)row * 512 + (col - 512)];
  outp[gid] = f2bf(v);
}

// gxT[(t*2048 + r)*16 + b] = gx_dec[(t*16+b)*2048 + r]
__global__ __launch_bounds__(256) void gxT_kernel(const float* gx, float* gxT) {
  int t = blockIdx.y;
  int r = blockIdx.x * 256 + threadIdx.x;
  float v[16];
#pragma unroll
  for (int b = 0; b < 16; ++b) v[b] = gx[((size_t)t * 16 + b) * G4 + r];
  f32x4* dst = (f32x4*)(gxT + ((size_t)t * G4 + r) * 16);
#pragma unroll
  for (int q = 0; q < 4; ++q) {
    f32x4 w = {v[q * 4], v[q * 4 + 1], v[q * 4 + 2], v[q * 4 + 3]};
    dst[q] = w;
  }
}

// ---------------- gather embeddings (bf16) ----------------
__global__ __launch_bounds__(256) void gather_src_kernel(const ushort_t* emb_bf, const int* source,
                                                         ushort_t* xs_bf) {
  int gid = blockIdx.x * 256 + threadIdx.x;  // 204800
  int r = gid >> 5, e = gid & 31;
  int s = r >> 4, b = r & 15;
  int tok = source[b * S_SZ + s];
  ((ushort8_t*)xs_bf)[gid] = ((const ushort8_t*)emb_bf)[(size_t)tok * 32 + e];
}
__global__ __launch_bounds__(256) void gather_tgt_kernel(const ushort_t* emb_bf, const int* target,
                                                         ushort_t* xt_bf) {
  int gid = blockIdx.x * 256 + threadIdx.x;  // 51200
  int r = gid >> 5, e = gid & 31;
  int t = r >> 4, b = r & 15;
  int tok = target[b * T_SZ + t];
  ((ushort8_t*)xt_bf)[gid] = ((const ushort8_t*)emb_bf)[(size_t)tok * 32 + e];
}

// ---------------- MFMA helper: one wave computes a 16x64 tile of A(M,K) @ B(N,K)^T ------------
__device__ __forceinline__ void mfma_16x64(const ushort_t* A, const ushort_t* B_, int K,
                                           int m0, int n0, f32x4 acc[4]) {
  const int lane = threadIdx.x & 63;
  const int lr = lane & 15, kh = lane >> 4;
  const ushort_t* ap = A + (size_t)(m0 + lr) * K + kh * 8;
  const ushort_t* bp = B_ + (size_t)(n0 + lr) * K + kh * 8;
  for (int k0 = 0; k0 < K; k0 += 32) {
    bf16x8 av = *(const bf16x8*)(ap + k0);
#pragma unroll
    for (int s = 0; s < 4; ++s) {
      bf16x8 bv = *(const bf16x8*)(bp + (size_t)s * 16 * K + k0);
      acc[s] = __builtin_amdgcn_mfma_f32_16x16x32_bf16(av, bv, acc[s], 0, 0, 0);
    }
  }
}

// ---------------- gates GEMM: out[m][n] = A[m]·B[n] + bias[n], N=2048 ----------------
__global__ __launch_bounds__(256) void gemm_abt_bias(const ushort_t* A, const ushort_t* Bm,
                                                     const float* bias, float* out, int K) {
  int wave = threadIdx.x >> 6;
  int m0 = blockIdx.y * 16;
  int n0 = blockIdx.x * 256 + wave * 64;
  f32x4 acc[4] = {};
  mfma_16x64(A, Bm, K, m0, n0, acc);
  int lane = threadIdx.x & 63, lr = lane & 15, kh = lane >> 4;
#pragma unroll
  for (int s = 0; s < 4; ++s) {
    int n = n0 + s * 16 + lr;
    float bv = bias[n];
#pragma unroll
    for (int i = 0; i < 4; ++i) {
      int m = m0 + kh * 4 + i;
      out[(size_t)m * G4 + n] = acc[s][i] + bv;
    }
  }
}

// ---------------- enc_outs = ys_cat @ Wproj^T + bproj, out layout [b][s][h] ----------------
__global__ __launch_bounds__(256) void gemm_encout(const ushort_t* ys_cat, const ushort_t* wproj_bf,
                                                   const float* bproj, float* enc_outs) {
  int wave = threadIdx.x >> 6;
  int m0 = blockIdx.y * 16;
  int n0 = blockIdx.x * 256 + wave * 64;
  f32x4 acc[4] = {};
  mfma_16x64(ys_cat, wproj_bf, 2 * H_SZ, m0, n0, acc);
  int lane = threadIdx.x & 63, lr = lane & 15, kh = lane >> 4;
#pragma unroll
  for (int s = 0; s < 4; ++s) {
    int n = n0 + s * 16 + lr;
    float bv = bproj[n];
#pragma unroll
    for (int i = 0; i < 4; ++i) {
      int m = m0 + kh * 4 + i;
      int b = m & 15, si = m >> 4;
      enc_outs[((size_t)b * S_SZ + si) * H_SZ + n] = acc[s][i] + bv;
    }
  }
}

// ---------------- E2 = emb @ Wo2  (32000 x 512, bf16) ----------------
__global__ __launch_bounds__(256) void gemm_e2(const ushort_t* emb_bf, const ushort_t* wo2t_bf,
                                               ushort_t* e2) {
  int wave = threadIdx.x >> 6;
  int m0 = blockIdx.y * 16;
  int n0 = blockIdx.x * 256 + wave * 64;
  f32x4 acc[4] = {};
  mfma_16x64(emb_bf, wo2t_bf, 256, m0, n0, acc);
  int lane = threadIdx.x & 63, lr = lane & 15, kh = lane >> 4;
#pragma unroll
  for (int s = 0; s < 4; ++s) {
    int n = n0 + s * 16 + lr;
#pragma unroll
    for (int i = 0; i < 4; ++i) {
      int m = m0 + kh * 4 + i;
      e2[(size_t)m * 512 + n] = f2bf(acc[s][i]);
    }
  }
}

// ---------------- logits = tmp @ E2^T  (K=512), into d_out cols [0,V) ----------------
__global__ __launch_bounds__(256) void gemm_logits(const ushort_t* tmp_bf, const ushort_t* e2_bf,
                                                   float* out) {
  int wave = threadIdx.x >> 6;
  int m0 = blockIdx.x * 16;
  int n0 = blockIdx.y * 256 + wave * 64;
  f32x4 acc[4] = {};
  mfma_16x64(tmp_bf, e2_bf, 512, m0, n0, acc);
  int lane = threadIdx.x & 63, lr = lane & 15, kh = lane >> 4;
#pragma unroll
  for (int s = 0; s < 4; ++s) {
    int n = n0 + s * 16 + lr;
#pragma unroll
    for (int i = 0; i < 4; ++i) {
      int m = m0 + kh * 4 + i;
      out[(size_t)m * VX + n] = acc[s][i];
    }
  }
}

// ---------------- persistent bidirectional encoder LSTM (MFMA) ----------------
// 64 blocks: dir = blk>>5, ub = blk&31 -> units j0=ub*16 .. +16. Wave g handles gate g.
__global__ __launch_bounds__(256) void enc_kernel(const float* gx_f, const float* gx_b,
                                                  const ushort_t* whh_pk, const int* src_len,
                                                  unsigned* hbf_f, unsigned* hbf_b,
                                                  unsigned* ys_cat_u32, float* h_final,
                                                  float* c_final, unsigned* ctrs) {
  __shared__ float gates_s[4 * 16 * 17];
  const int blk = blockIdx.x, tid = threadIdx.x;
  const int dir = blk >> 5, ub = blk & 31, j0 = ub * 16;
  const int g = tid >> 6, lane = tid & 63, lr = lane & 15, kh = lane >> 4;
  const float* gx = dir ? gx_b : gx_f;
  unsigned* hb = dir ? hbf_b : hbf_f;
  unsigned* region = ctrs + dir * 1024;
  const ushort_t* wrow =
      whh_pk + (size_t)(((dir * 32 + ub) * 4 + g) * 16 + lr) * 512 + kh * 8;
  const int b = tid & 15, u = tid >> 4;
  const int len_b = src_len[b];
  float c_reg = 0.0f, h_reg = 0.0f;

  // prefetch gx for t=0
  float gxa[4];
  {
    const int s0 = dir ? (S_SZ - 1) : 0;
    const float* g0 = gx + (size_t)s0 * (16 * 2048) + g * 512 + j0 + lr;
#pragma unroll
    for (int i = 0; i < 4; ++i) gxa[i] = g0[(size_t)(kh * 4 + i) * 2048];
  }

  for (int t = 0; t < S_SZ; ++t) {
    const int s_pos = dir ? (S_SZ - 1 - t) : t;
    // issue prefetch for t+1 early (hidden under MFMA chain + barrier drain)
    float gxn[4] = {0.f, 0.f, 0.f, 0.f};
    if (t + 1 < S_SZ) {
      const int sn = dir ? (S_SZ - 2 - t) : (t + 1);
      const float* gn = gx + (size_t)sn * (16 * 2048) + g * 512 + j0 + lr;
#pragma unroll
      for (int i = 0; i < 4; ++i) gxn[i] = gn[(size_t)(kh * 4 + i) * 2048];
    }
    f32x4 acc = {0.f, 0.f, 0.f, 0.f};
    const ushort_t* ap = (const ushort_t*)(hb + (size_t)t * 4096) + lr * 512 + kh * 8;
#pragma unroll
    for (int k0 = 0; k0 < 512; k0 += 32)
      acc = __builtin_amdgcn_mfma_f32_16x16x32_bf16(*(const bf16x8*)(ap + k0),
                                                    *(const bf16x8*)(wrow + k0), acc, 0, 0, 0);
#pragma unroll
    for (int i = 0; i < 4; ++i)
      gates_s[(g * 16 + lr) * 17 + kh * 4 + i] = acc[i] + gxa[i];
    __syncthreads();
    // cell update: thread (b, u) owns unit j0+u; h_reg carries masked h
    float gi = gates_s[u * 17 + b];
    float gf = gates_s[(16 + u) * 17 + b];
    float gg = gates_s[(32 + u) * 17 + b];
    float go = gates_s[(48 + u) * 17 + b];
    bool msk = s_pos < len_b;
    float cn = sigf(gf) * c_reg + sigf(gi) * tanh_f(gg);
    float hn = sigf(go) * tanh_f(cn);
    float hout = msk ? hn : h_reg;
    if (msk) c_reg = cn;
    h_reg = hout;
    unsigned hbits = (unsigned)f2bf(hout);
    unsigned hpart = __shfl_xor(hbits, 16);
    unsigned ybits = msk ? (unsigned)f2bf(hn) : 0u;
    unsigned ypart = __shfl_xor(ybits, 16);
    if ((u & 1) == 0) {
      stg_u32(&hb[(size_t)(t + 1) * 4096 + b * 256 + ((j0 + u) >> 1)], hbits | (hpart << 16));
      ys_cat_u32[(size_t)(s_pos * 16 + b) * 512 + dir * 256 + ((j0 + u) >> 1)] =
          ybits | (ypart << 16);
    }
    if (t == S_SZ - 1) {
      h_final[dir * 8192 + b * 512 + j0 + u] = hout;
      c_final[dir * 8192 + b * 512 + j0 + u] = c_reg;
    }
    if (t + 1 < S_SZ) grid_barrier(region, ub, 32, (unsigned)(t + 1));
#pragma unroll
    for (int i = 0; i < 4; ++i) gxa[i] = gxn[i];
  }
}

// ---------------- seq_mean ----------------
__global__ __launch_bounds__(256) void seqmean_kernel(const float* enc_outs, const int* src_len,
                                                      float* seq_mean) {
  int b = blockIdx.x >> 1;
  int j = (blockIdx.x & 1) * 256 + threadIdx.x;
  int L = src_len[b];
  float a = 0;
  for (int s = 0; s < L; ++s) a += enc_outs[((size_t)b * S_SZ + s) * H_SZ + j];
  seq_mean[b * 512 + j] = a / (float)L;
}

// ---------------- dec state init: h (bf16 packed) + c (f32) ----------------
__global__ __launch_bounds__(256) void init_state_kernel(const float* h_final, const float* c_final,
                                                         const float* w2h, const float* b2h,
                                                         const float* w2c, const float* b2c,
                                                         unsigned* h_u32, float* c_init) {
  int gid = blockIdx.x * 256 + threadIdx.x;  // 16384
  int half = gid >> 13;
  int idx = gid & 8191;
  int b = idx >> 9, j = idx & 511;
  const float* src = half ? c_final : h_final;
  const float* w = (half ? w2c : w2h) + (size_t)j * 1024;
  float acc = (half ? b2c : b2h)[j];
  const f32x4* s0 = (const f32x4*)(src + b * 512);
  const f32x4* s1 = (const f32x4*)(src + 8192 + b * 512);
  const f32x4* w0 = (const f32x4*)w;
  const f32x4* w1 = w0 + 128;
  float a = 0;
  for (int k = 0; k < 128; ++k) a += dot4(s0[k], w0[k]);
  for (int k = 0; k < 128; ++k) a += dot4(s1[k], w1[k]);
  acc += a;
  if (half) {
    c_init[idx] = acc;
  } else {
    unsigned bits = (unsigned)f2bf(acc);
    unsigned pb2 = __shfl_xor(bits, 1);
    if ((j & 1) == 0) h_u32[b * 256 + (j >> 1)] = bits | (pb2 << 16);
  }
}

// ---------------- tmp0 = tanh([dec_h | seq_mean] @ Wo1^T + bo1) -> tmp slot 0 (bf16) ---------
__global__ __launch_bounds__(256) void tmp0_kernel(const unsigned* h0_u32, const float* seq_mean,
                                                   const float* wo1, const float* bo1,
                                                   unsigned* tmp_u32) {
  int gid = blockIdx.x * 256 + threadIdx.x;  // 8192
  int b = gid >> 9, j = gid & 511;
  const f32x4* x1 = (const f32x4*)(seq_mean + b * 512);
  const f32x4* w0 = (const f32x4*)(wo1 + (size_t)j * 1024);
  const f32x4* w1 = w0 + 128;
  float a = bo1[j];
  float p = 0;
  const ushort_t* h0 = (const ushort_t*)(h0_u32) + b * 512;
  for (int k = 0; k < 128; ++k) {
    f32x4 hv = {bf2f(h0[k * 4]), bf2f(h0[k * 4 + 1]), bf2f(h0[k * 4 + 2]), bf2f(h0[k * 4 + 3])};
    p += dot4(hv, w0[k]);
  }
  for (int k = 0; k < 128; ++k) p += dot4(x1[k], w1[k]);
  float tv = tanh_f(a + p);
  unsigned bits = (unsigned)f2bf(tv);
  unsigned pb2 = __shfl_xor(bits, 1);
  if ((j & 1) == 0) tmp_u32[b * 256 + (j >> 1)] = bits | (pb2 << 16);
}

// ---------------- persistent decoder: PA (global) / PB (per-b) / PC (per-b) ----------------
// Per step: PA -> grid barrier -> PB -> 8-block group barrier -> PC -> grid barrier.
// Each block's enc_outs chunk (50 x 512) is LDS-resident bf16 (loaded once).
__global__ __launch_bounds__(256) void dec_kernel(
    const ushort_t* xt_bf, const int* src_len, const ushort_t* wdec_pk,
    const float* wpgen, const float* bpgen, const float* wfp, const ushort_t* wo1_bf,
    const float* bo1, const float* enc_outs, const float* gxT, unsigned* h_u32,
    const float* c_init, unsigned* tmp_u32, float* ctx_part, float* z_part, float* zinv,
    float* pgen_o, float* pexp, unsigned* ctrs) {
  __shared__ ushort_t ec_s[50 * 512];  // 51.2 KB enc chunk (bf16)
  __shared__ float part_s[4 * 16 * 17];
  __shared__ f32x4 smem4[272];  // h_s(512) + ctx_s(512) + pad
  __shared__ float red_s[8];
  __shared__ float p_s[64];
  float* sm = (float*)smem4;
  unsigned* region = ctrs + 2 * 1024;

  const int blk = blockIdx.x, tid = threadIdx.x;
  const int w = tid >> 6, lane = tid & 63, lr = lane & 15, kh = lane >> 4;
  const int j0 = blk * 4;
  const ushort_t* wrow = wdec_pk + (size_t)(blk * 16 + lr) * 1024 + w * 256 + kh * 8;
  const int b_c = tid & 15, u_c = (tid >> 4) & 3;
  float c_reg = (tid < 64) ? c_init[b_c * 512 + j0 + u_c] : 0.0f;
  const int b_pb = blk >> 3, ch = blk & 7, s0c = ch * 50;
  const int len_pb = src_len[b_pb];
  const int nc = ch;
  unsigned* greg = ctrs + 3 * 1024 + b_pb * 64;
  unsigned gpc = 0;

  // load enc chunk into LDS as bf16 (once; constant across all 100 steps)
  {
    const f32x4* ebase = (const f32x4*)(enc_outs + ((size_t)b_pb * S_SZ + s0c) * H_SZ);
    unsigned* dst = (unsigned*)ec_s;
    for (int i = tid; i < 6400; i += 256) {
      f32x4 v = ebase[i];
      dst[2 * i] = (unsigned)f2bf(v.x) | ((unsigned)f2bf(v.y) << 16);
      dst[2 * i + 1] = (unsigned)f2bf(v.z) | ((unsigned)f2bf(v.w) << 16);
    }
  }

  // prefetch gx for t=0 (coalesced gxT layout [t][row][b])
  float gxa[4] = {0.f, 0.f, 0.f, 0.f};
  if (tid < 64) {
#pragma unroll
    for (int g2 = 0; g2 < 4; ++g2)
      gxa[g2] = gxT[((size_t)(g2 * 512 + j0 + u_c)) * 16 + b_c];
  }

  for (int t = 0; t < T_SZ; ++t) {
    // ---------- PA: gates via MFMA (K=1024 split over 4 waves) ----------
    {
      f32x4 acc = {0.f, 0.f, 0.f, 0.f};
      const unsigned* asrc = (w < 2) ? (h_u32 + (size_t)t * 4096) : (tmp_u32 + (size_t)t * 4096);
      const ushort_t* ap = (const ushort_t*)asrc + lr * 512 + (w & 1) * 256 + kh * 8;
#pragma unroll
      for (int k0 = 0; k0 < 256; k0 += 32)
        acc = __builtin_amdgcn_mfma_f32_16x16x32_bf16(*(const bf16x8*)(ap + k0),
                                                      *(const bf16x8*)(wrow + k0), acc, 0, 0, 0);
#pragma unroll
      for (int i = 0; i < 4; ++i) part_s[(w * 16 + lr) * 17 + kh * 4 + i] = acc[i];
      __syncthreads();
      if (tid < 64) {
        float gt[4];
#pragma unroll
        for (int g2 = 0; g2 < 4; ++g2) {
          int p = g2 * 4 + u_c;
          float a = gxa[g2];
#pragma unroll
          for (int w2 = 0; w2 < 4; ++w2) a += part_s[(w2 * 16 + p) * 17 + b_c];
          gt[g2] = a;
        }
        float cn = sigf(gt[1]) * c_reg + sigf(gt[0]) * tanh_f(gt[2]);
        c_reg = cn;
        float hn = sigf(gt[3]) * tanh_f(cn);
        unsigned bits = (unsigned)f2bf(hn);
        unsigned pb2 = __shfl_xor(bits, 16);
        if ((u_c & 1) == 0)
          stg_u32(&h_u32[(size_t)(t + 1) * 4096 + b_c * 256 + ((j0 + u_c) >> 1)],
                  bits | (pb2 << 16));
      }
    }
    grid_barrier(region, blk, 128, ++gpc);
    // ---------- PB: scores + partial ctx from LDS chunk ----------
    {
      // prefetch next step's gx (pure latency hide)
      if (tid < 64 && t + 1 < T_SZ) {
#pragma unroll
        for (int g2 = 0; g2 < 4; ++g2)
          gxa[g2] = gxT[((size_t)(t + 1) * G4 + g2 * 512 + j0 + u_c) * 16 + b_c];
      }
      if (tid < 128) {
        unsigned v0 = h_u32[(size_t)(t + 1) * 4096 + b_pb * 256 + tid * 2];
        unsigned v1 = h_u32[(size_t)(t + 1) * 4096 + b_pb * 256 + tid * 2 + 1];
        f32x4 hv = {bfu2f(v0 & 0xffffu), bfu2f(v0 >> 16), bfu2f(v1 & 0xffffu), bfu2f(v1 >> 16)};
        ((f32x4*)sm)[tid] = hv;
      }
      __syncthreads();
      int st = tid >> 2, kq = tid & 3;
      if (st < 50) {
        const ushort8_t* er = (const ushort8_t*)(ec_s + st * 512) + kq * 16;
        const f32x4* hr = (const f32x4*)sm + kq * 32;
        float sc = 0;
#pragma unroll 4
        for (int k = 0; k < 16; ++k) {
          ushort8_t w8 = er[k];
          f32x4 w0 = {bf2f(w8[0]), bf2f(w8[1]), bf2f(w8[2]), bf2f(w8[3])};
          f32x4 w1 = {bf2f(w8[4]), bf2f(w8[5]), bf2f(w8[6]), bf2f(w8[7])};
          sc += dot4(hr[2 * k], w0) + dot4(hr[2 * k + 1], w1);
        }
        sc += __shfl_xor(sc, 1);
        sc += __shfl_xor(sc, 2);
        if (kq == 0) {
          int s_abs = s0c + st;
          float p = (s_abs < len_pb) ? __expf(sc) : 0.0f;
          p_s[st] = p;
          pexp[((size_t)t * 16 + b_pb) * S_SZ + s_abs] = p;
        }
      }
      __syncthreads();
      if (tid == 0) {
        float z = 0;
        for (int s = 0; s < 50; ++s) z += p_s[s];
        stg(&z_part[((size_t)t * 16 + b_pb) * 8 + ch], z);
      }
      float a0 = 0, a1 = 0;
      for (int s = 0; s < 50; ++s) {
        float p = p_s[s];
        a0 += p * bf2f(ec_s[s * 512 + tid]);
        a1 += p * bf2f(ec_s[s * 512 + tid + 256]);
      }
      float* cp = ctx_part + (((size_t)t * 16 + b_pb) * 8 + ch) * 512;
      stg(&cp[tid], a0);
      stg(&cp[tid + 256], a1);
    }
    group_barrier(greg, (unsigned)(t + 1));
    // ---------- PC: combine ctx + pgen + tmp (h staged in sm by PB) ----------
    {
      float* h_s = sm;
      float* ctx_s = sm + 512;
      const float* zp = z_part + ((size_t)t * 16 + b_pb) * 8;
      float z = 0;
#pragma unroll
      for (int c2 = 0; c2 < 8; ++c2) z += zp[c2];
      float inv = 1.0f / z;
      const float* cpb = ctx_part + ((size_t)t * 16 + b_pb) * 8 * 512;
      float c0 = 0, c1 = 0;
#pragma unroll
      for (int c2 = 0; c2 < 8; ++c2) {
        c0 += cpb[c2 * 512 + tid];
        c1 += cpb[c2 * 512 + tid + 256];
      }
      ctx_s[tid] = c0 * inv;
      ctx_s[tid + 256] = c1 * inv;
      __syncthreads();
      const ushort_t* tmpp = (const ushort_t*)(tmp_u32 + (size_t)t * 4096) + b_pb * 512;
      float tp0 = bf2f(tmpp[tid]);
      float tp1 = bf2f(tmpp[tid + 256]);
      float xe = bf2f(xt_bf[((size_t)t * 16 + b_pb) * 256 + tid]);
      float pg = wpgen[tid] * ctx_s[tid] + wpgen[tid + 256] * ctx_s[tid + 256] +
                 wpgen[512 + tid] * h_s[tid] + wpgen[512 + tid + 256] * h_s[tid + 256] +
                 wpgen[1024 + tid] * xe + wfp[tid] * tp0 + wfp[tid + 256] * tp1;
#pragma unroll
      for (int o = 32; o; o >>= 1) pg += __shfl_xor(pg, o);
      if (lane == 0) red_s[w] = pg;
      __syncthreads();
      if (nc == 0 && tid == 0) {
        pgen_o[t * 16 + b_pb] = sigf(red_s[0] + red_s[1] + red_s[2] + red_s[3] + bpgen[0]);
        zinv[t * 16 + b_pb] = inv;
      }
      int nidx = tid >> 2, kq = tid & 3;
      int n = nc * 64 + nidx;
      const ushort8_t* wrp = (const ushort8_t*)(wo1_bf + (size_t)n * 1024) + kq * 32;
      const f32x4* xr2 =
          (kq < 2) ? ((const f32x4*)h_s + kq * 64) : ((const f32x4*)ctx_s + (kq - 2) * 64);
      float a = 0;
#pragma unroll 4
      for (int k = 0; k < 32; ++k) {
        ushort8_t w8 = wrp[k];
        f32x4 w0 = {bf2f(w8[0]), bf2f(w8[1]), bf2f(w8[2]), bf2f(w8[3])};
        f32x4 w1 = {bf2f(w8[4]), bf2f(w8[5]), bf2f(w8[6]), bf2f(w8[7])};
        a += dot4(xr2[2 * k], w0) + dot4(xr2[2 * k + 1], w1);
      }
      a += __shfl_xor(a, 1);
      a += __shfl_xor(a, 2);
      float tv = tanh_f(a + bo1[n]);
      unsigned bits = (unsigned)f2bf(tv);
      unsigned pbits = __shfl_xor(bits, 4);
      if (kq == 0 && (nidx & 1) == 0)
        stg_u32(&tmp_u32[(size_t)(t + 1) * 4096 + b_pb * 256 + ((nc * 64 + nidx) >> 1)],
                bits | (pbits << 16));
    }
    if (t + 1 < T_SZ) grid_barrier(region, blk, 128, ++gpc);
  }
}

// ---------------- per (t,b) row softmax + copy-scatter + log ----------------
__global__ __launch_bounds__(1024) void finalize_kernel(float* out, const float* pexp,
                                                        const float* zinv, const float* pgen_i,
                                                        const int* src_ext) {
  __shared__ float scat[VX];
  __shared__ float red[64];
  const int row = blockIdx.x;
  const int b = row & 15;
  const int tid = threadIdx.x;
  for (int i = tid; i < VX; i += 1024) scat[i] = 0.0f;
  __syncthreads();
  const float pg = pgen_i[row];
  const float inv = zinv[row];
  if (tid < S_SZ) {
    float v = (1.0f - pg) * pexp[(size_t)row * S_SZ + tid] * inv;
    int col = src_ext[b * S_SZ + tid];
    atomicAdd(&scat[col], v);
  }
  float* orow = out + (size_t)row * VX;
  float l[32];
  float mx = -3.4e38f;
#pragma unroll
  for (int i2 = 0; i2 < 32; ++i2) {
    int col = tid + (i2 << 10);
    l[i2] = (col < V_SZ) ? orow[col] : -3.4e38f;
    mx = fmaxf(mx, l[i2]);
  }
#pragma unroll
  for (int o = 32; o; o >>= 1) mx = fmaxf(mx, __shfl_xor(mx, o));
  if ((tid & 63) == 0) red[16 + (tid >> 6)] = mx;
  __syncthreads();
  if (tid == 0) {
    float m2 = red[16];
    for (int w = 1; w < 16; ++w) m2 = fmaxf(m2, red[16 + w]);
    red[0] = m2;
  }
  __syncthreads();
  const float gmx = red[0];
  float se = 0.0f;
#pragma unroll
  for (int i2 = 0; i2 < 32; ++i2) {
    int col = tid + (i2 << 10);
    if (col < V_SZ) {
      l[i2] = __expf(l[i2] - gmx);
      se += l[i2];
    }
  }
#pragma unroll
  for (int o = 32; o; o >>= 1) se += __shfl_xor(se, o);
  if ((tid & 63) == 0) red[32 + (tid >> 6)] = se;
  __syncthreads();
  if (tid == 0) {
    float s2 = 0;
    for (int w = 0; w < 16; ++w) s2 += red[32 + w];
    red[1] = s2;
  }
  __syncthreads();
  const float scale = pg / red[1];
#pragma unroll
  for (int i2 = 0; i2 < 32; ++i2) {
    int col = tid + (i2 << 10);
    if (col < VX) {
      float base = (col < V_SZ) ? l[i2] * scale : 0.0f;
      orow[col] = __logf(base + scat[col] + 1e-20f);
    }
  }
}

extern "C" void kernel_launch(void* const* d_in, const int* in_sizes, int n_in, void* d_out,
                              int out_size, void* d_ws, size_t ws_size, hipStream_t stream) {
  (void)in_sizes; (void)n_in; (void)out_size; (void)ws_size;
  const int* source = (const int*)d_in[0];
  const int* source_ext = (const int*)d_in[1];
  const int* source_len = (const int*)d_in[2];
  const int* target = (const int*)d_in[3];
  const float* emb = (const float*)d_in[4];
  const float* wih_f = (const float*)d_in[5];
  const float* whh_f = (const float*)d_in[6];
  const float* b_f = (const float*)d_in[7];
  const float* wih_b = (const float*)d_in[8];
  const float* whh_b = (const float*)d_in[9];
  const float* b_b = (const float*)d_in[10];
  const float* wproj = (const float*)d_in[11];
  const float* bproj = (const float*)d_in[12];
  const float* w2h = (const float*)d_in[13];
  const float* b2h = (const float*)d_in[14];
  const float* w2c = (const float*)d_in[15];
  const float* b2c = (const float*)d_in[16];
  const float* wo1 = (const float*)d_in[17];
  const float* bo1 = (const float*)d_in[18];
  const float* wo2 = (const float*)d_in[19];
  const float* dwih = (const float*)d_in[20];
  const float* dwhh = (const float*)d_in[21];
  const float* dbias = (const float*)d_in[22];
  const float* wpgen = (const float*)d_in[23];
  const float* bpgen = (const float*)d_in[24];
  float* out = (float*)d_out;

  size_t off = 0;
  char* wsb = (char*)d_ws;
  auto alloc = [&](size_t bytes) -> void* {
    void* p = wsb + off;
    off += (bytes + 255) & ~(size_t)255;
    return p;
  };
  unsigned* ctrs = (unsigned*)alloc(4 * 4096);  // enc_f, enc_b, dec global, dec groups
  ushort_t* emb_bf = (ushort_t*)alloc((size_t)V_SZ * D_SZ * 2);
  ushort_t* wihf_bf = (ushort_t*)alloc((size_t)G4 * D_SZ * 2);
  ushort_t* wihb_bf = (ushort_t*)alloc((size_t)G4 * D_SZ * 2);
  ushort_t* wihd_bf = (ushort_t*)alloc((size_t)G4 * D_SZ * 2);
  ushort_t* wproj_bf = (ushort_t*)alloc((size_t)H_SZ * 2 * H_SZ * 2);
  ushort_t* wo2t_bf = (ushort_t*)alloc((size_t)H_SZ * D_SZ * 2);
  ushort_t* wo1_bf = (ushort_t*)alloc((size_t)H_SZ * 1024 * 2);
  float* wfused = (float*)alloc((size_t)G4 * H_SZ * 4);
  float* wfp = (float*)alloc(512 * 4);
  ushort_t* whh_pk = (ushort_t*)alloc((size_t)2 * G4 * H_SZ * 2);
  ushort_t* wdec_pk = (ushort_t*)alloc((size_t)G4 * 1024 * 2);
  ushort_t* xs_bf = (ushort_t*)alloc((size_t)S_SZ * B_SZ * D_SZ * 2);
  ushort_t* xt_bf = (ushort_t*)alloc((size_t)T_SZ * B_SZ * D_SZ * 2);
  float* gx_f = (float*)alloc((size_t)S_SZ * B_SZ * G4 * 4);  // aliased by e2_bf after enc
  float* gx_b = (float*)alloc((size_t)S_SZ * B_SZ * G4 * 4);  // aliased by gx_dec/ctx_part/gxT
  unsigned* hbf_f = (unsigned*)alloc((size_t)(S_SZ + 1) * 4096 * 4);
  unsigned* hbf_b = (unsigned*)alloc((size_t)(S_SZ + 1) * 4096 * 4);
  unsigned* ys_cat_u32 = (unsigned*)alloc((size_t)S_SZ * B_SZ * 512 * 4);
  float* h_final = (float*)alloc((size_t)2 * B_SZ * H_SZ * 4);
  float* c_final = (float*)alloc((size_t)2 * B_SZ * H_SZ * 4);
  float* enc_outs = (float*)alloc((size_t)B_SZ * S_SZ * H_SZ * 4);
  float* seq_mean = (float*)alloc((size_t)B_SZ * H_SZ * 4);
  unsigned* h_u32 = (unsigned*)alloc((size_t)(T_SZ + 1) * 4096 * 4);
  float* c_init = (float*)alloc((size_t)B_SZ * H_SZ * 4);
  unsigned* tmp_u32 = (unsigned*)alloc((size_t)(T_SZ + 1) * 4096 * 4);
  float* z_part = (float*)alloc((size_t)T_SZ * B_SZ * 8 * 4);
  float* zinv = (float*)alloc((size_t)T_SZ * B_SZ * 4);
  float* pgen_b = (float*)alloc((size_t)T_SZ * B_SZ * 4);
  float* pexp = (float*)alloc((size_t)T_SZ * B_SZ * S_SZ * 4);
  // aliases into dead-after-encoder regions (gx_b = 13,107,200 floats)
  ushort_t* e2_bf = (ushort_t*)gx_f;                     // 32.8 MB
  float* gx_dec = gx_b;                                  // 3,276,800 floats
  float* ctx_part = gx_b + (size_t)3276800;              // 6,553,600 floats
  float* gxT = gx_b + (size_t)9830400;                   // 3,276,800 floats (fits exactly)

  hipMemsetAsync(ctrs, 0, 4 * 4096, stream);           // barrier regions
  hipMemsetAsync(hbf_f, 0, 4096 * 4, stream);          // enc h slot 0 (dir f)
  hipMemsetAsync(hbf_b, 0, 4096 * 4, stream);          // enc h slot 0 (dir b)

  cvt_kernel<<<2048, 256, 0, stream>>>(emb, emb_bf, V_SZ * D_SZ);
  cvt_kernel<<<2048, 256, 0, stream>>>(wih_f, wihf_bf, G4 * D_SZ);
  cvt_kernel<<<2048, 256, 0, stream>>>(wih_b, wihb_bf, G4 * D_SZ);
  cvt_kernel<<<2048, 256, 0, stream>>>(wproj, wproj_bf, H_SZ * 2 * H_SZ);
  cvt_kernel<<<2048, 256, 0, stream>>>(wo1, wo1_bf, H_SZ * 1024);
  cvt_strided_kernel<<<2048, 256, 0, stream>>>(dwih, wihd_bf);
  cvt_wo2t_kernel<<<512, 256, 0, stream>>>(wo2, wo2t_bf);
  wfused_kernel<<<2048, 256, 0, stream>>>(dwih, wo2, wfused);
  wfp_kernel<<<2, 256, 0, stream>>>(wpgen, wo2, wfp);
  pack_whh_kernel<<<8192, 256, 0, stream>>>(whh_f, whh_b, whh_pk);
  pack_wdec_kernel<<<8192, 256, 0, stream>>>(dwhh, wfused, wdec_pk);
  gather_src_kernel<<<800, 256, 0, stream>>>(emb_bf, source, xs_bf);
  gather_tgt_kernel<<<200, 256, 0, stream>>>(emb_bf, target, xt_bf);
  gemm_abt_bias<<<dim3(8, 400), 256, 0, stream>>>(xs_bf, wihf_bf, b_f, gx_f, 256);
  gemm_abt_bias<<<dim3(8, 400), 256, 0, stream>>>(xs_bf, wihb_bf, b_b, gx_b, 256);
  enc_kernel<<<64, 256, 0, stream>>>(gx_f, gx_b, whh_pk, source_len, hbf_f, hbf_b, ys_cat_u32,
                                     h_final, c_final, ctrs);
  gemm_encout<<<dim3(2, 400), 256, 0, stream>>>((const ushort_t*)ys_cat_u32, wproj_bf, bproj,
                                                enc_outs);
  seqmean_kernel<<<32, 256, 0, stream>>>(enc_outs, source_len, seq_mean);
  init_state_kernel<<<64, 256, 0, stream>>>(h_final, c_final, w2h, b2h, w2c, b2c, h_u32, c_init);
  tmp0_kernel<<<32, 256, 0, stream>>>(h_u32, seq_mean, wo1, bo1, tmp_u32);
  gemm_abt_bias<<<dim3(8, 100), 256, 0, stream>>>(xt_bf, wihd_bf, dbias, gx_dec, 256);
  gxT_kernel<<<dim3(8, 100), 256, 0, stream>>>(gx_dec, gxT);
  gemm_e2<<<dim3(2, 2000), 256, 0, stream>>>(emb_bf, wo2t_bf, e2_bf);
  dec_kernel<<<128, 256, 0, stream>>>(xt_bf, source_len, wdec_pk, wpgen, bpgen, wfp, wo1_bf, bo1,
                                      enc_outs, gxT, h_u32, c_init, tmp_u32, ctx_part, z_part,
                                      zinv, pgen_b, pexp, ctrs);
  gemm_logits<<<dim3(100, 125), 256, 0, stream>>>((const ushort_t*)(tmp_u32 + 4096), e2_bf, out);
  finalize_kernel<<<1600, 1024, 0, stream>>>(out, pexp, zinv, pgen_b, source_ext);
}